// Round 10
// baseline (863.842 us; speedup 1.0000x reference)
//
#include <hip/hip_runtime.h>

static constexpr int NG = 512;       // graphs
static constexpr float LN_EPS = 1e-5f;
static constexpr float BNS = 0.9999950000374997f; // rsqrt(1 + 1e-5) for BatchNorm eval

__device__ __forceinline__ float eluf(float v) { return v > 0.f ? v : expm1f(v); }

typedef __attribute__((ext_vector_type(8))) short bf16x8;
typedef __attribute__((ext_vector_type(4))) float f32x4;

__device__ __forceinline__ ushort f2b(float f) {   // f32 -> bf16 RNE
    union { float f; unsigned u; } v; v.f = f;
    const unsigned u = v.u;
    return (ushort)((u + 0x7FFFu + ((u >> 16) & 1u)) >> 16);
}
__device__ __forceinline__ float b2f(ushort b) {
    union { unsigned u; float f; } v; v.u = ((unsigned)b) << 16;
    return v.f;
}

// async global->LDS, 16B per lane. LDS dest must be lane-contiguous (linear).
__device__ __forceinline__ void gl16(const ushort* g, ushort* l) {
    __builtin_amdgcn_global_load_lds(
        (const __attribute__((address_space(1))) void*)g,
        (__attribute__((address_space(3))) void*)l, 16, 0, 0);
}

// ---------------------------------------------------------------------------
// lin1 MFMA GEMM: B1 = bf16(elu(x@W+b)), gr slice0 = f32 of same.
// BM=128, BN=256, BK=64, KSTEPS=2 (K=128). 512 thr = 8 waves.
// Staging via global_load_lds: linear LDS slots, XOR'd SOURCE chunk (rule #21),
// ds_read keeps the same XOR.
// ---------------------------------------------------------------------------
template<int KSTEPS>
__global__ __launch_bounds__(512)
void tgemm_kernel(const ushort* __restrict__ Ab, int ldab,
                  const ushort* __restrict__ Wt,   // [256][K]
                  const float* __restrict__ bias,
                  ushort* __restrict__ Cb, float* __restrict__ Cf,
                  int n)
{
    __shared__ __align__(16) ushort sbuf[32768];   // 64 KB
    ushort* As = sbuf;          // 128*64
    ushort* Bs = sbuf + 8192;   // 256*64

    const int tid = threadIdx.x;
    const int lane = tid & 63;
    const int wv = tid >> 6;
    const int wr = wv >> 1, wc = wv & 1;
    const int r0 = blockIdx.x * 128;
    const int colL = lane & 15;
    const int lr = lane >> 4;

    f32x4 acc[2][8];
#pragma unroll
    for (int rt = 0; rt < 2; ++rt)
#pragma unroll
        for (int ct = 0; ct < 8; ++ct) acc[rt][ct] = (f32x4){0.f, 0.f, 0.f, 0.f};

    for (int ks = 0; ks < KSTEPS; ++ks) {
#pragma unroll
        for (int it = 0; it < 2; ++it) {           // A: 1024 chunks
            const int i = it * 512 + tid;
            const int row = i >> 3, cb = i & 7;
            const int rg = min(r0 + row, n - 1);
            gl16(Ab + (size_t)rg * ldab + ks * 64 + ((cb ^ (row & 7)) * 8), As + i * 8);
        }
#pragma unroll
        for (int it = 0; it < 4; ++it) {           // B: 2048 chunks
            const int i = it * 512 + tid;
            const int col = i >> 3, cb = i & 7;
            gl16(Wt + (size_t)col * (KSTEPS * 64) + ks * 64 + ((cb ^ (col & 7)) * 8), Bs + i * 8);
        }
        __syncthreads();

        bf16x8 af[2][2];
#pragma unroll
        for (int rt = 0; rt < 2; ++rt)
#pragma unroll
            for (int kk = 0; kk < 2; ++kk) {
                const int row = wr * 32 + rt * 16 + colL;
                const int blk = kk * 4 + lr;
                af[rt][kk] = *reinterpret_cast<const bf16x8*>(As + row * 64 + ((blk ^ (row & 7)) * 8));
            }
#pragma unroll
        for (int ct = 0; ct < 8; ++ct)
#pragma unroll
            for (int kk = 0; kk < 2; ++kk) {
                const int col = wc * 128 + ct * 16 + colL;
                const int blk = kk * 4 + lr;
                const bf16x8 bf = *reinterpret_cast<const bf16x8*>(Bs + col * 64 + ((blk ^ (col & 7)) * 8));
                acc[0][ct] = __builtin_amdgcn_mfma_f32_16x16x32_bf16(af[0][kk], bf, acc[0][ct], 0, 0, 0);
                acc[1][ct] = __builtin_amdgcn_mfma_f32_16x16x32_bf16(af[1][kk], bf, acc[1][ct], 0, 0, 0);
            }
        __syncthreads();
    }

    // epilogue: elu -> wave-private LDS transpose -> coalesced bf16 + f32 stores
    float bv[8];
#pragma unroll
    for (int ct = 0; ct < 8; ++ct) bv[ct] = bias[wc * 128 + ct * 16 + colL];

    ushort* eb = sbuf + wv * 4096;   // 32 rows x 128 cols
#pragma unroll
    for (int rt = 0; rt < 2; ++rt)
#pragma unroll
        for (int ct = 0; ct < 8; ++ct)
#pragma unroll
            for (int r = 0; r < 4; ++r) {
                const float v = eluf(acc[rt][ct][r] + bv[ct]);
                eb[(rt * 16 + lr * 4 + r) * 128 + ct * 16 + colL] = f2b(v);
            }
#pragma unroll
    for (int j = 0; j < 8; ++j) {
        const int idx = j * 64 + lane;
        const int lrow = idx >> 4, c8 = idx & 15;
        const int grow = r0 + wr * 32 + lrow;
        if (grow < n) {
            const bf16x8 v8 = *reinterpret_cast<const bf16x8*>(eb + lrow * 128 + c8 * 8);
            *reinterpret_cast<bf16x8*>(Cb + (size_t)grow * 256 + wc * 128 + c8 * 8) = v8;
            float4 lo = make_float4(b2f((ushort)v8[0]), b2f((ushort)v8[1]), b2f((ushort)v8[2]), b2f((ushort)v8[3]));
            float4 hi = make_float4(b2f((ushort)v8[4]), b2f((ushort)v8[5]), b2f((ushort)v8[6]), b2f((ushort)v8[7]));
            float* gp = Cf + (size_t)grow * 768 + wc * 128 + c8 * 8;
            *reinterpret_cast<float4*>(gp) = lo;
            *reinterpret_cast<float4*>(gp + 4) = hi;
        }
    }
}

// ---------------------------------------------------------------------------
// FUSED dense GIN MLP (layer 0): out = elu(relu(A@W1+b1)@W2+b2), stats on out.
// BM=128, BN=256, K=256. z [128x256] bf16 kept in LDS.
// ---------------------------------------------------------------------------
__global__ __launch_bounds__(512)
void mlp0_kernel(const ushort* __restrict__ Ab,    // [n][256]
                 const ushort* __restrict__ W1t,   // [256][256]
                 const ushort* __restrict__ W2t,
                 const float* __restrict__ b1, const float* __restrict__ b2,
                 ushort* __restrict__ Cb,
                 int n, double* __restrict__ stats)
{
    __shared__ __align__(16) ushort As[8192];
    __shared__ __align__(16) ushort Bs[16384];
    __shared__ __align__(16) ushort Z[32768];

    const int tid = threadIdx.x;
    const int lane = tid & 63;
    const int wv = tid >> 6;
    const int wr = wv >> 1, wc = wv & 1;
    const int r0 = blockIdx.x * 128;
    const int colL = lane & 15;
    const int lr = lane >> 4;

    f32x4 acc[2][8];
#pragma unroll
    for (int rt = 0; rt < 2; ++rt)
#pragma unroll
        for (int ct = 0; ct < 8; ++ct) acc[rt][ct] = (f32x4){0.f, 0.f, 0.f, 0.f};

    // ---- stage 1: z = relu(A @ W1 + b1) ----
    for (int ks = 0; ks < 4; ++ks) {
#pragma unroll
        for (int it = 0; it < 2; ++it) {
            const int i = it * 512 + tid;
            const int row = i >> 3, cb = i & 7;
            const int rg = min(r0 + row, n - 1);
            gl16(Ab + (size_t)rg * 256 + ks * 64 + ((cb ^ (row & 7)) * 8), As + i * 8);
        }
#pragma unroll
        for (int it = 0; it < 4; ++it) {
            const int i = it * 512 + tid;
            const int col = i >> 3, cb = i & 7;
            gl16(W1t + (size_t)col * 256 + ks * 64 + ((cb ^ (col & 7)) * 8), Bs + i * 8);
        }
        __syncthreads();
        bf16x8 af[2][2];
#pragma unroll
        for (int rt = 0; rt < 2; ++rt)
#pragma unroll
            for (int kk = 0; kk < 2; ++kk) {
                const int row = wr * 32 + rt * 16 + colL;
                const int blk = kk * 4 + lr;
                af[rt][kk] = *reinterpret_cast<const bf16x8*>(As + row * 64 + ((blk ^ (row & 7)) * 8));
            }
#pragma unroll
        for (int ct = 0; ct < 8; ++ct)
#pragma unroll
            for (int kk = 0; kk < 2; ++kk) {
                const int col = wc * 128 + ct * 16 + colL;
                const int blk = kk * 4 + lr;
                const bf16x8 bf = *reinterpret_cast<const bf16x8*>(Bs + col * 64 + ((blk ^ (col & 7)) * 8));
                acc[0][ct] = __builtin_amdgcn_mfma_f32_16x16x32_bf16(af[0][kk], bf, acc[0][ct], 0, 0, 0);
                acc[1][ct] = __builtin_amdgcn_mfma_f32_16x16x32_bf16(af[1][kk], bf, acc[1][ct], 0, 0, 0);
            }
        __syncthreads();
    }
    // write z (relu, bf16) to swizzled LDS: row-major [128][256], 16B-chunk swizzle
#pragma unroll
    for (int ct = 0; ct < 8; ++ct) {
        const float bvv = b1[wc * 128 + ct * 16 + colL];
#pragma unroll
        for (int rt = 0; rt < 2; ++rt)
#pragma unroll
            for (int r = 0; r < 4; ++r) {
                const float v = fmaxf(acc[rt][ct][r] + bvv, 0.f);
                const int zrow = wr * 32 + rt * 16 + lr * 4 + r;
                const int zcol = wc * 128 + ct * 16 + colL;
                const int chunk = zcol >> 3;
                const int sw = (chunk & 24) | ((chunk & 7) ^ (zrow & 7));
                Z[zrow * 256 + sw * 8 + (zcol & 7)] = f2b(v);
            }
    }
    __syncthreads();

    // ---- stage 2: out = elu(z @ W2 + b2) ----
#pragma unroll
    for (int rt = 0; rt < 2; ++rt)
#pragma unroll
        for (int ct = 0; ct < 8; ++ct) acc[rt][ct] = (f32x4){0.f, 0.f, 0.f, 0.f};

    for (int ks = 0; ks < 4; ++ks) {
#pragma unroll
        for (int it = 0; it < 4; ++it) {
            const int i = it * 512 + tid;
            const int col = i >> 3, cb = i & 7;
            gl16(W2t + (size_t)col * 256 + ks * 64 + ((cb ^ (col & 7)) * 8), Bs + i * 8);
        }
        __syncthreads();
        bf16x8 zf[2][2];
#pragma unroll
        for (int rt = 0; rt < 2; ++rt)
#pragma unroll
            for (int kk = 0; kk < 2; ++kk) {
                const int zrow = wr * 32 + rt * 16 + colL;
                const int chunk = ks * 8 + kk * 4 + lr;
                const int sw = (chunk & 24) | ((chunk & 7) ^ (zrow & 7));
                zf[rt][kk] = *reinterpret_cast<const bf16x8*>(Z + zrow * 256 + sw * 8);
            }
#pragma unroll
        for (int ct = 0; ct < 8; ++ct)
#pragma unroll
            for (int kk = 0; kk < 2; ++kk) {
                const int col = wc * 128 + ct * 16 + colL;
                const int blk = kk * 4 + lr;
                const bf16x8 bf = *reinterpret_cast<const bf16x8*>(Bs + col * 64 + ((blk ^ (col & 7)) * 8));
                acc[0][ct] = __builtin_amdgcn_mfma_f32_16x16x32_bf16(zf[0][kk], bf, acc[0][ct], 0, 0, 0);
                acc[1][ct] = __builtin_amdgcn_mfma_f32_16x16x32_bf16(zf[1][kk], bf, acc[1][ct], 0, 0, 0);
            }
        __syncthreads();
    }

    // ---- epilogue (Z reused as wave-private transpose buffer) ----
    float bv[8];
#pragma unroll
    for (int ct = 0; ct < 8; ++ct) bv[ct] = b2[wc * 128 + ct * 16 + colL];
    ushort* eb = Z + wv * 4096;
    float s = 0.f, ss = 0.f;
#pragma unroll
    for (int rt = 0; rt < 2; ++rt)
#pragma unroll
        for (int ct = 0; ct < 8; ++ct)
#pragma unroll
            for (int r = 0; r < 4; ++r) {
                const float v = eluf(acc[rt][ct][r] + bv[ct]);
                eb[(rt * 16 + lr * 4 + r) * 128 + ct * 16 + colL] = f2b(v);
                const int row = r0 + wr * 32 + rt * 16 + lr * 4 + r;
                if (row < n) { s += v; ss += v * v; }
            }
#pragma unroll
    for (int j = 0; j < 8; ++j) {
        const int idx = j * 64 + lane;
        const int lrow = idx >> 4, c8 = idx & 15;
        const int grow = r0 + wr * 32 + lrow;
        if (grow < n)
            *reinterpret_cast<bf16x8*>(Cb + (size_t)grow * 256 + wc * 128 + c8 * 8) =
                *reinterpret_cast<const bf16x8*>(eb + lrow * 128 + c8 * 8);
    }
    double ds = (double)s, dss = (double)ss;
    for (int o = 32; o; o >>= 1) { ds += __shfl_down(ds, o, 64); dss += __shfl_down(dss, o, 64); }
    if (lane == 0) { unsafeAtomicAdd(&stats[0], ds); unsafeAtomicAdd(&stats[1], dss); }
}

// ---------------------------------------------------------------------------
// FUSED block-diagonal GIN MLP (layer 1), 32KB LDS (Z overlays As).
// ---------------------------------------------------------------------------
__global__ __launch_bounds__(256)
void bd2_kernel(const ushort* __restrict__ Ab,    // [n][256]
                const ushort* __restrict__ W1t,   // [4][64 col][64 k]
                const ushort* __restrict__ W2t,
                const float* __restrict__ b1, const float* __restrict__ b2,
                ushort* __restrict__ Cb,
                int n, double* __restrict__ stats)
{
    __shared__ __align__(16) ushort As[8192];    // 128x64; later: 4 wave-private Z regions
    __shared__ __align__(16) ushort B1s[4096];
    __shared__ __align__(16) ushort B2s[4096];

    const int tid = threadIdx.x;
    const int lane = tid & 63;
    const int wv = tid >> 6;
    const int ch = blockIdx.y;
    const int r0 = blockIdx.x * 128;
    const int colL = lane & 15;
    const int lr = lane >> 4;

#pragma unroll
    for (int it = 0; it < 4; ++it) {             // A: 1024 chunks
        const int i = it * 256 + tid;
        const int row = i >> 3, cb = i & 7;
        const int rg = min(r0 + row, n - 1);
        gl16(Ab + (size_t)rg * 256 + ch * 64 + ((cb ^ (row & 7)) * 8), As + i * 8);
    }
#pragma unroll
    for (int it = 0; it < 2; ++it) {             // W1: 512 chunks
        const int i = it * 256 + tid;
        const int col = i >> 3, cb = i & 7;
        gl16(W1t + ch * 4096 + col * 64 + ((cb ^ (col & 7)) * 8), B1s + i * 8);
    }
#pragma unroll
    for (int it = 0; it < 2; ++it) {             // W2: 512 chunks
        const int i = it * 256 + tid;
        const int col = i >> 3, cb = i & 7;
        gl16(W2t + ch * 4096 + col * 64 + ((cb ^ (col & 7)) * 8), B2s + i * 8);
    }
    __syncthreads();

    // stage 1: z = relu(A @ W1 + b1)
    bf16x8 af[2][2];
#pragma unroll
    for (int rt = 0; rt < 2; ++rt)
#pragma unroll
        for (int kk = 0; kk < 2; ++kk) {
            const int row = wv * 32 + rt * 16 + colL;
            const int blk = kk * 4 + lr;
            af[rt][kk] = *reinterpret_cast<const bf16x8*>(As + row * 64 + ((blk ^ (row & 7)) * 8));
        }
    f32x4 acc[2][4];
#pragma unroll
    for (int rt = 0; rt < 2; ++rt)
#pragma unroll
        for (int ct = 0; ct < 4; ++ct) acc[rt][ct] = (f32x4){0.f, 0.f, 0.f, 0.f};
#pragma unroll
    for (int ct = 0; ct < 4; ++ct)
#pragma unroll
        for (int kk = 0; kk < 2; ++kk) {
            const int col = ct * 16 + colL;
            const int blk = kk * 4 + lr;
            const bf16x8 bf = *reinterpret_cast<const bf16x8*>(B1s + col * 64 + ((blk ^ (col & 7)) * 8));
            acc[0][ct] = __builtin_amdgcn_mfma_f32_16x16x32_bf16(af[0][kk], bf, acc[0][ct], 0, 0, 0);
            acc[1][ct] = __builtin_amdgcn_mfma_f32_16x16x32_bf16(af[1][kk], bf, acc[1][ct], 0, 0, 0);
        }

    ushort* Zw = As + wv * 2048;    // wave-private 32x64 (overlays this wave's As rows)
#pragma unroll
    for (int rt = 0; rt < 2; ++rt)
#pragma unroll
        for (int ct = 0; ct < 4; ++ct) {
            const float bvv = b1[ch * 64 + ct * 16 + colL];
#pragma unroll
            for (int r = 0; r < 4; ++r) {
                const float v = fmaxf(acc[rt][ct][r] + bvv, 0.f);
                const int zrow = rt * 16 + lr * 4 + r;
                const int zcol = ct * 16 + colL;
                Zw[zrow * 64 + (((zcol >> 3) ^ (zrow & 7)) * 8) + (zcol & 7)] = f2b(v);
            }
        }

    // stage 2: out = elu(z @ W2 + b2)
    bf16x8 zf[2][2];
#pragma unroll
    for (int rt = 0; rt < 2; ++rt)
#pragma unroll
        for (int kk = 0; kk < 2; ++kk) {
            const int zrow = rt * 16 + colL;
            const int blk = kk * 4 + lr;
            zf[rt][kk] = *reinterpret_cast<const bf16x8*>(Zw + zrow * 64 + ((blk ^ (zrow & 7)) * 8));
        }
#pragma unroll
    for (int rt = 0; rt < 2; ++rt)
#pragma unroll
        for (int ct = 0; ct < 4; ++ct) acc[rt][ct] = (f32x4){0.f, 0.f, 0.f, 0.f};
#pragma unroll
    for (int ct = 0; ct < 4; ++ct)
#pragma unroll
        for (int kk = 0; kk < 2; ++kk) {
            const int col = ct * 16 + colL;
            const int blk = kk * 4 + lr;
            const bf16x8 bf = *reinterpret_cast<const bf16x8*>(B2s + col * 64 + ((blk ^ (col & 7)) * 8));
            acc[0][ct] = __builtin_amdgcn_mfma_f32_16x16x32_bf16(zf[0][kk], bf, acc[0][ct], 0, 0, 0);
            acc[1][ct] = __builtin_amdgcn_mfma_f32_16x16x32_bf16(zf[1][kk], bf, acc[1][ct], 0, 0, 0);
        }

    float s = 0.f, ss = 0.f;
#pragma unroll
    for (int rt = 0; rt < 2; ++rt)
#pragma unroll
        for (int ct = 0; ct < 4; ++ct) {
            const float bvv = b2[ch * 64 + ct * 16 + colL];
#pragma unroll
            for (int r = 0; r < 4; ++r) {
                const float v = eluf(acc[rt][ct][r] + bvv);
                Zw[(rt * 16 + lr * 4 + r) * 64 + ct * 16 + colL] = f2b(v);
                const int row = r0 + wv * 32 + rt * 16 + lr * 4 + r;
                if (row < n) { s += v; ss += v * v; }
            }
        }
#pragma unroll
    for (int j = 0; j < 4; ++j) {
        const int idx = j * 64 + lane;
        const int lrow = idx >> 3, c8 = idx & 7;
        const int grow = r0 + wv * 32 + lrow;
        if (grow < n)
            *reinterpret_cast<bf16x8*>(Cb + (size_t)grow * 256 + ch * 64 + c8 * 8) =
                *reinterpret_cast<const bf16x8*>(Zw + lrow * 64 + c8 * 8);
    }

    double ds = (double)s, dss = (double)ss;
    for (int o = 32; o; o >>= 1) { ds += __shfl_down(ds, o, 64); dss += __shfl_down(dss, o, 64); }
    if (lane == 0) { unsafeAtomicAdd(&stats[0], ds); unsafeAtomicAdd(&stats[1], dss); }
}

// ---------------------------------------------------------------------------
// ONE prep kernel: x->bf16 + all 5 weight transposes
// ---------------------------------------------------------------------------
__global__ void prep_kernel(const float* __restrict__ x,
                            const float* __restrict__ lin1W,
                            const float* __restrict__ g0W1, const float* __restrict__ g0W2,
                            const float* __restrict__ g1W1, const float* __restrict__ g1W2,
                            ushort* __restrict__ xb,
                            ushort* __restrict__ Wt1,
                            ushort* __restrict__ Wt0a, ushort* __restrict__ Wt0b,
                            ushort* __restrict__ Wtbd1, ushort* __restrict__ Wtbd2,
                            int n32)
{
    const int i = blockIdx.x * 256 + threadIdx.x;
    if (i < n32) {
        const float4 v = reinterpret_cast<const float4*>(x)[i];
        reinterpret_cast<ushort4*>(xb)[i] = make_ushort4(f2b(v.x), f2b(v.y), f2b(v.z), f2b(v.w));
        return;
    }
    int j = i - n32;
    if (j < 32768) {                         // Wt1 [256][128]
        const int c = j >> 7, k = j & 127;
        Wt1[j] = f2b(lin1W[(size_t)k * 256 + c]);
    } else if (j < 98304) {                  // Wt0a [256][256]
        j -= 32768;
        const int c = j >> 8, k = j & 255;
        Wt0a[j] = f2b(g0W1[(size_t)k * 256 + c]);
    } else if (j < 163840) {                 // Wt0b
        j -= 98304;
        const int c = j >> 8, k = j & 255;
        Wt0b[j] = f2b(g0W2[(size_t)k * 256 + c]);
    } else if (j < 180224) {                 // Wtbd1 [4][64][64]
        j -= 163840;
        const int ch = j >> 12, r = j & 4095, cw = r >> 6, k = r & 63;
        Wtbd1[j] = f2b(g1W1[ch * 4096 + k * 64 + cw]);
    } else if (j < 196608) {                 // Wtbd2
        j -= 180224;
        const int ch = j >> 12, r = j & 4095, cw = r >> 6, k = r & 63;
        Wtbd2[j] = f2b(g1W2[ch * 4096 + k * 64 + cw]);
    }
}

// ---------------------------------------------------------------------------
// CSR construction
// ---------------------------------------------------------------------------
__global__ void count_kernel(const int* __restrict__ dst, int* __restrict__ cnt, int nE)
{
    const int e = blockIdx.x * 256 + threadIdx.x;
    if (e < nE) atomicAdd(&cnt[dst[e]], 1);
}

__global__ __launch_bounds__(1024)
void scan_kernel(const int* __restrict__ cnt, int* __restrict__ rowptr,
                 int* __restrict__ cursor, int n)
{
    __shared__ int part[1024];
    const int t = threadIdx.x;
    const int chunk = (n + 1023) / 1024;
    const int i0 = min(t * chunk, n), i1 = min(i0 + chunk, n);
    int s = 0;
    for (int i = i0; i < i1; ++i) s += cnt[i];
    part[t] = s;
    __syncthreads();
    for (int o = 1; o < 1024; o <<= 1) {
        const int v = (t >= o) ? part[t - o] : 0;
        __syncthreads();
        part[t] += v;
        __syncthreads();
    }
    int base = (t == 0) ? 0 : part[t - 1];
    for (int i = i0; i < i1; ++i) { rowptr[i] = base; cursor[i] = base; base += cnt[i]; }
    if (t == 1023) rowptr[n] = part[1023];
}

__global__ void fill_kernel(const int* __restrict__ src, const int* __restrict__ dst,
                            int* __restrict__ cursor, int* __restrict__ es, int nE)
{
    const int e = blockIdx.x * 256 + threadIdx.x;
    if (e >= nE) return;
    const int p = atomicAdd(&cursor[dst[e]], 1);
    es[p] = src[e];
}

// ---------------------------------------------------------------------------
// Gathers (bf16 rows, one wave per node)
// ---------------------------------------------------------------------------
__global__ __launch_bounds__(256)
void gather0b_kernel(const ushort* __restrict__ hb, const int* __restrict__ rowptr,
                     const int* __restrict__ es, const float* __restrict__ vn_emb,
                     ushort* __restrict__ ob, int n)
{
    const int node = blockIdx.x * 4 + (threadIdx.x >> 6);
    if (node >= n) return;
    const int lane = threadIdx.x & 63;
    const ushort4* H4 = reinterpret_cast<const ushort4*>(hb);
    const ushort4 o = H4[(size_t)node * 64 + lane];
    const int b = rowptr[node], e = rowptr[node + 1];
    const float4 vn = reinterpret_cast<const float4*>(vn_emb)[lane];
    const float cv = (float)(2 + (e - b));
    float a0 = fmaf(cv, vn.x, 2.f * b2f(o.x));
    float a1 = fmaf(cv, vn.y, 2.f * b2f(o.y));
    float a2 = fmaf(cv, vn.z, 2.f * b2f(o.z));
    float a3 = fmaf(cv, vn.w, 2.f * b2f(o.w));
    int i = b;
    for (; i + 2 <= e; i += 2) {
        const ushort4 v0 = H4[(size_t)es[i] * 64 + lane];
        const ushort4 v1 = H4[(size_t)es[i + 1] * 64 + lane];
        a0 += b2f(v0.x) + b2f(v1.x);
        a1 += b2f(v0.y) + b2f(v1.y);
        a2 += b2f(v0.z) + b2f(v1.z);
        a3 += b2f(v0.w) + b2f(v1.w);
    }
    for (; i < e; ++i) {
        const ushort4 v = H4[(size_t)es[i] * 64 + lane];
        a0 += b2f(v.x); a1 += b2f(v.y); a2 += b2f(v.z); a3 += b2f(v.w);
    }
    reinterpret_cast<ushort4*>(ob)[(size_t)node * 64 + lane] =
        make_ushort4(f2b(a0), f2b(a1), f2b(a2), f2b(a3));
}

__global__ __launch_bounds__(256)
void gatherb_kernel(const ushort* __restrict__ tb, const int* __restrict__ rowptr,
                    const int* __restrict__ es, ushort* __restrict__ ob, int n)
{
    const int node = blockIdx.x * 4 + (threadIdx.x >> 6);
    if (node >= n) return;
    const int lane = threadIdx.x & 63;
    const ushort4* H4 = reinterpret_cast<const ushort4*>(tb);
    const ushort4 o = H4[(size_t)node * 64 + lane];
    float a0 = 2.f * b2f(o.x), a1 = 2.f * b2f(o.y), a2 = 2.f * b2f(o.z), a3 = 2.f * b2f(o.w);
    const int b = rowptr[node], e = rowptr[node + 1];
    int i = b;
    for (; i + 2 <= e; i += 2) {
        const ushort4 v0 = H4[(size_t)es[i] * 64 + lane];
        const ushort4 v1 = H4[(size_t)es[i + 1] * 64 + lane];
        a0 += b2f(v0.x) + b2f(v1.x);
        a1 += b2f(v0.y) + b2f(v1.y);
        a2 += b2f(v0.z) + b2f(v1.z);
        a3 += b2f(v0.w) + b2f(v1.w);
    }
    for (; i < e; ++i) {
        const ushort4 v = H4[(size_t)es[i] * 64 + lane];
        a0 += b2f(v.x); a1 += b2f(v.y); a2 += b2f(v.z); a3 += b2f(v.w);
    }
    reinterpret_cast<ushort4*>(ob)[(size_t)node * 64 + lane] =
        make_ushort4(f2b(a0), f2b(a1), f2b(a2), f2b(a3));
}

// Graph boundaries (batch is sorted)
__global__ void offsets_kernel(const int* __restrict__ batch, int n, int* __restrict__ off)
{
    const int g = blockIdx.x * blockDim.x + threadIdx.x;
    if (g > NG) return;
    int lo = 0, hi = n;
    while (lo < hi) { const int mid = (lo + hi) >> 1; if (batch[mid] < g) lo = mid + 1; else hi = mid; }
    off[g] = lo;
}

// LN normalize (finalize inlined): gr slice f32 + bf16(z + vn2[batch]) for layer 1
__global__ void norm0f_kernel(const ushort* __restrict__ zb, const double* __restrict__ sacc,
                              const float* __restrict__ vn2, const int* __restrict__ batch,
                              float* __restrict__ grs, ushort* __restrict__ tb, int n, double M)
{
    const size_t i4 = (size_t)blockIdx.x * blockDim.x + threadIdx.x;
    if (i4 >= (size_t)n * 64) return;
    const double mean = sacc[0] / M;
    double var = sacc[1] / M - mean * mean;
    if (var < 0.0) var = 0.0;
    const float m = (float)mean, rs = (float)(1.0 / sqrt(var + (double)LN_EPS));
    const int row = (int)(i4 >> 6), c4 = (int)(i4 & 63);
    const ushort4 u = reinterpret_cast<const ushort4*>(zb)[i4];
    const float z0 = (b2f(u.x) - m) * rs, z1 = (b2f(u.y) - m) * rs,
                z2 = (b2f(u.z) - m) * rs, z3 = (b2f(u.w) - m) * rs;
    reinterpret_cast<float4*>(grs)[(size_t)row * 192 + c4] = make_float4(z0, z1, z2, z3);
    const int g = batch[row];
    const float4 e = reinterpret_cast<const float4*>(vn2 + (size_t)g * 256)[c4];
    reinterpret_cast<ushort4*>(tb)[i4] =
        make_ushort4(f2b(z0 + e.x), f2b(z1 + e.y), f2b(z2 + e.z), f2b(z3 + e.w));
}

__global__ void norm1b_kernel(const ushort* __restrict__ zb, const double* __restrict__ sacc,
                              float* __restrict__ grs, int n, double M)
{
    const size_t i4 = (size_t)blockIdx.x * blockDim.x + threadIdx.x;
    if (i4 >= (size_t)n * 64) return;
    const double mean = sacc[0] / M;
    double var = sacc[1] / M - mean * mean;
    if (var < 0.0) var = 0.0;
    const float m = (float)mean, rs = (float)(1.0 / sqrt(var + (double)LN_EPS));
    const int row = (int)(i4 >> 6), c4 = (int)(i4 & 63);
    const ushort4 u = reinterpret_cast<const ushort4*>(zb)[i4];
    reinterpret_cast<float4*>(grs)[(size_t)row * 192 + c4] =
        make_float4((b2f(u.x) - m) * rs, (b2f(u.y) - m) * rs,
                    (b2f(u.z) - m) * rs, (b2f(u.w) - m) * rs);
}

// FUSED virtual-node update: vt -> vn1 -> vn2 in one kernel (block = graph)
__global__ __launch_bounds__(256)
void vnall_kernel(const float* __restrict__ gr, const int* __restrict__ off,
                  const float* __restrict__ vn_emb,
                  const float* __restrict__ W1, const float* __restrict__ bb1,
                  const float* __restrict__ W2, const float* __restrict__ bb2,
                  float* __restrict__ vn2)
{
    __shared__ float r1[256];
    __shared__ float r2[512];
    const int g = blockIdx.x, t = threadIdx.x;
    const int i0 = off[g], i1 = off[g + 1];
    float s = 0.f;
    for (int i = i0; i < i1; ++i) s += gr[(size_t)i * 768 + t];
    r1[t] = s + vn_emb[t];
    __syncthreads();
    float a0 = 0.f, a1 = 0.f;
    for (int k = 0; k < 256; ++k) {
        const float rv = r1[k];
        a0 = fmaf(rv, W1[(size_t)k * 512 + t], a0);
        a1 = fmaf(rv, W1[(size_t)k * 512 + 256 + t], a1);
    }
    r2[t]       = fmaxf((a0 + bb1[t]) * BNS, 0.f);
    r2[t + 256] = fmaxf((a1 + bb1[256 + t]) * BNS, 0.f);
    __syncthreads();
    float a = 0.f;
    for (int k = 0; k < 512; ++k) a = fmaf(r2[k], W2[(size_t)k * 256 + t], a);
    vn2[(size_t)g * 256 + t] = fmaxf((a + bb2[t]) * BNS, 0.f);
}

// segment max + mean over gr [n x 768] -> readb [NG x 1536] = [max | mean]
__global__ __launch_bounds__(256)
void pool_kernel(const float* __restrict__ gr, const int* __restrict__ off,
                 float* __restrict__ readb)
{
    const int g = blockIdx.x, t = threadIdx.x;
    const int i0 = off[g], i1 = off[g + 1];
    float m0 = -__builtin_inff(), m1 = m0, m2 = m0;
    float s0 = 0.f, s1 = 0.f, s2 = 0.f;
    for (int i = i0; i < i1; ++i) {
        const float* p = gr + (size_t)i * 768;
        const float v0 = p[t], v1 = p[t + 256], v2 = p[t + 512];
        m0 = fmaxf(m0, v0); m1 = fmaxf(m1, v1); m2 = fmaxf(m2, v2);
        s0 += v0; s1 += v1; s2 += v2;
    }
    const float inv = 1.f / fmaxf((float)(i1 - i0), 1.f);
    float* rb = readb + (size_t)g * 1536;
    rb[t] = m0; rb[t + 256] = m1; rb[t + 512] = m2;
    rb[768 + t] = s0 * inv; rb[768 + 256 + t] = s1 * inv; rb[768 + 512 + t] = s2 * inv;
}

// FUSED readout head
__global__ __launch_bounds__(256)
void outg2_kernel(const float* __restrict__ readb, const float* __restrict__ W,
                  const float* __restrict__ b,
                  const float* __restrict__ clsW, const float* __restrict__ clsb,
                  const float* __restrict__ dW, const float* __restrict__ db,
                  float* __restrict__ x5, float* __restrict__ logits, float* __restrict__ ssl)
{
    __shared__ float rows[8][1536];
    __shared__ float x5s[8][256];
    const int g0 = blockIdx.x * 8, t = threadIdx.x;
    for (int i = t; i < 8 * 1536; i += 256) rows[i / 1536][i % 1536] = readb[(size_t)g0 * 1536 + i];
    __syncthreads();
    float acc[8];
#pragma unroll
    for (int r = 0; r < 8; ++r) acc[r] = 0.f;
    for (int k = 0; k < 1536; ++k) {
        const float wv = W[(size_t)k * 256 + t];
#pragma unroll
        for (int r = 0; r < 8; ++r) acc[r] = fmaf(rows[r][k], wv, acc[r]);
    }
    const float bb = b[t];
#pragma unroll
    for (int r = 0; r < 8; ++r) {
        const float v = eluf(acc[r] + bb);
        x5[(size_t)(g0 + r) * 256 + t] = v;
        x5s[r][t] = v;
    }
    __syncthreads();

    const int grp = t >> 5, l32 = t & 31;
    float p0 = 0.f, p1 = 0.f;
    for (int c = l32; c < 256; c += 32) {
        const float v = x5s[grp][c];
        p0 = fmaf(v, clsW[c * 2], p0);
        p1 = fmaf(v, clsW[c * 2 + 1], p1);
    }
    float q0 = 0.f, q1 = 0.f, q2 = 0.f;
    for (int c = l32; c < 64; c += 32) {
        q0 = fmaf(x5s[grp][c],       dW[c],       q0);
        q1 = fmaf(x5s[grp][64 + c],  dW[64 + c],  q1);
        q2 = fmaf(x5s[grp][128 + c], dW[128 + c], q2);
    }
    for (int o = 16; o; o >>= 1) {
        p0 += __shfl_down(p0, o, 32); p1 += __shfl_down(p1, o, 32);
        q0 += __shfl_down(q0, o, 32); q1 += __shfl_down(q1, o, 32); q2 += __shfl_down(q2, o, 32);
    }
    if (l32 == 0) {
        const float z0 = p0 + clsb[0], z1 = p1 + clsb[1];
        const float m = fmaxf(z0, z1);
        const float lse = m + logf(expf(z0 - m) + expf(z1 - m));
        logits[(size_t)(g0 + grp) * 2 + 0] = z0 - lse;
        logits[(size_t)(g0 + grp) * 2 + 1] = z1 - lse;
        ssl[(size_t)(g0 + grp) * 3 + 0] = 0.05f + 0.35f / (1.f + expf(-(q0 + db[0])));
        ssl[(size_t)(g0 + grp) * 3 + 1] = 0.05f + 0.35f / (1.f + expf(-(q1 + db[1])));
        ssl[(size_t)(g0 + grp) * 3 + 2] = 0.05f + 0.35f / (1.f + expf(-(q2 + db[2])));
    }
}

// ---------------------------------------------------------------------------
extern "C" void kernel_launch(void* const* d_in, const int* in_sizes, int n_in,
                              void* d_out, int out_size, void* d_ws, size_t ws_size,
                              hipStream_t stream)
{
    const float* x      = (const float*)d_in[0];
    const int*   eidx   = (const int*)d_in[1];
    const int*   batch  = (const int*)d_in[2];
    const float* lin1_W = (const float*)d_in[3];
    const float* lin1_b = (const float*)d_in[4];
    const float* g0W1   = (const float*)d_in[5];
    const float* g0b1   = (const float*)d_in[6];
    const float* g0W2   = (const float*)d_in[7];
    const float* g0b2   = (const float*)d_in[8];
    const float* g1W1   = (const float*)d_in[9];
    const float* g1b1   = (const float*)d_in[10];
    const float* g1W2   = (const float*)d_in[11];
    const float* g1b2   = (const float*)d_in[12];
    const float* vn_emb = (const float*)d_in[13];
    const float* vnW1   = (const float*)d_in[14];
    const float* vnb1   = (const float*)d_in[15];
    const float* vnW2   = (const float*)d_in[16];
    const float* vnb2   = (const float*)d_in[17];
    const float* loW    = (const float*)d_in[18];
    const float* lob    = (const float*)d_in[19];
    const float* clsW   = (const float*)d_in[20];
    const float* clsb   = (const float*)d_in[21];
    const float* dhW    = (const float*)d_in[22];
    const float* dhb    = (const float*)d_in[23];

    const int N = in_sizes[2];        // 50000 nodes
    const int E = in_sizes[1] / 2;    // 800000 edges
    const int* esrc = eidx;
    const int* edst = eidx + E;

    float* out = (float*)d_out;
    float* out_logits = out;                                     // [NG,2]
    float* out_x5     = out + (size_t)NG * 2;                    // [NG,256]
    float* out_ssl    = out + (size_t)NG * 2 + (size_t)NG * 256; // [NG,3]

    // --- workspace carve (256B aligned; sacc+cnt adjacent for single memset) ---
    char* p = (char*)d_ws;
    auto carve = [&](size_t bytes) { char* r = p; p += (bytes + 255) & ~(size_t)255; return (void*)r; };
    double* sacc   = (double*)carve(4 * sizeof(double));            // [0..1]=L0, [2..3]=L1
    int*    cnt    = (int*)   carve((size_t)N * sizeof(int));
    int*    goff   = (int*)   carve((NG + 1) * sizeof(int));
    int*    rowptr = (int*)   carve((size_t)(N + 1) * sizeof(int));
    int*    cursor = (int*)   carve((size_t)N * sizeof(int));
    int*    es     = (int*)   carve((size_t)E * sizeof(int));
    float*  gr     = (float*) carve((size_t)N * 768 * sizeof(float)); // [gr0|gr1|gr2]
    ushort* xb     = (ushort*)carve((size_t)N * 128 * sizeof(ushort));
    ushort* B1     = (ushort*)carve((size_t)N * 256 * sizeof(ushort));
    ushort* B2     = (ushort*)carve((size_t)N * 256 * sizeof(ushort));
    ushort* B3     = (ushort*)carve((size_t)N * 256 * sizeof(ushort));
    ushort* Wt1    = (ushort*)carve(256 * 128 * sizeof(ushort));
    ushort* Wt0a   = (ushort*)carve(256 * 256 * sizeof(ushort));
    ushort* Wt0b   = (ushort*)carve(256 * 256 * sizeof(ushort));
    ushort* Wtbd1  = (ushort*)carve(16384 * sizeof(ushort));
    ushort* Wtbd2  = (ushort*)carve(16384 * sizeof(ushort));
    float*  vn2    = (float*) carve((size_t)NG * 256 * sizeof(float));
    float*  readb  = (float*) carve((size_t)NG * 1536 * sizeof(float));

    // one memset covers sacc (256B slot) + cnt
    hipMemsetAsync(sacc, 0, 256 + (size_t)N * sizeof(int), stream);

    const int mt = (N + 127) / 128;
    const int vecGrid = (N * 64 + 255) / 256;
    const int eGrid = (E + 255) / 256;
    const int gatherGrid = (N + 3) / 4;
    const int prepTotal = N * 32 + 196608;

    // ---- CSR build ----
    count_kernel<<<eGrid, 256, 0, stream>>>(edst, cnt, E);
    scan_kernel<<<1, 1024, 0, stream>>>(cnt, rowptr, cursor, N);
    fill_kernel<<<eGrid, 256, 0, stream>>>(esrc, edst, cursor, es, E);

    // ---- all weight/input prep in ONE kernel ----
    prep_kernel<<<(prepTotal + 255) / 256, 256, 0, stream>>>(
        x, lin1_W, g0W1, g0W2, g1W1, g1W2, xb, Wt1, Wt0a, Wt0b, Wtbd1, Wtbd2, N * 32);

    // h0 = elu(x @ lin1_W + b) -> B1 (bf16) + gr slice0 (f32)
    tgemm_kernel<2><<<mt, 512, 0, stream>>>(xb, 128, Wt1, lin1_b, B1, gr, N);
    offsets_kernel<<<3, 256, 0, stream>>>(batch, N, goff);

    // ---- virtual node update ----
    vnall_kernel<<<NG, 256, 0, stream>>>(gr, goff, vn_emb, vnW1, vnb1, vnW2, vnb2, vn2);

    // ---- layer 0 (gather + fused dense MLP) ----
    gather0b_kernel<<<gatherGrid, 256, 0, stream>>>(B1, rowptr, es, vn_emb, B2, N);
    mlp0_kernel<<<mt, 512, 0, stream>>>(B2, Wt0a, Wt0b, g0b1, g0b2, B3, N, sacc);
    norm0f_kernel<<<vecGrid, 256, 0, stream>>>(B3, sacc, vn2, batch, gr + 256, B1, N, (double)N * 256.0);

    // ---- layer 1 (gather + fused block-diagonal MLP) ----
    gatherb_kernel<<<gatherGrid, 256, 0, stream>>>(B1, rowptr, es, B2, N);
    bd2_kernel<<<dim3(mt, 4), 256, 0, stream>>>(B2, Wtbd1, Wtbd2, g1b1, g1b2, B3, N, sacc + 2);
    norm1b_kernel<<<vecGrid, 256, 0, stream>>>(B3, sacc + 2, gr + 512, N, (double)N * 256.0);

    // ---- readout (pool + fused head) ----
    pool_kernel<<<NG, 256, 0, stream>>>(gr, goff, readb);
    outg2_kernel<<<NG / 8, 256, 0, stream>>>(readb, loW, lob, clsW, clsb, dhW, dhb,
                                             out_x5, out_logits, out_ssl);
}

// Round 11
// 626.720 us; speedup vs baseline: 1.3784x; 1.3784x over previous
//
#include <hip/hip_runtime.h>

static constexpr int NG = 512;       // graphs
static constexpr float LN_EPS = 1e-5f;
static constexpr float BNS = 0.9999950000374997f; // rsqrt(1 + 1e-5) for BatchNorm eval

__device__ __forceinline__ float eluf(float v) { return v > 0.f ? v : expm1f(v); }

typedef __attribute__((ext_vector_type(8))) short bf16x8;
typedef __attribute__((ext_vector_type(4))) float f32x4;

__device__ __forceinline__ ushort f2b(float f) {   // f32 -> bf16 RNE
    union { float f; unsigned u; } v; v.f = f;
    const unsigned u = v.u;
    return (ushort)((u + 0x7FFFu + ((u >> 16) & 1u)) >> 16);
}
__device__ __forceinline__ float b2f(ushort b) {
    union { unsigned u; float f; } v; v.u = ((unsigned)b) << 16;
    return v.f;
}

// async global->LDS, 16B per lane. LDS dest lane-contiguous (linear).
__device__ __forceinline__ void gl16(const ushort* g, ushort* l) {
    __builtin_amdgcn_global_load_lds(
        (const __attribute__((address_space(1))) void*)g,
        (__attribute__((address_space(3))) void*)l, 16, 0, 0);
}

// ---------------------------------------------------------------------------
// lin1 MFMA GEMM: B1 = bf16(elu(x@W+b)).  BM=128,BN=256,BK=64,K=128.
// ---------------------------------------------------------------------------
template<int KSTEPS>
__global__ __launch_bounds__(512)
void tgemm_kernel(const ushort* __restrict__ Ab, int ldab,
                  const ushort* __restrict__ Wt,   // [256][K]
                  const float* __restrict__ bias,
                  ushort* __restrict__ Cb,
                  int n)
{
    __shared__ __align__(16) ushort sbuf[32768];   // 64 KB
    ushort* As = sbuf;          // 128*64
    ushort* Bs = sbuf + 8192;   // 256*64

    const int tid = threadIdx.x;
    const int lane = tid & 63;
    const int wv = tid >> 6;
    const int wr = wv >> 1, wc = wv & 1;
    const int r0 = blockIdx.x * 128;
    const int colL = lane & 15;
    const int lr = lane >> 4;

    f32x4 acc[2][8];
#pragma unroll
    for (int rt = 0; rt < 2; ++rt)
#pragma unroll
        for (int ct = 0; ct < 8; ++ct) acc[rt][ct] = (f32x4){0.f, 0.f, 0.f, 0.f};

    for (int ks = 0; ks < KSTEPS; ++ks) {
#pragma unroll
        for (int it = 0; it < 2; ++it) {           // A
            const int i = it * 512 + tid;
            const int row = i >> 3, cb = i & 7;
            const int rg = min(r0 + row, n - 1);
            gl16(Ab + (size_t)rg * ldab + ks * 64 + ((cb ^ (row & 7)) * 8), As + i * 8);
        }
#pragma unroll
        for (int it = 0; it < 4; ++it) {           // B
            const int i = it * 512 + tid;
            const int col = i >> 3, cb = i & 7;
            gl16(Wt + (size_t)col * (KSTEPS * 64) + ks * 64 + ((cb ^ (col & 7)) * 8), Bs + i * 8);
        }
        __syncthreads();

        bf16x8 af[2][2];
#pragma unroll
        for (int rt = 0; rt < 2; ++rt)
#pragma unroll
            for (int kk = 0; kk < 2; ++kk) {
                const int row = wr * 32 + rt * 16 + colL;
                const int blk = kk * 4 + lr;
                af[rt][kk] = *reinterpret_cast<const bf16x8*>(As + row * 64 + ((blk ^ (row & 7)) * 8));
            }
#pragma unroll
        for (int ct = 0; ct < 8; ++ct)
#pragma unroll
            for (int kk = 0; kk < 2; ++kk) {
                const int col = wc * 128 + ct * 16 + colL;
                const int blk = kk * 4 + lr;
                const bf16x8 bf = *reinterpret_cast<const bf16x8*>(Bs + col * 64 + ((blk ^ (col & 7)) * 8));
                acc[0][ct] = __builtin_amdgcn_mfma_f32_16x16x32_bf16(af[0][kk], bf, acc[0][ct], 0, 0, 0);
                acc[1][ct] = __builtin_amdgcn_mfma_f32_16x16x32_bf16(af[1][kk], bf, acc[1][ct], 0, 0, 0);
            }
        __syncthreads();
    }

    float bv[8];
#pragma unroll
    for (int ct = 0; ct < 8; ++ct) bv[ct] = bias[wc * 128 + ct * 16 + colL];

    ushort* eb = sbuf + wv * 4096;   // 32 rows x 128 cols
#pragma unroll
    for (int rt = 0; rt < 2; ++rt)
#pragma unroll
        for (int ct = 0; ct < 8; ++ct)
#pragma unroll
            for (int r = 0; r < 4; ++r) {
                const float v = eluf(acc[rt][ct][r] + bv[ct]);
                eb[(rt * 16 + lr * 4 + r) * 128 + ct * 16 + colL] = f2b(v);
            }
#pragma unroll
    for (int j = 0; j < 8; ++j) {
        const int idx = j * 64 + lane;
        const int lrow = idx >> 4, c8 = idx & 15;
        const int grow = r0 + wr * 32 + lrow;
        if (grow < n)
            *reinterpret_cast<bf16x8*>(Cb + (size_t)grow * 256 + wc * 128 + c8 * 8) =
                *reinterpret_cast<const bf16x8*>(eb + lrow * 128 + c8 * 8);
    }
}

// ---------------------------------------------------------------------------
// FUSED dense GIN MLP (layer 0). Stats -> 64 atomic buckets (blockIdx&63).
// ---------------------------------------------------------------------------
__global__ __launch_bounds__(512)
void mlp0_kernel(const ushort* __restrict__ Ab,    // [n][256]
                 const ushort* __restrict__ W1t,   // [256][256]
                 const ushort* __restrict__ W2t,
                 const float* __restrict__ b1, const float* __restrict__ b2,
                 ushort* __restrict__ Cb,
                 int n, double* __restrict__ stats)
{
    __shared__ __align__(16) ushort As[8192];
    __shared__ __align__(16) ushort Bs[16384];
    __shared__ __align__(16) ushort Z[32768];

    const int tid = threadIdx.x;
    const int lane = tid & 63;
    const int wv = tid >> 6;
    const int wr = wv >> 1, wc = wv & 1;
    const int r0 = blockIdx.x * 128;
    const int colL = lane & 15;
    const int lr = lane >> 4;

    f32x4 acc[2][8];
#pragma unroll
    for (int rt = 0; rt < 2; ++rt)
#pragma unroll
        for (int ct = 0; ct < 8; ++ct) acc[rt][ct] = (f32x4){0.f, 0.f, 0.f, 0.f};

    // ---- stage 1: z = relu(A @ W1 + b1) ----
    for (int ks = 0; ks < 4; ++ks) {
#pragma unroll
        for (int it = 0; it < 2; ++it) {
            const int i = it * 512 + tid;
            const int row = i >> 3, cb = i & 7;
            const int rg = min(r0 + row, n - 1);
            gl16(Ab + (size_t)rg * 256 + ks * 64 + ((cb ^ (row & 7)) * 8), As + i * 8);
        }
#pragma unroll
        for (int it = 0; it < 4; ++it) {
            const int i = it * 512 + tid;
            const int col = i >> 3, cb = i & 7;
            gl16(W1t + (size_t)col * 256 + ks * 64 + ((cb ^ (col & 7)) * 8), Bs + i * 8);
        }
        __syncthreads();
        bf16x8 af[2][2];
#pragma unroll
        for (int rt = 0; rt < 2; ++rt)
#pragma unroll
            for (int kk = 0; kk < 2; ++kk) {
                const int row = wr * 32 + rt * 16 + colL;
                const int blk = kk * 4 + lr;
                af[rt][kk] = *reinterpret_cast<const bf16x8*>(As + row * 64 + ((blk ^ (row & 7)) * 8));
            }
#pragma unroll
        for (int ct = 0; ct < 8; ++ct)
#pragma unroll
            for (int kk = 0; kk < 2; ++kk) {
                const int col = wc * 128 + ct * 16 + colL;
                const int blk = kk * 4 + lr;
                const bf16x8 bf = *reinterpret_cast<const bf16x8*>(Bs + col * 64 + ((blk ^ (col & 7)) * 8));
                acc[0][ct] = __builtin_amdgcn_mfma_f32_16x16x32_bf16(af[0][kk], bf, acc[0][ct], 0, 0, 0);
                acc[1][ct] = __builtin_amdgcn_mfma_f32_16x16x32_bf16(af[1][kk], bf, acc[1][ct], 0, 0, 0);
            }
        __syncthreads();
    }
#pragma unroll
    for (int ct = 0; ct < 8; ++ct) {
        const float bvv = b1[wc * 128 + ct * 16 + colL];
#pragma unroll
        for (int rt = 0; rt < 2; ++rt)
#pragma unroll
            for (int r = 0; r < 4; ++r) {
                const float v = fmaxf(acc[rt][ct][r] + bvv, 0.f);
                const int zrow = wr * 32 + rt * 16 + lr * 4 + r;
                const int zcol = wc * 128 + ct * 16 + colL;
                const int chunk = zcol >> 3;
                const int sw = (chunk & 24) | ((chunk & 7) ^ (zrow & 7));
                Z[zrow * 256 + sw * 8 + (zcol & 7)] = f2b(v);
            }
    }
    __syncthreads();

    // ---- stage 2: out = elu(z @ W2 + b2) ----
#pragma unroll
    for (int rt = 0; rt < 2; ++rt)
#pragma unroll
        for (int ct = 0; ct < 8; ++ct) acc[rt][ct] = (f32x4){0.f, 0.f, 0.f, 0.f};

    for (int ks = 0; ks < 4; ++ks) {
#pragma unroll
        for (int it = 0; it < 4; ++it) {
            const int i = it * 512 + tid;
            const int col = i >> 3, cb = i & 7;
            gl16(W2t + (size_t)col * 256 + ks * 64 + ((cb ^ (col & 7)) * 8), Bs + i * 8);
        }
        __syncthreads();
        bf16x8 zf[2][2];
#pragma unroll
        for (int rt = 0; rt < 2; ++rt)
#pragma unroll
            for (int kk = 0; kk < 2; ++kk) {
                const int zrow = wr * 32 + rt * 16 + colL;
                const int chunk = ks * 8 + kk * 4 + lr;
                const int sw = (chunk & 24) | ((chunk & 7) ^ (zrow & 7));
                zf[rt][kk] = *reinterpret_cast<const bf16x8*>(Z + zrow * 256 + sw * 8);
            }
#pragma unroll
        for (int ct = 0; ct < 8; ++ct)
#pragma unroll
            for (int kk = 0; kk < 2; ++kk) {
                const int col = wc * 128 + ct * 16 + colL;
                const int blk = kk * 4 + lr;
                const bf16x8 bf = *reinterpret_cast<const bf16x8*>(Bs + col * 64 + ((blk ^ (col & 7)) * 8));
                acc[0][ct] = __builtin_amdgcn_mfma_f32_16x16x32_bf16(zf[0][kk], bf, acc[0][ct], 0, 0, 0);
                acc[1][ct] = __builtin_amdgcn_mfma_f32_16x16x32_bf16(zf[1][kk], bf, acc[1][ct], 0, 0, 0);
            }
        __syncthreads();
    }

    float bv[8];
#pragma unroll
    for (int ct = 0; ct < 8; ++ct) bv[ct] = b2[wc * 128 + ct * 16 + colL];
    ushort* eb = Z + wv * 4096;
    float s = 0.f, ss = 0.f;
#pragma unroll
    for (int rt = 0; rt < 2; ++rt)
#pragma unroll
        for (int ct = 0; ct < 8; ++ct)
#pragma unroll
            for (int r = 0; r < 4; ++r) {
                const float v = eluf(acc[rt][ct][r] + bv[ct]);
                eb[(rt * 16 + lr * 4 + r) * 128 + ct * 16 + colL] = f2b(v);
                const int row = r0 + wr * 32 + rt * 16 + lr * 4 + r;
                if (row < n) { s += v; ss += v * v; }
            }
#pragma unroll
    for (int j = 0; j < 8; ++j) {
        const int idx = j * 64 + lane;
        const int lrow = idx >> 4, c8 = idx & 15;
        const int grow = r0 + wr * 32 + lrow;
        if (grow < n)
            *reinterpret_cast<bf16x8*>(Cb + (size_t)grow * 256 + wc * 128 + c8 * 8) =
                *reinterpret_cast<const bf16x8*>(eb + lrow * 128 + c8 * 8);
    }
    double ds = (double)s, dss = (double)ss;
    for (int o = 32; o; o >>= 1) { ds += __shfl_down(ds, o, 64); dss += __shfl_down(dss, o, 64); }
    if (lane == 0) {
        const int bkt = (blockIdx.x & 63) * 2;
        unsafeAtomicAdd(&stats[bkt], ds); unsafeAtomicAdd(&stats[bkt + 1], dss);
    }
}

// ---------------------------------------------------------------------------
// FUSED block-diagonal GIN MLP (layer 1). Bucketed stats.
// ---------------------------------------------------------------------------
__global__ __launch_bounds__(256)
void bd2_kernel(const ushort* __restrict__ Ab,    // [n][256]
                const ushort* __restrict__ W1t,   // [4][64 col][64 k]
                const ushort* __restrict__ W2t,
                const float* __restrict__ b1, const float* __restrict__ b2,
                ushort* __restrict__ Cb,
                int n, double* __restrict__ stats)
{
    __shared__ __align__(16) ushort As[8192];
    __shared__ __align__(16) ushort B1s[4096];
    __shared__ __align__(16) ushort B2s[4096];

    const int tid = threadIdx.x;
    const int lane = tid & 63;
    const int wv = tid >> 6;
    const int ch = blockIdx.y;
    const int r0 = blockIdx.x * 128;
    const int colL = lane & 15;
    const int lr = lane >> 4;

#pragma unroll
    for (int it = 0; it < 4; ++it) {             // A
        const int i = it * 256 + tid;
        const int row = i >> 3, cb = i & 7;
        const int rg = min(r0 + row, n - 1);
        gl16(Ab + (size_t)rg * 256 + ch * 64 + ((cb ^ (row & 7)) * 8), As + i * 8);
    }
#pragma unroll
    for (int it = 0; it < 2; ++it) {             // W1
        const int i = it * 256 + tid;
        const int col = i >> 3, cb = i & 7;
        gl16(W1t + ch * 4096 + col * 64 + ((cb ^ (col & 7)) * 8), B1s + i * 8);
    }
#pragma unroll
    for (int it = 0; it < 2; ++it) {             // W2
        const int i = it * 256 + tid;
        const int col = i >> 3, cb = i & 7;
        gl16(W2t + ch * 4096 + col * 64 + ((cb ^ (col & 7)) * 8), B2s + i * 8);
    }
    __syncthreads();

    bf16x8 af[2][2];
#pragma unroll
    for (int rt = 0; rt < 2; ++rt)
#pragma unroll
        for (int kk = 0; kk < 2; ++kk) {
            const int row = wv * 32 + rt * 16 + colL;
            const int blk = kk * 4 + lr;
            af[rt][kk] = *reinterpret_cast<const bf16x8*>(As + row * 64 + ((blk ^ (row & 7)) * 8));
        }
    f32x4 acc[2][4];
#pragma unroll
    for (int rt = 0; rt < 2; ++rt)
#pragma unroll
        for (int ct = 0; ct < 4; ++ct) acc[rt][ct] = (f32x4){0.f, 0.f, 0.f, 0.f};
#pragma unroll
    for (int ct = 0; ct < 4; ++ct)
#pragma unroll
        for (int kk = 0; kk < 2; ++kk) {
            const int col = ct * 16 + colL;
            const int blk = kk * 4 + lr;
            const bf16x8 bf = *reinterpret_cast<const bf16x8*>(B1s + col * 64 + ((blk ^ (col & 7)) * 8));
            acc[0][ct] = __builtin_amdgcn_mfma_f32_16x16x32_bf16(af[0][kk], bf, acc[0][ct], 0, 0, 0);
            acc[1][ct] = __builtin_amdgcn_mfma_f32_16x16x32_bf16(af[1][kk], bf, acc[1][ct], 0, 0, 0);
        }

    ushort* Zw = As + wv * 2048;    // wave-private 32x64
#pragma unroll
    for (int rt = 0; rt < 2; ++rt)
#pragma unroll
        for (int ct = 0; ct < 4; ++ct) {
            const float bvv = b1[ch * 64 + ct * 16 + colL];
#pragma unroll
            for (int r = 0; r < 4; ++r) {
                const float v = fmaxf(acc[rt][ct][r] + bvv, 0.f);
                const int zrow = rt * 16 + lr * 4 + r;
                const int zcol = ct * 16 + colL;
                Zw[zrow * 64 + (((zcol >> 3) ^ (zrow & 7)) * 8) + (zcol & 7)] = f2b(v);
            }
        }

    bf16x8 zf[2][2];
#pragma unroll
    for (int rt = 0; rt < 2; ++rt)
#pragma unroll
        for (int kk = 0; kk < 2; ++kk) {
            const int zrow = rt * 16 + colL;
            const int blk = kk * 4 + lr;
            zf[rt][kk] = *reinterpret_cast<const bf16x8*>(Zw + zrow * 64 + ((blk ^ (zrow & 7)) * 8));
        }
#pragma unroll
    for (int rt = 0; rt < 2; ++rt)
#pragma unroll
        for (int ct = 0; ct < 4; ++ct) acc[rt][ct] = (f32x4){0.f, 0.f, 0.f, 0.f};
#pragma unroll
    for (int ct = 0; ct < 4; ++ct)
#pragma unroll
        for (int kk = 0; kk < 2; ++kk) {
            const int col = ct * 16 + colL;
            const int blk = kk * 4 + lr;
            const bf16x8 bf = *reinterpret_cast<const bf16x8*>(B2s + col * 64 + ((blk ^ (col & 7)) * 8));
            acc[0][ct] = __builtin_amdgcn_mfma_f32_16x16x32_bf16(zf[0][kk], bf, acc[0][ct], 0, 0, 0);
            acc[1][ct] = __builtin_amdgcn_mfma_f32_16x16x32_bf16(zf[1][kk], bf, acc[1][ct], 0, 0, 0);
        }

    float s = 0.f, ss = 0.f;
#pragma unroll
    for (int rt = 0; rt < 2; ++rt)
#pragma unroll
        for (int ct = 0; ct < 4; ++ct) {
            const float bvv = b2[ch * 64 + ct * 16 + colL];
#pragma unroll
            for (int r = 0; r < 4; ++r) {
                const float v = eluf(acc[rt][ct][r] + bvv);
                Zw[(rt * 16 + lr * 4 + r) * 64 + ct * 16 + colL] = f2b(v);
                const int row = r0 + wv * 32 + rt * 16 + lr * 4 + r;
                if (row < n) { s += v; ss += v * v; }
            }
        }
#pragma unroll
    for (int j = 0; j < 4; ++j) {
        const int idx = j * 64 + lane;
        const int lrow = idx >> 3, c8 = idx & 7;
        const int grow = r0 + wv * 32 + lrow;
        if (grow < n)
            *reinterpret_cast<bf16x8*>(Cb + (size_t)grow * 256 + ch * 64 + c8 * 8) =
                *reinterpret_cast<const bf16x8*>(Zw + lrow * 64 + c8 * 8);
    }

    double ds = (double)s, dss = (double)ss;
    for (int o = 32; o; o >>= 1) { ds += __shfl_down(ds, o, 64); dss += __shfl_down(dss, o, 64); }
    if (lane == 0) {
        const int bkt = ((blockIdx.x + blockIdx.y * 16) & 63) * 2;
        unsafeAtomicAdd(&stats[bkt], ds); unsafeAtomicAdd(&stats[bkt + 1], dss);
    }
}

// reduce 64 stat buckets -> sfin {mean, rsqrt}
__global__ __launch_bounds__(64)
void finalize_kernel(const double* __restrict__ sacc, float* __restrict__ sfin, double M)
{
    const int t = threadIdx.x;
    double s = sacc[t * 2], ss = sacc[t * 2 + 1];
    for (int o = 32; o; o >>= 1) { s += __shfl_down(s, o, 64); ss += __shfl_down(ss, o, 64); }
    if (t == 0) {
        const double mean = s / M;
        double var = ss / M - mean * mean;
        if (var < 0.0) var = 0.0;
        sfin[0] = (float)mean;
        sfin[1] = (float)(1.0 / sqrt(var + (double)LN_EPS));
    }
}

// ---------------------------------------------------------------------------
// ONE prep kernel: x->bf16 + all 5 weight transposes
// ---------------------------------------------------------------------------
__global__ void prep_kernel(const float* __restrict__ x,
                            const float* __restrict__ lin1W,
                            const float* __restrict__ g0W1, const float* __restrict__ g0W2,
                            const float* __restrict__ g1W1, const float* __restrict__ g1W2,
                            ushort* __restrict__ xb,
                            ushort* __restrict__ Wt1,
                            ushort* __restrict__ Wt0a, ushort* __restrict__ Wt0b,
                            ushort* __restrict__ Wtbd1, ushort* __restrict__ Wtbd2,
                            int n32)
{
    const int i = blockIdx.x * 256 + threadIdx.x;
    if (i < n32) {
        const float4 v = reinterpret_cast<const float4*>(x)[i];
        reinterpret_cast<ushort4*>(xb)[i] = make_ushort4(f2b(v.x), f2b(v.y), f2b(v.z), f2b(v.w));
        return;
    }
    int j = i - n32;
    if (j < 32768) {                         // Wt1 [256][128]
        const int c = j >> 7, k = j & 127;
        Wt1[j] = f2b(lin1W[(size_t)k * 256 + c]);
    } else if (j < 98304) {                  // Wt0a [256][256]
        j -= 32768;
        const int c = j >> 8, k = j & 255;
        Wt0a[j] = f2b(g0W1[(size_t)k * 256 + c]);
    } else if (j < 163840) {                 // Wt0b
        j -= 98304;
        const int c = j >> 8, k = j & 255;
        Wt0b[j] = f2b(g0W2[(size_t)k * 256 + c]);
    } else if (j < 180224) {                 // Wtbd1 [4][64][64]
        j -= 163840;
        const int ch = j >> 12, r = j & 4095, cw = r >> 6, k = r & 63;
        Wtbd1[j] = f2b(g1W1[ch * 4096 + k * 64 + cw]);
    } else if (j < 196608) {                 // Wtbd2
        j -= 180224;
        const int ch = j >> 12, r = j & 4095, cw = r >> 6, k = r & 63;
        Wtbd2[j] = f2b(g1W2[ch * 4096 + k * 64 + cw]);
    }
}

// ---------------------------------------------------------------------------
// CSR construction
// ---------------------------------------------------------------------------
__global__ void count_kernel(const int* __restrict__ dst, int* __restrict__ cnt, int nE)
{
    const int e = blockIdx.x * 256 + threadIdx.x;
    if (e < nE) atomicAdd(&cnt[dst[e]], 1);
}

__global__ __launch_bounds__(1024)
void scan_kernel(const int* __restrict__ cnt, int* __restrict__ rowptr,
                 int* __restrict__ cursor, int n)
{
    __shared__ int part[1024];
    const int t = threadIdx.x;
    const int chunk = (n + 1023) / 1024;
    const int i0 = min(t * chunk, n), i1 = min(i0 + chunk, n);
    int s = 0;
    for (int i = i0; i < i1; ++i) s += cnt[i];
    part[t] = s;
    __syncthreads();
    for (int o = 1; o < 1024; o <<= 1) {
        const int v = (t >= o) ? part[t - o] : 0;
        __syncthreads();
        part[t] += v;
        __syncthreads();
    }
    int base = (t == 0) ? 0 : part[t - 1];
    for (int i = i0; i < i1; ++i) { rowptr[i] = base; cursor[i] = base; base += cnt[i]; }
    if (t == 1023) rowptr[n] = part[1023];
}

__global__ void fill_kernel(const int* __restrict__ src, const int* __restrict__ dst,
                            int* __restrict__ cursor, int* __restrict__ es, int nE)
{
    const int e = blockIdx.x * 256 + threadIdx.x;
    if (e >= nE) return;
    const int p = atomicAdd(&cursor[dst[e]], 1);
    es[p] = src[e];
}

// ---------------------------------------------------------------------------
// Gathers (bf16 rows, one wave per node)
// ---------------------------------------------------------------------------
__global__ __launch_bounds__(256)
void gather0b_kernel(const ushort* __restrict__ hb, const int* __restrict__ rowptr,
                     const int* __restrict__ es, const float* __restrict__ vn_emb,
                     ushort* __restrict__ ob, int n)
{
    const int node = blockIdx.x * 4 + (threadIdx.x >> 6);
    if (node >= n) return;
    const int lane = threadIdx.x & 63;
    const ushort4* H4 = reinterpret_cast<const ushort4*>(hb);
    const ushort4 o = H4[(size_t)node * 64 + lane];
    const int b = rowptr[node], e = rowptr[node + 1];
    const float4 vn = reinterpret_cast<const float4*>(vn_emb)[lane];
    const float cv = (float)(2 + (e - b));
    float a0 = fmaf(cv, vn.x, 2.f * b2f(o.x));
    float a1 = fmaf(cv, vn.y, 2.f * b2f(o.y));
    float a2 = fmaf(cv, vn.z, 2.f * b2f(o.z));
    float a3 = fmaf(cv, vn.w, 2.f * b2f(o.w));
    int i = b;
    for (; i + 2 <= e; i += 2) {
        const ushort4 v0 = H4[(size_t)es[i] * 64 + lane];
        const ushort4 v1 = H4[(size_t)es[i + 1] * 64 + lane];
        a0 += b2f(v0.x) + b2f(v1.x);
        a1 += b2f(v0.y) + b2f(v1.y);
        a2 += b2f(v0.z) + b2f(v1.z);
        a3 += b2f(v0.w) + b2f(v1.w);
    }
    for (; i < e; ++i) {
        const ushort4 v = H4[(size_t)es[i] * 64 + lane];
        a0 += b2f(v.x); a1 += b2f(v.y); a2 += b2f(v.z); a3 += b2f(v.w);
    }
    reinterpret_cast<ushort4*>(ob)[(size_t)node * 64 + lane] =
        make_ushort4(f2b(a0), f2b(a1), f2b(a2), f2b(a3));
}

__global__ __launch_bounds__(256)
void gatherb_kernel(const ushort* __restrict__ tb, const int* __restrict__ rowptr,
                    const int* __restrict__ es, ushort* __restrict__ ob, int n)
{
    const int node = blockIdx.x * 4 + (threadIdx.x >> 6);
    if (node >= n) return;
    const int lane = threadIdx.x & 63;
    const ushort4* H4 = reinterpret_cast<const ushort4*>(tb);
    const ushort4 o = H4[(size_t)node * 64 + lane];
    float a0 = 2.f * b2f(o.x), a1 = 2.f * b2f(o.y), a2 = 2.f * b2f(o.z), a3 = 2.f * b2f(o.w);
    const int b = rowptr[node], e = rowptr[node + 1];
    int i = b;
    for (; i + 2 <= e; i += 2) {
        const ushort4 v0 = H4[(size_t)es[i] * 64 + lane];
        const ushort4 v1 = H4[(size_t)es[i + 1] * 64 + lane];
        a0 += b2f(v0.x) + b2f(v1.x);
        a1 += b2f(v0.y) + b2f(v1.y);
        a2 += b2f(v0.z) + b2f(v1.z);
        a3 += b2f(v0.w) + b2f(v1.w);
    }
    for (; i < e; ++i) {
        const ushort4 v = H4[(size_t)es[i] * 64 + lane];
        a0 += b2f(v.x); a1 += b2f(v.y); a2 += b2f(v.z); a3 += b2f(v.w);
    }
    reinterpret_cast<ushort4*>(ob)[(size_t)node * 64 + lane] =
        make_ushort4(f2b(a0), f2b(a1), f2b(a2), f2b(a3));
}

// Graph boundaries (batch is sorted)
__global__ void offsets_kernel(const int* __restrict__ batch, int n, int* __restrict__ off)
{
    const int g = blockIdx.x * blockDim.x + threadIdx.x;
    if (g > NG) return;
    int lo = 0, hi = n;
    while (lo < hi) { const int mid = (lo + hi) >> 1; if (batch[mid] < g) lo = mid + 1; else hi = mid; }
    off[g] = lo;
}

// LN normalize: bf16 z -> bf16 gr slice0 (of [N][512]) + bf16(z + vn2[batch]) for layer 1
__global__ void norm0f_kernel(const ushort* __restrict__ zb, const float* __restrict__ sfin,
                              const float* __restrict__ vn2, const int* __restrict__ batch,
                              ushort* __restrict__ grs, ushort* __restrict__ tb, int n)
{
    const size_t i4 = (size_t)blockIdx.x * blockDim.x + threadIdx.x;
    if (i4 >= (size_t)n * 64) return;
    const float m = sfin[0], rs = sfin[1];
    const int row = (int)(i4 >> 6), c4 = (int)(i4 & 63);
    const ushort4 u = reinterpret_cast<const ushort4*>(zb)[i4];
    const float z0 = (b2f(u.x) - m) * rs, z1 = (b2f(u.y) - m) * rs,
                z2 = (b2f(u.z) - m) * rs, z3 = (b2f(u.w) - m) * rs;
    reinterpret_cast<ushort4*>(grs)[(size_t)row * 128 + c4] =
        make_ushort4(f2b(z0), f2b(z1), f2b(z2), f2b(z3));
    const int g = batch[row];
    const float4 e = reinterpret_cast<const float4*>(vn2 + (size_t)g * 256)[c4];
    reinterpret_cast<ushort4*>(tb)[i4] =
        make_ushort4(f2b(z0 + e.x), f2b(z1 + e.y), f2b(z2 + e.z), f2b(z3 + e.w));
}

// LN normalize: bf16 z -> bf16 gr slice1
__global__ void norm1b_kernel(const ushort* __restrict__ zb, const float* __restrict__ sfin,
                              ushort* __restrict__ grs, int n)
{
    const size_t i4 = (size_t)blockIdx.x * blockDim.x + threadIdx.x;
    if (i4 >= (size_t)n * 64) return;
    const float m = sfin[0], rs = sfin[1];
    const int row = (int)(i4 >> 6), c4 = (int)(i4 & 63);
    const ushort4 u = reinterpret_cast<const ushort4*>(zb)[i4];
    reinterpret_cast<ushort4*>(grs)[(size_t)row * 128 + 64 + c4] =
        make_ushort4(f2b((b2f(u.x) - m) * rs), f2b((b2f(u.y) - m) * rs),
                     f2b((b2f(u.z) - m) * rs), f2b((b2f(u.w) - m) * rs));
}

// FUSED virtual-node update (reads h0 from bf16 B1)
__global__ __launch_bounds__(256)
void vnall_kernel(const ushort* __restrict__ hb, const int* __restrict__ off,
                  const float* __restrict__ vn_emb,
                  const float* __restrict__ W1, const float* __restrict__ bb1,
                  const float* __restrict__ W2, const float* __restrict__ bb2,
                  float* __restrict__ vn2)
{
    __shared__ float r1[256];
    __shared__ float r2[512];
    const int g = blockIdx.x, t = threadIdx.x;
    const int i0 = off[g], i1 = off[g + 1];
    float s = 0.f;
    for (int i = i0; i < i1; ++i) s += b2f(hb[(size_t)i * 256 + t]);
    r1[t] = s + vn_emb[t];
    __syncthreads();
    float a0 = 0.f, a1 = 0.f;
    for (int k = 0; k < 256; ++k) {
        const float rv = r1[k];
        a0 = fmaf(rv, W1[(size_t)k * 512 + t], a0);
        a1 = fmaf(rv, W1[(size_t)k * 512 + 256 + t], a1);
    }
    r2[t]       = fmaxf((a0 + bb1[t]) * BNS, 0.f);
    r2[t + 256] = fmaxf((a1 + bb1[256 + t]) * BNS, 0.f);
    __syncthreads();
    float a = 0.f;
    for (int k = 0; k < 512; ++k) a = fmaf(r2[k], W2[(size_t)k * 256 + t], a);
    vn2[(size_t)g * 256 + t] = fmaxf((a + bb2[t]) * BNS, 0.f);
}

// segment max+mean over [h0(B1) | gr slices] -> readb [NG][1536] = [max | mean]
__global__ __launch_bounds__(256)
void pool_kernel(const ushort* __restrict__ hb, const ushort* __restrict__ g2,
                 const int* __restrict__ off, float* __restrict__ readb)
{
    const int g = blockIdx.x, t = threadIdx.x;
    const int i0 = off[g], i1 = off[g + 1];
    float m0 = -__builtin_inff(), m1 = m0, m2 = m0;
    float s0 = 0.f, s1 = 0.f, s2 = 0.f;
    for (int i = i0; i < i1; ++i) {
        const float v0 = b2f(hb[(size_t)i * 256 + t]);
        const ushort2 z = *reinterpret_cast<const ushort2*>(g2 + (size_t)i * 512 + 2 * t);
        const float v1 = b2f(z.x), v2 = b2f(z.y);
        m0 = fmaxf(m0, v0); m1 = fmaxf(m1, v1); m2 = fmaxf(m2, v2);
        s0 += v0; s1 += v1; s2 += v2;
    }
    const float inv = 1.f / fmaxf((float)(i1 - i0), 1.f);
    float* rb = readb + (size_t)g * 1536;
    rb[t] = m0;
    rb[256 + 2 * t] = m1; rb[256 + 2 * t + 1] = m2;
    rb[768 + t] = s0 * inv;
    rb[1024 + 2 * t] = s1 * inv; rb[1024 + 2 * t + 1] = s2 * inv;
}

// FUSED readout head
__global__ __launch_bounds__(256)
void outg2_kernel(const float* __restrict__ readb, const float* __restrict__ W,
                  const float* __restrict__ b,
                  const float* __restrict__ clsW, const float* __restrict__ clsb,
                  const float* __restrict__ dW, const float* __restrict__ db,
                  float* __restrict__ x5, float* __restrict__ logits, float* __restrict__ ssl)
{
    __shared__ float rows[8][1536];
    __shared__ float x5s[8][256];
    const int g0 = blockIdx.x * 8, t = threadIdx.x;
    for (int i = t; i < 8 * 1536; i += 256) rows[i / 1536][i % 1536] = readb[(size_t)g0 * 1536 + i];
    __syncthreads();
    float acc[8];
#pragma unroll
    for (int r = 0; r < 8; ++r) acc[r] = 0.f;
    for (int k = 0; k < 1536; ++k) {
        const float wv = W[(size_t)k * 256 + t];
#pragma unroll
        for (int r = 0; r < 8; ++r) acc[r] = fmaf(rows[r][k], wv, acc[r]);
    }
    const float bb = b[t];
#pragma unroll
    for (int r = 0; r < 8; ++r) {
        const float v = eluf(acc[r] + bb);
        x5[(size_t)(g0 + r) * 256 + t] = v;
        x5s[r][t] = v;
    }
    __syncthreads();

    const int grp = t >> 5, l32 = t & 31;
    float p0 = 0.f, p1 = 0.f;
    for (int c = l32; c < 256; c += 32) {
        const float v = x5s[grp][c];
        p0 = fmaf(v, clsW[c * 2], p0);
        p1 = fmaf(v, clsW[c * 2 + 1], p1);
    }
    float q0 = 0.f, q1 = 0.f, q2 = 0.f;
    for (int c = l32; c < 64; c += 32) {
        q0 = fmaf(x5s[grp][c],       dW[c],       q0);
        q1 = fmaf(x5s[grp][64 + c],  dW[64 + c],  q1);
        q2 = fmaf(x5s[grp][128 + c], dW[128 + c], q2);
    }
    for (int o = 16; o; o >>= 1) {
        p0 += __shfl_down(p0, o, 32); p1 += __shfl_down(p1, o, 32);
        q0 += __shfl_down(q0, o, 32); q1 += __shfl_down(q1, o, 32); q2 += __shfl_down(q2, o, 32);
    }
    if (l32 == 0) {
        const float z0 = p0 + clsb[0], z1 = p1 + clsb[1];
        const float m = fmaxf(z0, z1);
        const float lse = m + logf(expf(z0 - m) + expf(z1 - m));
        logits[(size_t)(g0 + grp) * 2 + 0] = z0 - lse;
        logits[(size_t)(g0 + grp) * 2 + 1] = z1 - lse;
        ssl[(size_t)(g0 + grp) * 3 + 0] = 0.05f + 0.35f / (1.f + expf(-(q0 + db[0])));
        ssl[(size_t)(g0 + grp) * 3 + 1] = 0.05f + 0.35f / (1.f + expf(-(q1 + db[1])));
        ssl[(size_t)(g0 + grp) * 3 + 2] = 0.05f + 0.35f / (1.f + expf(-(q2 + db[2])));
    }
}

// ---------------------------------------------------------------------------
extern "C" void kernel_launch(void* const* d_in, const int* in_sizes, int n_in,
                              void* d_out, int out_size, void* d_ws, size_t ws_size,
                              hipStream_t stream)
{
    const float* x      = (const float*)d_in[0];
    const int*   eidx   = (const int*)d_in[1];
    const int*   batch  = (const int*)d_in[2];
    const float* lin1_W = (const float*)d_in[3];
    const float* lin1_b = (const float*)d_in[4];
    const float* g0W1   = (const float*)d_in[5];
    const float* g0b1   = (const float*)d_in[6];
    const float* g0W2   = (const float*)d_in[7];
    const float* g0b2   = (const float*)d_in[8];
    const float* g1W1   = (const float*)d_in[9];
    const float* g1b1   = (const float*)d_in[10];
    const float* g1W2   = (const float*)d_in[11];
    const float* g1b2   = (const float*)d_in[12];
    const float* vn_emb = (const float*)d_in[13];
    const float* vnW1   = (const float*)d_in[14];
    const float* vnb1   = (const float*)d_in[15];
    const float* vnW2   = (const float*)d_in[16];
    const float* vnb2   = (const float*)d_in[17];
    const float* loW    = (const float*)d_in[18];
    const float* lob    = (const float*)d_in[19];
    const float* clsW   = (const float*)d_in[20];
    const float* clsb   = (const float*)d_in[21];
    const float* dhW    = (const float*)d_in[22];
    const float* dhb    = (const float*)d_in[23];

    const int N = in_sizes[2];        // 50000 nodes
    const int E = in_sizes[1] / 2;    // 800000 edges
    const int* esrc = eidx;
    const int* edst = eidx + E;

    float* out = (float*)d_out;
    float* out_logits = out;                                     // [NG,2]
    float* out_x5     = out + (size_t)NG * 2;                    // [NG,256]
    float* out_ssl    = out + (size_t)NG * 2 + (size_t)NG * 256; // [NG,3]

    // --- workspace carve (256B aligned; sacc(2KB)+cnt adjacent, one memset) ---
    char* p = (char*)d_ws;
    auto carve = [&](size_t bytes) { char* r = p; p += (bytes + 255) & ~(size_t)255; return (void*)r; };
    double* sacc   = (double*)carve(256 * sizeof(double));          // 64 buckets x2 x 2 layers
    int*    cnt    = (int*)   carve((size_t)N * sizeof(int));
    float*  sfin   = (float*) carve(4 * sizeof(float));
    int*    goff   = (int*)   carve((NG + 1) * sizeof(int));
    int*    rowptr = (int*)   carve((size_t)(N + 1) * sizeof(int));
    int*    cursor = (int*)   carve((size_t)N * sizeof(int));
    int*    es     = (int*)   carve((size_t)E * sizeof(int));
    ushort* gr2    = (ushort*)carve((size_t)N * 512 * sizeof(ushort)); // [z1|z2] bf16
    ushort* xb     = (ushort*)carve((size_t)N * 128 * sizeof(ushort));
    ushort* B1     = (ushort*)carve((size_t)N * 256 * sizeof(ushort)); // h0 (kept for pool)
    ushort* B2     = (ushort*)carve((size_t)N * 256 * sizeof(ushort));
    ushort* B3     = (ushort*)carve((size_t)N * 256 * sizeof(ushort));
    ushort* Wt1    = (ushort*)carve(256 * 128 * sizeof(ushort));
    ushort* Wt0a   = (ushort*)carve(256 * 256 * sizeof(ushort));
    ushort* Wt0b   = (ushort*)carve(256 * 256 * sizeof(ushort));
    ushort* Wtbd1  = (ushort*)carve(16384 * sizeof(ushort));
    ushort* Wtbd2  = (ushort*)carve(16384 * sizeof(ushort));
    float*  vn2    = (float*) carve((size_t)NG * 256 * sizeof(float));
    float*  readb  = (float*) carve((size_t)NG * 1536 * sizeof(float));

    hipMemsetAsync(sacc, 0, 2048 + (size_t)N * sizeof(int), stream);

    const int mt = (N + 127) / 128;
    const int vecGrid = (N * 64 + 255) / 256;
    const int eGrid = (E + 255) / 256;
    const int gatherGrid = (N + 3) / 4;
    const int prepTotal = N * 32 + 196608;

    // ---- CSR build ----
    count_kernel<<<eGrid, 256, 0, stream>>>(edst, cnt, E);
    scan_kernel<<<1, 1024, 0, stream>>>(cnt, rowptr, cursor, N);
    fill_kernel<<<eGrid, 256, 0, stream>>>(esrc, edst, cursor, es, E);

    // ---- all weight/input prep ----
    prep_kernel<<<(prepTotal + 255) / 256, 256, 0, stream>>>(
        x, lin1_W, g0W1, g0W2, g1W1, g1W2, xb, Wt1, Wt0a, Wt0b, Wtbd1, Wtbd2, N * 32);

    // h0 = elu(x @ lin1_W + b) -> B1 (bf16 only)
    tgemm_kernel<2><<<mt, 512, 0, stream>>>(xb, 128, Wt1, lin1_b, B1, N);
    offsets_kernel<<<3, 256, 0, stream>>>(batch, N, goff);

    // ---- virtual node update (reads B1 bf16) ----
    vnall_kernel<<<NG, 256, 0, stream>>>(B1, goff, vn_emb, vnW1, vnb1, vnW2, vnb2, vn2);

    // ---- layer 0 ----
    gather0b_kernel<<<gatherGrid, 256, 0, stream>>>(B1, rowptr, es, vn_emb, B2, N);
    mlp0_kernel<<<mt, 512, 0, stream>>>(B2, Wt0a, Wt0b, g0b1, g0b2, B3, N, sacc);
    finalize_kernel<<<1, 64, 0, stream>>>(sacc, sfin, (double)N * 256.0);
    norm0f_kernel<<<vecGrid, 256, 0, stream>>>(B3, sfin, vn2, batch, gr2, B2, N);

    // ---- layer 1 ----
    gatherb_kernel<<<gatherGrid, 256, 0, stream>>>(B2, rowptr, es, B3, N);
    bd2_kernel<<<dim3(mt, 4), 256, 0, stream>>>(B3, Wtbd1, Wtbd2, g1b1, g1b2, B2, N, sacc + 128);
    finalize_kernel<<<1, 64, 0, stream>>>(sacc + 128, sfin + 2, (double)N * 256.0);
    norm1b_kernel<<<vecGrid, 256, 0, stream>>>(B2, sfin + 2, gr2, N);

    // ---- readout ----
    pool_kernel<<<NG, 256, 0, stream>>>(B1, gr2, goff, readb);
    outg2_kernel<<<NG / 8, 256, 0, stream>>>(readb, loW, lob, clsW, clsb, dhW, dhb,
                                             out_x5, out_logits, out_ssl);
}

// Round 12
// 512.403 us; speedup vs baseline: 1.6859x; 1.2231x over previous
//
#include <hip/hip_runtime.h>

static constexpr int NG = 512;       // graphs
static constexpr float LN_EPS = 1e-5f;
static constexpr float BNS = 0.9999950000374997f; // rsqrt(1 + 1e-5) for BatchNorm eval

__device__ __forceinline__ float eluf(float v) { return v > 0.f ? v : expm1f(v); }

typedef __attribute__((ext_vector_type(8))) short bf16x8;
typedef __attribute__((ext_vector_type(4))) float f32x4;

__device__ __forceinline__ ushort f2b(float f) {   // f32 -> bf16 RNE
    union { float f; unsigned u; } v; v.f = f;
    const unsigned u = v.u;
    return (ushort)((u + 0x7FFFu + ((u >> 16) & 1u)) >> 16);
}
__device__ __forceinline__ float b2f(ushort b) {
    union { unsigned u; float f; } v; v.u = ((unsigned)b) << 16;
    return v.f;
}

// async global->LDS, 16B per lane. LDS dest lane-contiguous (linear).
__device__ __forceinline__ void gl16(const ushort* g, ushort* l) {
    __builtin_amdgcn_global_load_lds(
        (const __attribute__((address_space(1))) void*)g,
        (__attribute__((address_space(3))) void*)l, 16, 0, 0);
}

// ---------------------------------------------------------------------------
// lin1 MFMA GEMM: B1 = bf16(elu(x@W+b)).  BM=128,BN=256,BK=64,K=128.
// ---------------------------------------------------------------------------
template<int KSTEPS>
__global__ __launch_bounds__(512)
void tgemm_kernel(const ushort* __restrict__ Ab, int ldab,
                  const ushort* __restrict__ Wt,   // [256][K]
                  const float* __restrict__ bias,
                  ushort* __restrict__ Cb,
                  int n)
{
    __shared__ __align__(16) ushort sbuf[32768];   // 64 KB
    ushort* As = sbuf;          // 128*64
    ushort* Bs = sbuf + 8192;   // 256*64

    const int tid = threadIdx.x;
    const int lane = tid & 63;
    const int wv = tid >> 6;
    const int wr = wv >> 1, wc = wv & 1;
    const int r0 = blockIdx.x * 128;
    const int colL = lane & 15;
    const int lr = lane >> 4;

    f32x4 acc[2][8];
#pragma unroll
    for (int rt = 0; rt < 2; ++rt)
#pragma unroll
        for (int ct = 0; ct < 8; ++ct) acc[rt][ct] = (f32x4){0.f, 0.f, 0.f, 0.f};

    for (int ks = 0; ks < KSTEPS; ++ks) {
#pragma unroll
        for (int it = 0; it < 2; ++it) {           // A
            const int i = it * 512 + tid;
            const int row = i >> 3, cb = i & 7;
            const int rg = min(r0 + row, n - 1);
            gl16(Ab + (size_t)rg * ldab + ks * 64 + ((cb ^ (row & 7)) * 8), As + i * 8);
        }
#pragma unroll
        for (int it = 0; it < 4; ++it) {           // B
            const int i = it * 512 + tid;
            const int col = i >> 3, cb = i & 7;
            gl16(Wt + (size_t)col * (KSTEPS * 64) + ks * 64 + ((cb ^ (col & 7)) * 8), Bs + i * 8);
        }
        __syncthreads();

        bf16x8 af[2][2];
#pragma unroll
        for (int rt = 0; rt < 2; ++rt)
#pragma unroll
            for (int kk = 0; kk < 2; ++kk) {
                const int row = wr * 32 + rt * 16 + colL;
                const int blk = kk * 4 + lr;
                af[rt][kk] = *reinterpret_cast<const bf16x8*>(As + row * 64 + ((blk ^ (row & 7)) * 8));
            }
#pragma unroll
        for (int ct = 0; ct < 8; ++ct)
#pragma unroll
            for (int kk = 0; kk < 2; ++kk) {
                const int col = wc * 128 + ct * 16 + colL;
                const int blk = kk * 4 + lr;
                const bf16x8 bf = *reinterpret_cast<const bf16x8*>(Bs + col * 64 + ((blk ^ (col & 7)) * 8));
                acc[0][ct] = __builtin_amdgcn_mfma_f32_16x16x32_bf16(af[0][kk], bf, acc[0][ct], 0, 0, 0);
                acc[1][ct] = __builtin_amdgcn_mfma_f32_16x16x32_bf16(af[1][kk], bf, acc[1][ct], 0, 0, 0);
            }
        __syncthreads();
    }

    float bv[8];
#pragma unroll
    for (int ct = 0; ct < 8; ++ct) bv[ct] = bias[wc * 128 + ct * 16 + colL];

    ushort* eb = sbuf + wv * 4096;   // 32 rows x 128 cols
#pragma unroll
    for (int rt = 0; rt < 2; ++rt)
#pragma unroll
        for (int ct = 0; ct < 8; ++ct)
#pragma unroll
            for (int r = 0; r < 4; ++r) {
                const float v = eluf(acc[rt][ct][r] + bv[ct]);
                eb[(rt * 16 + lr * 4 + r) * 128 + ct * 16 + colL] = f2b(v);
            }
#pragma unroll
    for (int j = 0; j < 8; ++j) {
        const int idx = j * 64 + lane;
        const int lrow = idx >> 4, c8 = idx & 15;
        const int grow = r0 + wr * 32 + lrow;
        if (grow < n)
            *reinterpret_cast<bf16x8*>(Cb + (size_t)grow * 256 + wc * 128 + c8 * 8) =
                *reinterpret_cast<const bf16x8*>(eb + lrow * 128 + c8 * 8);
    }
}

// ---------------------------------------------------------------------------
// FUSED dense GIN MLP (layer 0). Stats -> 64 atomic buckets (blockIdx&63).
// ---------------------------------------------------------------------------
__global__ __launch_bounds__(512)
void mlp0_kernel(const ushort* __restrict__ Ab,    // [n][256]
                 const ushort* __restrict__ W1t,   // [256][256]
                 const ushort* __restrict__ W2t,
                 const float* __restrict__ b1, const float* __restrict__ b2,
                 ushort* __restrict__ Cb,
                 int n, double* __restrict__ stats)
{
    __shared__ __align__(16) ushort As[8192];
    __shared__ __align__(16) ushort Bs[16384];
    __shared__ __align__(16) ushort Z[32768];

    const int tid = threadIdx.x;
    const int lane = tid & 63;
    const int wv = tid >> 6;
    const int wr = wv >> 1, wc = wv & 1;
    const int r0 = blockIdx.x * 128;
    const int colL = lane & 15;
    const int lr = lane >> 4;

    f32x4 acc[2][8];
#pragma unroll
    for (int rt = 0; rt < 2; ++rt)
#pragma unroll
        for (int ct = 0; ct < 8; ++ct) acc[rt][ct] = (f32x4){0.f, 0.f, 0.f, 0.f};

    // ---- stage 1: z = relu(A @ W1 + b1) ----
    for (int ks = 0; ks < 4; ++ks) {
#pragma unroll
        for (int it = 0; it < 2; ++it) {
            const int i = it * 512 + tid;
            const int row = i >> 3, cb = i & 7;
            const int rg = min(r0 + row, n - 1);
            gl16(Ab + (size_t)rg * 256 + ks * 64 + ((cb ^ (row & 7)) * 8), As + i * 8);
        }
#pragma unroll
        for (int it = 0; it < 4; ++it) {
            const int i = it * 512 + tid;
            const int col = i >> 3, cb = i & 7;
            gl16(W1t + (size_t)col * 256 + ks * 64 + ((cb ^ (col & 7)) * 8), Bs + i * 8);
        }
        __syncthreads();
        bf16x8 af[2][2];
#pragma unroll
        for (int rt = 0; rt < 2; ++rt)
#pragma unroll
            for (int kk = 0; kk < 2; ++kk) {
                const int row = wr * 32 + rt * 16 + colL;
                const int blk = kk * 4 + lr;
                af[rt][kk] = *reinterpret_cast<const bf16x8*>(As + row * 64 + ((blk ^ (row & 7)) * 8));
            }
#pragma unroll
        for (int ct = 0; ct < 8; ++ct)
#pragma unroll
            for (int kk = 0; kk < 2; ++kk) {
                const int col = wc * 128 + ct * 16 + colL;
                const int blk = kk * 4 + lr;
                const bf16x8 bf = *reinterpret_cast<const bf16x8*>(Bs + col * 64 + ((blk ^ (col & 7)) * 8));
                acc[0][ct] = __builtin_amdgcn_mfma_f32_16x16x32_bf16(af[0][kk], bf, acc[0][ct], 0, 0, 0);
                acc[1][ct] = __builtin_amdgcn_mfma_f32_16x16x32_bf16(af[1][kk], bf, acc[1][ct], 0, 0, 0);
            }
        __syncthreads();
    }
#pragma unroll
    for (int ct = 0; ct < 8; ++ct) {
        const float bvv = b1[wc * 128 + ct * 16 + colL];
#pragma unroll
        for (int rt = 0; rt < 2; ++rt)
#pragma unroll
            for (int r = 0; r < 4; ++r) {
                const float v = fmaxf(acc[rt][ct][r] + bvv, 0.f);
                const int zrow = wr * 32 + rt * 16 + lr * 4 + r;
                const int zcol = wc * 128 + ct * 16 + colL;
                const int chunk = zcol >> 3;
                const int sw = (chunk & 24) | ((chunk & 7) ^ (zrow & 7));
                Z[zrow * 256 + sw * 8 + (zcol & 7)] = f2b(v);
            }
    }
    __syncthreads();

    // ---- stage 2: out = elu(z @ W2 + b2) ----
#pragma unroll
    for (int rt = 0; rt < 2; ++rt)
#pragma unroll
        for (int ct = 0; ct < 8; ++ct) acc[rt][ct] = (f32x4){0.f, 0.f, 0.f, 0.f};

    for (int ks = 0; ks < 4; ++ks) {
#pragma unroll
        for (int it = 0; it < 4; ++it) {
            const int i = it * 512 + tid;
            const int col = i >> 3, cb = i & 7;
            gl16(W2t + (size_t)col * 256 + ks * 64 + ((cb ^ (col & 7)) * 8), Bs + i * 8);
        }
        __syncthreads();
        bf16x8 zf[2][2];
#pragma unroll
        for (int rt = 0; rt < 2; ++rt)
#pragma unroll
            for (int kk = 0; kk < 2; ++kk) {
                const int zrow = wr * 32 + rt * 16 + colL;
                const int chunk = ks * 8 + kk * 4 + lr;
                const int sw = (chunk & 24) | ((chunk & 7) ^ (zrow & 7));
                zf[rt][kk] = *reinterpret_cast<const bf16x8*>(Z + zrow * 256 + sw * 8);
            }
#pragma unroll
        for (int ct = 0; ct < 8; ++ct)
#pragma unroll
            for (int kk = 0; kk < 2; ++kk) {
                const int col = wc * 128 + ct * 16 + colL;
                const int blk = kk * 4 + lr;
                const bf16x8 bf = *reinterpret_cast<const bf16x8*>(Bs + col * 64 + ((blk ^ (col & 7)) * 8));
                acc[0][ct] = __builtin_amdgcn_mfma_f32_16x16x32_bf16(zf[0][kk], bf, acc[0][ct], 0, 0, 0);
                acc[1][ct] = __builtin_amdgcn_mfma_f32_16x16x32_bf16(zf[1][kk], bf, acc[1][ct], 0, 0, 0);
            }
        __syncthreads();
    }

    float bv[8];
#pragma unroll
    for (int ct = 0; ct < 8; ++ct) bv[ct] = b2[wc * 128 + ct * 16 + colL];
    ushort* eb = Z + wv * 4096;
    float s = 0.f, ss = 0.f;
#pragma unroll
    for (int rt = 0; rt < 2; ++rt)
#pragma unroll
        for (int ct = 0; ct < 8; ++ct)
#pragma unroll
            for (int r = 0; r < 4; ++r) {
                const float v = eluf(acc[rt][ct][r] + bv[ct]);
                eb[(rt * 16 + lr * 4 + r) * 128 + ct * 16 + colL] = f2b(v);
                const int row = r0 + wr * 32 + rt * 16 + lr * 4 + r;
                if (row < n) { s += v; ss += v * v; }
            }
#pragma unroll
    for (int j = 0; j < 8; ++j) {
        const int idx = j * 64 + lane;
        const int lrow = idx >> 4, c8 = idx & 15;
        const int grow = r0 + wr * 32 + lrow;
        if (grow < n)
            *reinterpret_cast<bf16x8*>(Cb + (size_t)grow * 256 + wc * 128 + c8 * 8) =
                *reinterpret_cast<const bf16x8*>(eb + lrow * 128 + c8 * 8);
    }
    double ds = (double)s, dss = (double)ss;
    for (int o = 32; o; o >>= 1) { ds += __shfl_down(ds, o, 64); dss += __shfl_down(dss, o, 64); }
    if (lane == 0) {
        const int bkt = (blockIdx.x & 63) * 2;
        unsafeAtomicAdd(&stats[bkt], ds); unsafeAtomicAdd(&stats[bkt + 1], dss);
    }
}

// ---------------------------------------------------------------------------
// FUSED block-diagonal GIN MLP (layer 1). Bucketed stats.
// ---------------------------------------------------------------------------
__global__ __launch_bounds__(256)
void bd2_kernel(const ushort* __restrict__ Ab,    // [n][256]
                const ushort* __restrict__ W1t,   // [4][64 col][64 k]
                const ushort* __restrict__ W2t,
                const float* __restrict__ b1, const float* __restrict__ b2,
                ushort* __restrict__ Cb,
                int n, double* __restrict__ stats)
{
    __shared__ __align__(16) ushort As[8192];
    __shared__ __align__(16) ushort B1s[4096];
    __shared__ __align__(16) ushort B2s[4096];

    const int tid = threadIdx.x;
    const int lane = tid & 63;
    const int wv = tid >> 6;
    const int ch = blockIdx.y;
    const int r0 = blockIdx.x * 128;
    const int colL = lane & 15;
    const int lr = lane >> 4;

#pragma unroll
    for (int it = 0; it < 4; ++it) {             // A
        const int i = it * 256 + tid;
        const int row = i >> 3, cb = i & 7;
        const int rg = min(r0 + row, n - 1);
        gl16(Ab + (size_t)rg * 256 + ch * 64 + ((cb ^ (row & 7)) * 8), As + i * 8);
    }
#pragma unroll
    for (int it = 0; it < 2; ++it) {             // W1
        const int i = it * 256 + tid;
        const int col = i >> 3, cb = i & 7;
        gl16(W1t + ch * 4096 + col * 64 + ((cb ^ (col & 7)) * 8), B1s + i * 8);
    }
#pragma unroll
    for (int it = 0; it < 2; ++it) {             // W2
        const int i = it * 256 + tid;
        const int col = i >> 3, cb = i & 7;
        gl16(W2t + ch * 4096 + col * 64 + ((cb ^ (col & 7)) * 8), B2s + i * 8);
    }
    __syncthreads();

    bf16x8 af[2][2];
#pragma unroll
    for (int rt = 0; rt < 2; ++rt)
#pragma unroll
        for (int kk = 0; kk < 2; ++kk) {
            const int row = wv * 32 + rt * 16 + colL;
            const int blk = kk * 4 + lr;
            af[rt][kk] = *reinterpret_cast<const bf16x8*>(As + row * 64 + ((blk ^ (row & 7)) * 8));
        }
    f32x4 acc[2][4];
#pragma unroll
    for (int rt = 0; rt < 2; ++rt)
#pragma unroll
        for (int ct = 0; ct < 4; ++ct) acc[rt][ct] = (f32x4){0.f, 0.f, 0.f, 0.f};
#pragma unroll
    for (int ct = 0; ct < 4; ++ct)
#pragma unroll
        for (int kk = 0; kk < 2; ++kk) {
            const int col = ct * 16 + colL;
            const int blk = kk * 4 + lr;
            const bf16x8 bf = *reinterpret_cast<const bf16x8*>(B1s + col * 64 + ((blk ^ (col & 7)) * 8));
            acc[0][ct] = __builtin_amdgcn_mfma_f32_16x16x32_bf16(af[0][kk], bf, acc[0][ct], 0, 0, 0);
            acc[1][ct] = __builtin_amdgcn_mfma_f32_16x16x32_bf16(af[1][kk], bf, acc[1][ct], 0, 0, 0);
        }

    ushort* Zw = As + wv * 2048;    // wave-private 32x64
#pragma unroll
    for (int rt = 0; rt < 2; ++rt)
#pragma unroll
        for (int ct = 0; ct < 4; ++ct) {
            const float bvv = b1[ch * 64 + ct * 16 + colL];
#pragma unroll
            for (int r = 0; r < 4; ++r) {
                const float v = fmaxf(acc[rt][ct][r] + bvv, 0.f);
                const int zrow = rt * 16 + lr * 4 + r;
                const int zcol = ct * 16 + colL;
                Zw[zrow * 64 + (((zcol >> 3) ^ (zrow & 7)) * 8) + (zcol & 7)] = f2b(v);
            }
        }

    bf16x8 zf[2][2];
#pragma unroll
    for (int rt = 0; rt < 2; ++rt)
#pragma unroll
        for (int kk = 0; kk < 2; ++kk) {
            const int zrow = rt * 16 + colL;
            const int blk = kk * 4 + lr;
            zf[rt][kk] = *reinterpret_cast<const bf16x8*>(Zw + zrow * 64 + ((blk ^ (zrow & 7)) * 8));
        }
#pragma unroll
    for (int rt = 0; rt < 2; ++rt)
#pragma unroll
        for (int ct = 0; ct < 4; ++ct) acc[rt][ct] = (f32x4){0.f, 0.f, 0.f, 0.f};
#pragma unroll
    for (int ct = 0; ct < 4; ++ct)
#pragma unroll
        for (int kk = 0; kk < 2; ++kk) {
            const int col = ct * 16 + colL;
            const int blk = kk * 4 + lr;
            const bf16x8 bf = *reinterpret_cast<const bf16x8*>(B2s + col * 64 + ((blk ^ (col & 7)) * 8));
            acc[0][ct] = __builtin_amdgcn_mfma_f32_16x16x32_bf16(zf[0][kk], bf, acc[0][ct], 0, 0, 0);
            acc[1][ct] = __builtin_amdgcn_mfma_f32_16x16x32_bf16(zf[1][kk], bf, acc[1][ct], 0, 0, 0);
        }

    float s = 0.f, ss = 0.f;
#pragma unroll
    for (int rt = 0; rt < 2; ++rt)
#pragma unroll
        for (int ct = 0; ct < 4; ++ct) {
            const float bvv = b2[ch * 64 + ct * 16 + colL];
#pragma unroll
            for (int r = 0; r < 4; ++r) {
                const float v = eluf(acc[rt][ct][r] + bvv);
                Zw[(rt * 16 + lr * 4 + r) * 64 + ct * 16 + colL] = f2b(v);
                const int row = r0 + wv * 32 + rt * 16 + lr * 4 + r;
                if (row < n) { s += v; ss += v * v; }
            }
        }
#pragma unroll
    for (int j = 0; j < 4; ++j) {
        const int idx = j * 64 + lane;
        const int lrow = idx >> 3, c8 = idx & 7;
        const int grow = r0 + wv * 32 + lrow;
        if (grow < n)
            *reinterpret_cast<bf16x8*>(Cb + (size_t)grow * 256 + ch * 64 + c8 * 8) =
                *reinterpret_cast<const bf16x8*>(Zw + lrow * 64 + c8 * 8);
    }

    double ds = (double)s, dss = (double)ss;
    for (int o = 32; o; o >>= 1) { ds += __shfl_down(ds, o, 64); dss += __shfl_down(dss, o, 64); }
    if (lane == 0) {
        const int bkt = ((blockIdx.x + blockIdx.y * 16) & 63) * 2;
        unsafeAtomicAdd(&stats[bkt], ds); unsafeAtomicAdd(&stats[bkt + 1], dss);
    }
}

// reduce 64 stat buckets -> sfin {mean, rsqrt}
__global__ __launch_bounds__(64)
void finalize_kernel(const double* __restrict__ sacc, float* __restrict__ sfin, double M)
{
    const int t = threadIdx.x;
    double s = sacc[t * 2], ss = sacc[t * 2 + 1];
    for (int o = 32; o; o >>= 1) { s += __shfl_down(s, o, 64); ss += __shfl_down(ss, o, 64); }
    if (t == 0) {
        const double mean = s / M;
        double var = ss / M - mean * mean;
        if (var < 0.0) var = 0.0;
        sfin[0] = (float)mean;
        sfin[1] = (float)(1.0 / sqrt(var + (double)LN_EPS));
    }
}

// ---------------------------------------------------------------------------
// ONE prep kernel: x->bf16 + all 5 weight transposes
// ---------------------------------------------------------------------------
__global__ void prep_kernel(const float* __restrict__ x,
                            const float* __restrict__ lin1W,
                            const float* __restrict__ g0W1, const float* __restrict__ g0W2,
                            const float* __restrict__ g1W1, const float* __restrict__ g1W2,
                            ushort* __restrict__ xb,
                            ushort* __restrict__ Wt1,
                            ushort* __restrict__ Wt0a, ushort* __restrict__ Wt0b,
                            ushort* __restrict__ Wtbd1, ushort* __restrict__ Wtbd2,
                            int n32)
{
    const int i = blockIdx.x * 256 + threadIdx.x;
    if (i < n32) {
        const float4 v = reinterpret_cast<const float4*>(x)[i];
        reinterpret_cast<ushort4*>(xb)[i] = make_ushort4(f2b(v.x), f2b(v.y), f2b(v.z), f2b(v.w));
        return;
    }
    int j = i - n32;
    if (j < 32768) {                         // Wt1 [256][128]
        const int c = j >> 7, k = j & 127;
        Wt1[j] = f2b(lin1W[(size_t)k * 256 + c]);
    } else if (j < 98304) {                  // Wt0a [256][256]
        j -= 32768;
        const int c = j >> 8, k = j & 255;
        Wt0a[j] = f2b(g0W1[(size_t)k * 256 + c]);
    } else if (j < 163840) {                 // Wt0b
        j -= 98304;
        const int c = j >> 8, k = j & 255;
        Wt0b[j] = f2b(g0W2[(size_t)k * 256 + c]);
    } else if (j < 180224) {                 // Wtbd1 [4][64][64]
        j -= 163840;
        const int ch = j >> 12, r = j & 4095, cw = r >> 6, k = r & 63;
        Wtbd1[j] = f2b(g1W1[ch * 4096 + k * 64 + cw]);
    } else if (j < 196608) {                 // Wtbd2
        j -= 180224;
        const int ch = j >> 12, r = j & 4095, cw = r >> 6, k = r & 63;
        Wtbd2[j] = f2b(g1W2[ch * 4096 + k * 64 + cw]);
    }
}

// ---------------------------------------------------------------------------
// CSR construction: count + 3-level scan + fill
// ---------------------------------------------------------------------------
__global__ void count_kernel(const int* __restrict__ dst, int* __restrict__ cnt, int nE)
{
    const int e = blockIdx.x * 256 + threadIdx.x;
    if (e < nE) atomicAdd(&cnt[dst[e]], 1);
}

// level 1: per-block (256 elems) sums
__global__ __launch_bounds__(256)
void scan1_kernel(const int* __restrict__ cnt, int* __restrict__ bsum, int n)
{
    __shared__ int ws[4];
    const int i = blockIdx.x * 256 + threadIdx.x;
    int v = (i < n) ? cnt[i] : 0;
    for (int o = 32; o; o >>= 1) v += __shfl_down(v, o, 64);
    if ((threadIdx.x & 63) == 0) ws[threadIdx.x >> 6] = v;
    __syncthreads();
    if (threadIdx.x == 0) bsum[blockIdx.x] = ws[0] + ws[1] + ws[2] + ws[3];
}

// level 2: exclusive scan of nb (<256) block sums; writes rowptr[n] = total
__global__ __launch_bounds__(256)
void scan2_kernel(int* __restrict__ bsum, int* __restrict__ rowptr, int nb, int n)
{
    __shared__ int sh[256];
    const int t = threadIdx.x;
    const int v = (t < nb) ? bsum[t] : 0;
    sh[t] = v;
    __syncthreads();
    for (int o = 1; o < 256; o <<= 1) {
        const int u = (t >= o) ? sh[t - o] : 0;
        __syncthreads();
        sh[t] += u;
        __syncthreads();
    }
    if (t < nb) bsum[t] = sh[t] - v;    // exclusive
    if (t == 255) rowptr[n] = sh[255];
}

// level 3: in-block exclusive prefix + block offset -> rowptr, cursor
__global__ __launch_bounds__(256)
void scan3_kernel(const int* __restrict__ cnt, const int* __restrict__ bsum,
                  int* __restrict__ rowptr, int* __restrict__ cursor, int n)
{
    __shared__ int sh[256];
    const int t = threadIdx.x;
    const int i = blockIdx.x * 256 + t;
    const int v = (i < n) ? cnt[i] : 0;
    sh[t] = v;
    __syncthreads();
    for (int o = 1; o < 256; o <<= 1) {
        const int u = (t >= o) ? sh[t - o] : 0;
        __syncthreads();
        sh[t] += u;
        __syncthreads();
    }
    if (i < n) {
        const int ex = bsum[blockIdx.x] + sh[t] - v;
        rowptr[i] = ex;
        cursor[i] = ex;
    }
}

__global__ void fill_kernel(const int* __restrict__ src, const int* __restrict__ dst,
                            int* __restrict__ cursor, int* __restrict__ es, int nE)
{
    const int e = blockIdx.x * 256 + threadIdx.x;
    if (e >= nE) return;
    const int p = atomicAdd(&cursor[dst[e]], 1);
    es[p] = src[e];
}

// ---------------------------------------------------------------------------
// Gathers (bf16 rows, one wave per node)
// ---------------------------------------------------------------------------
__global__ __launch_bounds__(256)
void gather0b_kernel(const ushort* __restrict__ hb, const int* __restrict__ rowptr,
                     const int* __restrict__ es, const float* __restrict__ vn_emb,
                     ushort* __restrict__ ob, int n)
{
    const int node = blockIdx.x * 4 + (threadIdx.x >> 6);
    if (node >= n) return;
    const int lane = threadIdx.x & 63;
    const ushort4* H4 = reinterpret_cast<const ushort4*>(hb);
    const ushort4 o = H4[(size_t)node * 64 + lane];
    const int b = rowptr[node], e = rowptr[node + 1];
    const float4 vn = reinterpret_cast<const float4*>(vn_emb)[lane];
    const float cv = (float)(2 + (e - b));
    float a0 = fmaf(cv, vn.x, 2.f * b2f(o.x));
    float a1 = fmaf(cv, vn.y, 2.f * b2f(o.y));
    float a2 = fmaf(cv, vn.z, 2.f * b2f(o.z));
    float a3 = fmaf(cv, vn.w, 2.f * b2f(o.w));
    int i = b;
    for (; i + 2 <= e; i += 2) {
        const ushort4 v0 = H4[(size_t)es[i] * 64 + lane];
        const ushort4 v1 = H4[(size_t)es[i + 1] * 64 + lane];
        a0 += b2f(v0.x) + b2f(v1.x);
        a1 += b2f(v0.y) + b2f(v1.y);
        a2 += b2f(v0.z) + b2f(v1.z);
        a3 += b2f(v0.w) + b2f(v1.w);
    }
    for (; i < e; ++i) {
        const ushort4 v = H4[(size_t)es[i] * 64 + lane];
        a0 += b2f(v.x); a1 += b2f(v.y); a2 += b2f(v.z); a3 += b2f(v.w);
    }
    reinterpret_cast<ushort4*>(ob)[(size_t)node * 64 + lane] =
        make_ushort4(f2b(a0), f2b(a1), f2b(a2), f2b(a3));
}

__global__ __launch_bounds__(256)
void gatherb_kernel(const ushort* __restrict__ tb, const int* __restrict__ rowptr,
                    const int* __restrict__ es, ushort* __restrict__ ob, int n)
{
    const int node = blockIdx.x * 4 + (threadIdx.x >> 6);
    if (node >= n) return;
    const int lane = threadIdx.x & 63;
    const ushort4* H4 = reinterpret_cast<const ushort4*>(tb);
    const ushort4 o = H4[(size_t)node * 64 + lane];
    float a0 = 2.f * b2f(o.x), a1 = 2.f * b2f(o.y), a2 = 2.f * b2f(o.z), a3 = 2.f * b2f(o.w);
    const int b = rowptr[node], e = rowptr[node + 1];
    int i = b;
    for (; i + 2 <= e; i += 2) {
        const ushort4 v0 = H4[(size_t)es[i] * 64 + lane];
        const ushort4 v1 = H4[(size_t)es[i + 1] * 64 + lane];
        a0 += b2f(v0.x) + b2f(v1.x);
        a1 += b2f(v0.y) + b2f(v1.y);
        a2 += b2f(v0.z) + b2f(v1.z);
        a3 += b2f(v0.w) + b2f(v1.w);
    }
    for (; i < e; ++i) {
        const ushort4 v = H4[(size_t)es[i] * 64 + lane];
        a0 += b2f(v.x); a1 += b2f(v.y); a2 += b2f(v.z); a3 += b2f(v.w);
    }
    reinterpret_cast<ushort4*>(ob)[(size_t)node * 64 + lane] =
        make_ushort4(f2b(a0), f2b(a1), f2b(a2), f2b(a3));
}

// Graph boundaries (batch is sorted)
__global__ void offsets_kernel(const int* __restrict__ batch, int n, int* __restrict__ off)
{
    const int g = blockIdx.x * blockDim.x + threadIdx.x;
    if (g > NG) return;
    int lo = 0, hi = n;
    while (lo < hi) { const int mid = (lo + hi) >> 1; if (batch[mid] < g) lo = mid + 1; else hi = mid; }
    off[g] = lo;
}

// LN normalize: bf16 z -> bf16 gr slice0 (of [N][512]) + bf16(z + vn2[batch]) for layer 1
__global__ void norm0f_kernel(const ushort* __restrict__ zb, const float* __restrict__ sfin,
                              const float* __restrict__ vn2, const int* __restrict__ batch,
                              ushort* __restrict__ grs, ushort* __restrict__ tb, int n)
{
    const size_t i4 = (size_t)blockIdx.x * blockDim.x + threadIdx.x;
    if (i4 >= (size_t)n * 64) return;
    const float m = sfin[0], rs = sfin[1];
    const int row = (int)(i4 >> 6), c4 = (int)(i4 & 63);
    const ushort4 u = reinterpret_cast<const ushort4*>(zb)[i4];
    const float z0 = (b2f(u.x) - m) * rs, z1 = (b2f(u.y) - m) * rs,
                z2 = (b2f(u.z) - m) * rs, z3 = (b2f(u.w) - m) * rs;
    reinterpret_cast<ushort4*>(grs)[(size_t)row * 128 + c4] =
        make_ushort4(f2b(z0), f2b(z1), f2b(z2), f2b(z3));
    const int g = batch[row];
    const float4 e = reinterpret_cast<const float4*>(vn2 + (size_t)g * 256)[c4];
    reinterpret_cast<ushort4*>(tb)[i4] =
        make_ushort4(f2b(z0 + e.x), f2b(z1 + e.y), f2b(z2 + e.z), f2b(z3 + e.w));
}

// LN normalize: bf16 z -> bf16 gr slice1
__global__ void norm1b_kernel(const ushort* __restrict__ zb, const float* __restrict__ sfin,
                              ushort* __restrict__ grs, int n)
{
    const size_t i4 = (size_t)blockIdx.x * blockDim.x + threadIdx.x;
    if (i4 >= (size_t)n * 64) return;
    const float m = sfin[0], rs = sfin[1];
    const int row = (int)(i4 >> 6), c4 = (int)(i4 & 63);
    const ushort4 u = reinterpret_cast<const ushort4*>(zb)[i4];
    reinterpret_cast<ushort4*>(grs)[(size_t)row * 128 + 64 + c4] =
        make_ushort4(f2b((b2f(u.x) - m) * rs), f2b((b2f(u.y) - m) * rs),
                     f2b((b2f(u.z) - m) * rs), f2b((b2f(u.w) - m) * rs));
}

// FUSED virtual-node update (reads h0 from bf16 B1)
__global__ __launch_bounds__(256)
void vnall_kernel(const ushort* __restrict__ hb, const int* __restrict__ off,
                  const float* __restrict__ vn_emb,
                  const float* __restrict__ W1, const float* __restrict__ bb1,
                  const float* __restrict__ W2, const float* __restrict__ bb2,
                  float* __restrict__ vn2)
{
    __shared__ float r1[256];
    __shared__ float r2[512];
    const int g = blockIdx.x, t = threadIdx.x;
    const int i0 = off[g], i1 = off[g + 1];
    float s = 0.f;
    for (int i = i0; i < i1; ++i) s += b2f(hb[(size_t)i * 256 + t]);
    r1[t] = s + vn_emb[t];
    __syncthreads();
    float a0 = 0.f, a1 = 0.f;
    for (int k = 0; k < 256; ++k) {
        const float rv = r1[k];
        a0 = fmaf(rv, W1[(size_t)k * 512 + t], a0);
        a1 = fmaf(rv, W1[(size_t)k * 512 + 256 + t], a1);
    }
    r2[t]       = fmaxf((a0 + bb1[t]) * BNS, 0.f);
    r2[t + 256] = fmaxf((a1 + bb1[256 + t]) * BNS, 0.f);
    __syncthreads();
    float a = 0.f;
    for (int k = 0; k < 512; ++k) a = fmaf(r2[k], W2[(size_t)k * 256 + t], a);
    vn2[(size_t)g * 256 + t] = fmaxf((a + bb2[t]) * BNS, 0.f);
}

// segment max+mean over [h0(B1) | gr slices] -> readb [NG][1536] = [max | mean]
__global__ __launch_bounds__(256)
void pool_kernel(const ushort* __restrict__ hb, const ushort* __restrict__ g2,
                 const int* __restrict__ off, float* __restrict__ readb)
{
    const int g = blockIdx.x, t = threadIdx.x;
    const int i0 = off[g], i1 = off[g + 1];
    float m0 = -__builtin_inff(), m1 = m0, m2 = m0;
    float s0 = 0.f, s1 = 0.f, s2 = 0.f;
    for (int i = i0; i < i1; ++i) {
        const float v0 = b2f(hb[(size_t)i * 256 + t]);
        const ushort2 z = *reinterpret_cast<const ushort2*>(g2 + (size_t)i * 512 + 2 * t);
        const float v1 = b2f(z.x), v2 = b2f(z.y);
        m0 = fmaxf(m0, v0); m1 = fmaxf(m1, v1); m2 = fmaxf(m2, v2);
        s0 += v0; s1 += v1; s2 += v2;
    }
    const float inv = 1.f / fmaxf((float)(i1 - i0), 1.f);
    float* rb = readb + (size_t)g * 1536;
    rb[t] = m0;
    rb[256 + 2 * t] = m1; rb[256 + 2 * t + 1] = m2;
    rb[768 + t] = s0 * inv;
    rb[1024 + 2 * t] = s1 * inv; rb[1024 + 2 * t + 1] = s2 * inv;
}

// FUSED readout head: 2 graphs per block, 256 blocks (occupancy fix)
__global__ __launch_bounds__(256)
void outg2_kernel(const float* __restrict__ readb, const float* __restrict__ W,
                  const float* __restrict__ b,
                  const float* __restrict__ clsW, const float* __restrict__ clsb,
                  const float* __restrict__ dW, const float* __restrict__ db,
                  float* __restrict__ x5, float* __restrict__ logits, float* __restrict__ ssl)
{
    __shared__ float rows[2][1536];
    __shared__ float x5s[2][256];
    const int g0 = blockIdx.x * 2, t = threadIdx.x;
    for (int i = t; i < 2 * 1536; i += 256) rows[i / 1536][i % 1536] = readb[(size_t)g0 * 1536 + i];
    __syncthreads();
    float a0 = 0.f, a1 = 0.f;
    for (int k = 0; k < 1536; ++k) {
        const float wv = W[(size_t)k * 256 + t];
        a0 = fmaf(rows[0][k], wv, a0);
        a1 = fmaf(rows[1][k], wv, a1);
    }
    const float bb = b[t];
    const float v0 = eluf(a0 + bb), v1 = eluf(a1 + bb);
    x5[(size_t)g0 * 256 + t] = v0;
    x5[(size_t)(g0 + 1) * 256 + t] = v1;
    x5s[0][t] = v0;
    x5s[1][t] = v1;
    __syncthreads();

    const int grp = t >> 5, l32 = t & 31;
    if (grp < 2) {
        float p0 = 0.f, p1 = 0.f;
        for (int c = l32; c < 256; c += 32) {
            const float v = x5s[grp][c];
            p0 = fmaf(v, clsW[c * 2], p0);
            p1 = fmaf(v, clsW[c * 2 + 1], p1);
        }
        float q0 = 0.f, q1 = 0.f, q2 = 0.f;
        for (int c = l32; c < 64; c += 32) {
            q0 = fmaf(x5s[grp][c],       dW[c],       q0);
            q1 = fmaf(x5s[grp][64 + c],  dW[64 + c],  q1);
            q2 = fmaf(x5s[grp][128 + c], dW[128 + c], q2);
        }
        for (int o = 16; o; o >>= 1) {
            p0 += __shfl_down(p0, o, 32); p1 += __shfl_down(p1, o, 32);
            q0 += __shfl_down(q0, o, 32); q1 += __shfl_down(q1, o, 32); q2 += __shfl_down(q2, o, 32);
        }
        if (l32 == 0) {
            const float z0 = p0 + clsb[0], z1 = p1 + clsb[1];
            const float m = fmaxf(z0, z1);
            const float lse = m + logf(expf(z0 - m) + expf(z1 - m));
            logits[(size_t)(g0 + grp) * 2 + 0] = z0 - lse;
            logits[(size_t)(g0 + grp) * 2 + 1] = z1 - lse;
            ssl[(size_t)(g0 + grp) * 3 + 0] = 0.05f + 0.35f / (1.f + expf(-(q0 + db[0])));
            ssl[(size_t)(g0 + grp) * 3 + 1] = 0.05f + 0.35f / (1.f + expf(-(q1 + db[1])));
            ssl[(size_t)(g0 + grp) * 3 + 2] = 0.05f + 0.35f / (1.f + expf(-(q2 + db[2])));
        }
    }
}

// ---------------------------------------------------------------------------
extern "C" void kernel_launch(void* const* d_in, const int* in_sizes, int n_in,
                              void* d_out, int out_size, void* d_ws, size_t ws_size,
                              hipStream_t stream)
{
    const float* x      = (const float*)d_in[0];
    const int*   eidx   = (const int*)d_in[1];
    const int*   batch  = (const int*)d_in[2];
    const float* lin1_W = (const float*)d_in[3];
    const float* lin1_b = (const float*)d_in[4];
    const float* g0W1   = (const float*)d_in[5];
    const float* g0b1   = (const float*)d_in[6];
    const float* g0W2   = (const float*)d_in[7];
    const float* g0b2   = (const float*)d_in[8];
    const float* g1W1   = (const float*)d_in[9];
    const float* g1b1   = (const float*)d_in[10];
    const float* g1W2   = (const float*)d_in[11];
    const float* g1b2   = (const float*)d_in[12];
    const float* vn_emb = (const float*)d_in[13];
    const float* vnW1   = (const float*)d_in[14];
    const float* vnb1   = (const float*)d_in[15];
    const float* vnW2   = (const float*)d_in[16];
    const float* vnb2   = (const float*)d_in[17];
    const float* loW    = (const float*)d_in[18];
    const float* lob    = (const float*)d_in[19];
    const float* clsW   = (const float*)d_in[20];
    const float* clsb   = (const float*)d_in[21];
    const float* dhW    = (const float*)d_in[22];
    const float* dhb    = (const float*)d_in[23];

    const int N = in_sizes[2];        // 50000 nodes
    const int E = in_sizes[1] / 2;    // 800000 edges
    const int* esrc = eidx;
    const int* edst = eidx + E;

    float* out = (float*)d_out;
    float* out_logits = out;                                     // [NG,2]
    float* out_x5     = out + (size_t)NG * 2;                    // [NG,256]
    float* out_ssl    = out + (size_t)NG * 2 + (size_t)NG * 256; // [NG,3]

    // --- workspace carve (256B aligned; sacc(2KB)+cnt adjacent, one memset) ---
    char* p = (char*)d_ws;
    auto carve = [&](size_t bytes) { char* r = p; p += (bytes + 255) & ~(size_t)255; return (void*)r; };
    double* sacc   = (double*)carve(256 * sizeof(double));          // 64 buckets x2 x 2 layers
    int*    cnt    = (int*)   carve((size_t)N * sizeof(int));
    float*  sfin   = (float*) carve(4 * sizeof(float));
    int*    goff   = (int*)   carve((NG + 1) * sizeof(int));
    int*    rowptr = (int*)   carve((size_t)(N + 1) * sizeof(int));
    int*    cursor = (int*)   carve((size_t)N * sizeof(int));
    int*    bsum   = (int*)   carve(256 * sizeof(int));
    int*    es     = (int*)   carve((size_t)E * sizeof(int));
    ushort* gr2    = (ushort*)carve((size_t)N * 512 * sizeof(ushort)); // [z1|z2] bf16
    ushort* xb     = (ushort*)carve((size_t)N * 128 * sizeof(ushort));
    ushort* B1     = (ushort*)carve((size_t)N * 256 * sizeof(ushort)); // h0 (kept for pool)
    ushort* B2     = (ushort*)carve((size_t)N * 256 * sizeof(ushort));
    ushort* B3     = (ushort*)carve((size_t)N * 256 * sizeof(ushort));
    ushort* Wt1    = (ushort*)carve(256 * 128 * sizeof(ushort));
    ushort* Wt0a   = (ushort*)carve(256 * 256 * sizeof(ushort));
    ushort* Wt0b   = (ushort*)carve(256 * 256 * sizeof(ushort));
    ushort* Wtbd1  = (ushort*)carve(16384 * sizeof(ushort));
    ushort* Wtbd2  = (ushort*)carve(16384 * sizeof(ushort));
    float*  vn2    = (float*) carve((size_t)NG * 256 * sizeof(float));
    float*  readb  = (float*) carve((size_t)NG * 1536 * sizeof(float));

    hipMemsetAsync(sacc, 0, 2048 + (size_t)N * sizeof(int), stream);

    const int mt = (N + 127) / 128;
    const int vecGrid = (N * 64 + 255) / 256;
    const int eGrid = (E + 255) / 256;
    const int gatherGrid = (N + 3) / 4;
    const int nb = (N + 255) / 256;     // scan blocks (196 <= 256)
    const int prepTotal = N * 32 + 196608;

    // ---- CSR build (count + 3-level scan + fill) ----
    count_kernel<<<eGrid, 256, 0, stream>>>(edst, cnt, E);
    scan1_kernel<<<nb, 256, 0, stream>>>(cnt, bsum, N);
    scan2_kernel<<<1, 256, 0, stream>>>(bsum, rowptr, nb, N);
    scan3_kernel<<<nb, 256, 0, stream>>>(cnt, bsum, rowptr, cursor, N);
    fill_kernel<<<eGrid, 256, 0, stream>>>(esrc, edst, cursor, es, E);

    // ---- all weight/input prep ----
    prep_kernel<<<(prepTotal + 255) / 256, 256, 0, stream>>>(
        x, lin1_W, g0W1, g0W2, g1W1, g1W2, xb, Wt1, Wt0a, Wt0b, Wtbd1, Wtbd2, N * 32);

    // h0 = elu(x @ lin1_W + b) -> B1 (bf16 only)
    tgemm_kernel<2><<<mt, 512, 0, stream>>>(xb, 128, Wt1, lin1_b, B1, N);
    offsets_kernel<<<3, 256, 0, stream>>>(batch, N, goff);

    // ---- virtual node update (reads B1 bf16) ----
    vnall_kernel<<<NG, 256, 0, stream>>>(B1, goff, vn_emb, vnW1, vnb1, vnW2, vnb2, vn2);

    // ---- layer 0 ----
    gather0b_kernel<<<gatherGrid, 256, 0, stream>>>(B1, rowptr, es, vn_emb, B2, N);
    mlp0_kernel<<<mt, 512, 0, stream>>>(B2, Wt0a, Wt0b, g0b1, g0b2, B3, N, sacc);
    finalize_kernel<<<1, 64, 0, stream>>>(sacc, sfin, (double)N * 256.0);
    norm0f_kernel<<<vecGrid, 256, 0, stream>>>(B3, sfin, vn2, batch, gr2, B2, N);

    // ---- layer 1 ----
    gatherb_kernel<<<gatherGrid, 256, 0, stream>>>(B2, rowptr, es, B3, N);
    bd2_kernel<<<dim3(mt, 4), 256, 0, stream>>>(B3, Wtbd1, Wtbd2, g1b1, g1b2, B2, N, sacc + 128);
    finalize_kernel<<<1, 64, 0, stream>>>(sacc + 128, sfin + 2, (double)N * 256.0);
    norm1b_kernel<<<vecGrid, 256, 0, stream>>>(B2, sfin + 2, gr2, N);

    // ---- readout ----
    pool_kernel<<<NG, 256, 0, stream>>>(B1, gr2, goff, readb);
    outg2_kernel<<<NG / 2, 256, 0, stream>>>(readb, loW, lob, clsW, clsb, dhW, dhb,
                                             out_x5, out_logits, out_ssl);
}

// Round 13
// 504.331 us; speedup vs baseline: 1.7128x; 1.0160x over previous
//
#include <hip/hip_runtime.h>

static constexpr int NG = 512;       // graphs
static constexpr float LN_EPS = 1e-5f;
static constexpr float BNS = 0.9999950000374997f; // rsqrt(1 + 1e-5) for BatchNorm eval

__device__ __forceinline__ float eluf(float v) { return v > 0.f ? v : expm1f(v); }

typedef __attribute__((ext_vector_type(8))) short bf16x8;
typedef __attribute__((ext_vector_type(4))) float f32x4;

__device__ __forceinline__ ushort f2b(float f) {   // f32 -> bf16 RNE
    union { float f; unsigned u; } v; v.f = f;
    const unsigned u = v.u;
    return (ushort)((u + 0x7FFFu + ((u >> 16) & 1u)) >> 16);
}
__device__ __forceinline__ float b2f(ushort b) {
    union { unsigned u; float f; } v; v.u = ((unsigned)b) << 16;
    return v.f;
}

// async global->LDS, 16B per lane. LDS dest lane-contiguous (linear).
__device__ __forceinline__ void gl16(const ushort* g, ushort* l) {
    __builtin_amdgcn_global_load_lds(
        (const __attribute__((address_space(1))) void*)g,
        (__attribute__((address_space(3))) void*)l, 16, 0, 0);
}

// ---------------------------------------------------------------------------
// MFMA GEMM: out = elu(A[n x K]@Wt^T + b). BM=128, BN=256, BK=64.
// WB16: bf16 out via LDS-transpose coalesced stores. WF32: f32 out scattered.
// Used for lin1 (KSTEPS=2) and the readout x5 GEMM (KSTEPS=24).
// ---------------------------------------------------------------------------
template<int KSTEPS, bool WB16, bool WF32>
__global__ __launch_bounds__(512)
void tgemm_kernel(const ushort* __restrict__ Ab, int ldab,
                  const ushort* __restrict__ Wt,   // [256][KSTEPS*64]
                  const float* __restrict__ bias,
                  ushort* __restrict__ Cb, float* __restrict__ Cf,
                  int n)
{
    __shared__ __align__(16) ushort sbuf[32768];   // 64 KB
    ushort* As = sbuf;          // 128*64
    ushort* Bs = sbuf + 8192;   // 256*64

    const int tid = threadIdx.x;
    const int lane = tid & 63;
    const int wv = tid >> 6;
    const int wr = wv >> 1, wc = wv & 1;
    const int r0 = blockIdx.x * 128;
    const int colL = lane & 15;
    const int lr = lane >> 4;

    f32x4 acc[2][8];
#pragma unroll
    for (int rt = 0; rt < 2; ++rt)
#pragma unroll
        for (int ct = 0; ct < 8; ++ct) acc[rt][ct] = (f32x4){0.f, 0.f, 0.f, 0.f};

    for (int ks = 0; ks < KSTEPS; ++ks) {
#pragma unroll
        for (int it = 0; it < 2; ++it) {           // A
            const int i = it * 512 + tid;
            const int row = i >> 3, cb = i & 7;
            const int rg = min(r0 + row, n - 1);
            gl16(Ab + (size_t)rg * ldab + ks * 64 + ((cb ^ (row & 7)) * 8), As + i * 8);
        }
#pragma unroll
        for (int it = 0; it < 4; ++it) {           // B
            const int i = it * 512 + tid;
            const int col = i >> 3, cb = i & 7;
            gl16(Wt + (size_t)col * (KSTEPS * 64) + ks * 64 + ((cb ^ (col & 7)) * 8), Bs + i * 8);
        }
        __syncthreads();

        bf16x8 af[2][2];
#pragma unroll
        for (int rt = 0; rt < 2; ++rt)
#pragma unroll
            for (int kk = 0; kk < 2; ++kk) {
                const int row = wr * 32 + rt * 16 + colL;
                const int blk = kk * 4 + lr;
                af[rt][kk] = *reinterpret_cast<const bf16x8*>(As + row * 64 + ((blk ^ (row & 7)) * 8));
            }
#pragma unroll
        for (int ct = 0; ct < 8; ++ct)
#pragma unroll
            for (int kk = 0; kk < 2; ++kk) {
                const int col = wc * 128 + ct * 16 + colL;
                const int blk = kk * 4 + lr;
                const bf16x8 bf = *reinterpret_cast<const bf16x8*>(Bs + col * 64 + ((blk ^ (col & 7)) * 8));
                acc[0][ct] = __builtin_amdgcn_mfma_f32_16x16x32_bf16(af[0][kk], bf, acc[0][ct], 0, 0, 0);
                acc[1][ct] = __builtin_amdgcn_mfma_f32_16x16x32_bf16(af[1][kk], bf, acc[1][ct], 0, 0, 0);
            }
        __syncthreads();
    }

    float bv[8];
#pragma unroll
    for (int ct = 0; ct < 8; ++ct) bv[ct] = bias[wc * 128 + ct * 16 + colL];

    ushort* eb = sbuf + wv * 4096;   // 32 rows x 128 cols
#pragma unroll
    for (int rt = 0; rt < 2; ++rt)
#pragma unroll
        for (int ct = 0; ct < 8; ++ct)
#pragma unroll
            for (int r = 0; r < 4; ++r) {
                const float v = eluf(acc[rt][ct][r] + bv[ct]);
                if constexpr (WB16)
                    eb[(rt * 16 + lr * 4 + r) * 128 + ct * 16 + colL] = f2b(v);
                if constexpr (WF32) {
                    const int row = r0 + wr * 32 + rt * 16 + lr * 4 + r;
                    const int col = wc * 128 + ct * 16 + colL;
                    if (row < n) Cf[(size_t)row * 256 + col] = v;
                }
            }
    if constexpr (WB16) {
#pragma unroll
        for (int j = 0; j < 8; ++j) {
            const int idx = j * 64 + lane;
            const int lrow = idx >> 4, c8 = idx & 15;
            const int grow = r0 + wr * 32 + lrow;
            if (grow < n)
                *reinterpret_cast<bf16x8*>(Cb + (size_t)grow * 256 + wc * 128 + c8 * 8) =
                    *reinterpret_cast<const bf16x8*>(eb + lrow * 128 + c8 * 8);
        }
    }
}

// ---------------------------------------------------------------------------
// FUSED dense GIN MLP (layer 0). Stats -> 64 atomic buckets (blockIdx&63).
// ---------------------------------------------------------------------------
__global__ __launch_bounds__(512)
void mlp0_kernel(const ushort* __restrict__ Ab,    // [n][256]
                 const ushort* __restrict__ W1t,   // [256][256]
                 const ushort* __restrict__ W2t,
                 const float* __restrict__ b1, const float* __restrict__ b2,
                 ushort* __restrict__ Cb,
                 int n, double* __restrict__ stats)
{
    __shared__ __align__(16) ushort As[8192];
    __shared__ __align__(16) ushort Bs[16384];
    __shared__ __align__(16) ushort Z[32768];

    const int tid = threadIdx.x;
    const int lane = tid & 63;
    const int wv = tid >> 6;
    const int wr = wv >> 1, wc = wv & 1;
    const int r0 = blockIdx.x * 128;
    const int colL = lane & 15;
    const int lr = lane >> 4;

    f32x4 acc[2][8];
#pragma unroll
    for (int rt = 0; rt < 2; ++rt)
#pragma unroll
        for (int ct = 0; ct < 8; ++ct) acc[rt][ct] = (f32x4){0.f, 0.f, 0.f, 0.f};

    // ---- stage 1: z = relu(A @ W1 + b1) ----
    for (int ks = 0; ks < 4; ++ks) {
#pragma unroll
        for (int it = 0; it < 2; ++it) {
            const int i = it * 512 + tid;
            const int row = i >> 3, cb = i & 7;
            const int rg = min(r0 + row, n - 1);
            gl16(Ab + (size_t)rg * 256 + ks * 64 + ((cb ^ (row & 7)) * 8), As + i * 8);
        }
#pragma unroll
        for (int it = 0; it < 4; ++it) {
            const int i = it * 512 + tid;
            const int col = i >> 3, cb = i & 7;
            gl16(W1t + (size_t)col * 256 + ks * 64 + ((cb ^ (col & 7)) * 8), Bs + i * 8);
        }
        __syncthreads();
        bf16x8 af[2][2];
#pragma unroll
        for (int rt = 0; rt < 2; ++rt)
#pragma unroll
            for (int kk = 0; kk < 2; ++kk) {
                const int row = wr * 32 + rt * 16 + colL;
                const int blk = kk * 4 + lr;
                af[rt][kk] = *reinterpret_cast<const bf16x8*>(As + row * 64 + ((blk ^ (row & 7)) * 8));
            }
#pragma unroll
        for (int ct = 0; ct < 8; ++ct)
#pragma unroll
            for (int kk = 0; kk < 2; ++kk) {
                const int col = wc * 128 + ct * 16 + colL;
                const int blk = kk * 4 + lr;
                const bf16x8 bf = *reinterpret_cast<const bf16x8*>(Bs + col * 64 + ((blk ^ (col & 7)) * 8));
                acc[0][ct] = __builtin_amdgcn_mfma_f32_16x16x32_bf16(af[0][kk], bf, acc[0][ct], 0, 0, 0);
                acc[1][ct] = __builtin_amdgcn_mfma_f32_16x16x32_bf16(af[1][kk], bf, acc[1][ct], 0, 0, 0);
            }
        __syncthreads();
    }
#pragma unroll
    for (int ct = 0; ct < 8; ++ct) {
        const float bvv = b1[wc * 128 + ct * 16 + colL];
#pragma unroll
        for (int rt = 0; rt < 2; ++rt)
#pragma unroll
            for (int r = 0; r < 4; ++r) {
                const float v = fmaxf(acc[rt][ct][r] + bvv, 0.f);
                const int zrow = wr * 32 + rt * 16 + lr * 4 + r;
                const int zcol = wc * 128 + ct * 16 + colL;
                const int chunk = zcol >> 3;
                const int sw = (chunk & 24) | ((chunk & 7) ^ (zrow & 7));
                Z[zrow * 256 + sw * 8 + (zcol & 7)] = f2b(v);
            }
    }
    __syncthreads();

    // ---- stage 2: out = elu(z @ W2 + b2) ----
#pragma unroll
    for (int rt = 0; rt < 2; ++rt)
#pragma unroll
        for (int ct = 0; ct < 8; ++ct) acc[rt][ct] = (f32x4){0.f, 0.f, 0.f, 0.f};

    for (int ks = 0; ks < 4; ++ks) {
#pragma unroll
        for (int it = 0; it < 4; ++it) {
            const int i = it * 512 + tid;
            const int col = i >> 3, cb = i & 7;
            gl16(W2t + (size_t)col * 256 + ks * 64 + ((cb ^ (col & 7)) * 8), Bs + i * 8);
        }
        __syncthreads();
        bf16x8 zf[2][2];
#pragma unroll
        for (int rt = 0; rt < 2; ++rt)
#pragma unroll
            for (int kk = 0; kk < 2; ++kk) {
                const int zrow = wr * 32 + rt * 16 + colL;
                const int chunk = ks * 8 + kk * 4 + lr;
                const int sw = (chunk & 24) | ((chunk & 7) ^ (zrow & 7));
                zf[rt][kk] = *reinterpret_cast<const bf16x8*>(Z + zrow * 256 + sw * 8);
            }
#pragma unroll
        for (int ct = 0; ct < 8; ++ct)
#pragma unroll
            for (int kk = 0; kk < 2; ++kk) {
                const int col = wc * 128 + ct * 16 + colL;
                const int blk = kk * 4 + lr;
                const bf16x8 bf = *reinterpret_cast<const bf16x8*>(Bs + col * 64 + ((blk ^ (col & 7)) * 8));
                acc[0][ct] = __builtin_amdgcn_mfma_f32_16x16x32_bf16(zf[0][kk], bf, acc[0][ct], 0, 0, 0);
                acc[1][ct] = __builtin_amdgcn_mfma_f32_16x16x32_bf16(zf[1][kk], bf, acc[1][ct], 0, 0, 0);
            }
        __syncthreads();
    }

    float bv[8];
#pragma unroll
    for (int ct = 0; ct < 8; ++ct) bv[ct] = b2[wc * 128 + ct * 16 + colL];
    ushort* eb = Z + wv * 4096;
    float s = 0.f, ss = 0.f;
#pragma unroll
    for (int rt = 0; rt < 2; ++rt)
#pragma unroll
        for (int ct = 0; ct < 8; ++ct)
#pragma unroll
            for (int r = 0; r < 4; ++r) {
                const float v = eluf(acc[rt][ct][r] + bv[ct]);
                eb[(rt * 16 + lr * 4 + r) * 128 + ct * 16 + colL] = f2b(v);
                const int row = r0 + wr * 32 + rt * 16 + lr * 4 + r;
                if (row < n) { s += v; ss += v * v; }
            }
#pragma unroll
    for (int j = 0; j < 8; ++j) {
        const int idx = j * 64 + lane;
        const int lrow = idx >> 4, c8 = idx & 15;
        const int grow = r0 + wr * 32 + lrow;
        if (grow < n)
            *reinterpret_cast<bf16x8*>(Cb + (size_t)grow * 256 + wc * 128 + c8 * 8) =
                *reinterpret_cast<const bf16x8*>(eb + lrow * 128 + c8 * 8);
    }
    double ds = (double)s, dss = (double)ss;
    for (int o = 32; o; o >>= 1) { ds += __shfl_down(ds, o, 64); dss += __shfl_down(dss, o, 64); }
    if (lane == 0) {
        const int bkt = (blockIdx.x & 63) * 2;
        unsafeAtomicAdd(&stats[bkt], ds); unsafeAtomicAdd(&stats[bkt + 1], dss);
    }
}

// ---------------------------------------------------------------------------
// FUSED block-diagonal GIN MLP (layer 1). Bucketed stats.
// ---------------------------------------------------------------------------
__global__ __launch_bounds__(256)
void bd2_kernel(const ushort* __restrict__ Ab,    // [n][256]
                const ushort* __restrict__ W1t,   // [4][64 col][64 k]
                const ushort* __restrict__ W2t,
                const float* __restrict__ b1, const float* __restrict__ b2,
                ushort* __restrict__ Cb,
                int n, double* __restrict__ stats)
{
    __shared__ __align__(16) ushort As[8192];
    __shared__ __align__(16) ushort B1s[4096];
    __shared__ __align__(16) ushort B2s[4096];

    const int tid = threadIdx.x;
    const int lane = tid & 63;
    const int wv = tid >> 6;
    const int ch = blockIdx.y;
    const int r0 = blockIdx.x * 128;
    const int colL = lane & 15;
    const int lr = lane >> 4;

#pragma unroll
    for (int it = 0; it < 4; ++it) {             // A
        const int i = it * 256 + tid;
        const int row = i >> 3, cb = i & 7;
        const int rg = min(r0 + row, n - 1);
        gl16(Ab + (size_t)rg * 256 + ch * 64 + ((cb ^ (row & 7)) * 8), As + i * 8);
    }
#pragma unroll
    for (int it = 0; it < 2; ++it) {             // W1
        const int i = it * 256 + tid;
        const int col = i >> 3, cb = i & 7;
        gl16(W1t + ch * 4096 + col * 64 + ((cb ^ (col & 7)) * 8), B1s + i * 8);
    }
#pragma unroll
    for (int it = 0; it < 2; ++it) {             // W2
        const int i = it * 256 + tid;
        const int col = i >> 3, cb = i & 7;
        gl16(W2t + ch * 4096 + col * 64 + ((cb ^ (col & 7)) * 8), B2s + i * 8);
    }
    __syncthreads();

    bf16x8 af[2][2];
#pragma unroll
    for (int rt = 0; rt < 2; ++rt)
#pragma unroll
        for (int kk = 0; kk < 2; ++kk) {
            const int row = wv * 32 + rt * 16 + colL;
            const int blk = kk * 4 + lr;
            af[rt][kk] = *reinterpret_cast<const bf16x8*>(As + row * 64 + ((blk ^ (row & 7)) * 8));
        }
    f32x4 acc[2][4];
#pragma unroll
    for (int rt = 0; rt < 2; ++rt)
#pragma unroll
        for (int ct = 0; ct < 4; ++ct) acc[rt][ct] = (f32x4){0.f, 0.f, 0.f, 0.f};
#pragma unroll
    for (int ct = 0; ct < 4; ++ct)
#pragma unroll
        for (int kk = 0; kk < 2; ++kk) {
            const int col = ct * 16 + colL;
            const int blk = kk * 4 + lr;
            const bf16x8 bf = *reinterpret_cast<const bf16x8*>(B1s + col * 64 + ((blk ^ (col & 7)) * 8));
            acc[0][ct] = __builtin_amdgcn_mfma_f32_16x16x32_bf16(af[0][kk], bf, acc[0][ct], 0, 0, 0);
            acc[1][ct] = __builtin_amdgcn_mfma_f32_16x16x32_bf16(af[1][kk], bf, acc[1][ct], 0, 0, 0);
        }

    ushort* Zw = As + wv * 2048;    // wave-private 32x64
#pragma unroll
    for (int rt = 0; rt < 2; ++rt)
#pragma unroll
        for (int ct = 0; ct < 4; ++ct) {
            const float bvv = b1[ch * 64 + ct * 16 + colL];
#pragma unroll
            for (int r = 0; r < 4; ++r) {
                const float v = fmaxf(acc[rt][ct][r] + bvv, 0.f);
                const int zrow = rt * 16 + lr * 4 + r;
                const int zcol = ct * 16 + colL;
                Zw[zrow * 64 + (((zcol >> 3) ^ (zrow & 7)) * 8) + (zcol & 7)] = f2b(v);
            }
        }

    bf16x8 zf[2][2];
#pragma unroll
    for (int rt = 0; rt < 2; ++rt)
#pragma unroll
        for (int kk = 0; kk < 2; ++kk) {
            const int zrow = rt * 16 + colL;
            const int blk = kk * 4 + lr;
            zf[rt][kk] = *reinterpret_cast<const bf16x8*>(Zw + zrow * 64 + ((blk ^ (zrow & 7)) * 8));
        }
#pragma unroll
    for (int rt = 0; rt < 2; ++rt)
#pragma unroll
        for (int ct = 0; ct < 4; ++ct) acc[rt][ct] = (f32x4){0.f, 0.f, 0.f, 0.f};
#pragma unroll
    for (int ct = 0; ct < 4; ++ct)
#pragma unroll
        for (int kk = 0; kk < 2; ++kk) {
            const int col = ct * 16 + colL;
            const int blk = kk * 4 + lr;
            const bf16x8 bf = *reinterpret_cast<const bf16x8*>(B2s + col * 64 + ((blk ^ (col & 7)) * 8));
            acc[0][ct] = __builtin_amdgcn_mfma_f32_16x16x32_bf16(zf[0][kk], bf, acc[0][ct], 0, 0, 0);
            acc[1][ct] = __builtin_amdgcn_mfma_f32_16x16x32_bf16(zf[1][kk], bf, acc[1][ct], 0, 0, 0);
        }

    float s = 0.f, ss = 0.f;
#pragma unroll
    for (int rt = 0; rt < 2; ++rt)
#pragma unroll
        for (int ct = 0; ct < 4; ++ct) {
            const float bvv = b2[ch * 64 + ct * 16 + colL];
#pragma unroll
            for (int r = 0; r < 4; ++r) {
                const float v = eluf(acc[rt][ct][r] + bvv);
                Zw[(rt * 16 + lr * 4 + r) * 64 + ct * 16 + colL] = f2b(v);
                const int row = r0 + wv * 32 + rt * 16 + lr * 4 + r;
                if (row < n) { s += v; ss += v * v; }
            }
        }
#pragma unroll
    for (int j = 0; j < 4; ++j) {
        const int idx = j * 64 + lane;
        const int lrow = idx >> 3, c8 = idx & 7;
        const int grow = r0 + wv * 32 + lrow;
        if (grow < n)
            *reinterpret_cast<bf16x8*>(Cb + (size_t)grow * 256 + ch * 64 + c8 * 8) =
                *reinterpret_cast<const bf16x8*>(Zw + lrow * 64 + c8 * 8);
    }

    double ds = (double)s, dss = (double)ss;
    for (int o = 32; o; o >>= 1) { ds += __shfl_down(ds, o, 64); dss += __shfl_down(dss, o, 64); }
    if (lane == 0) {
        const int bkt = ((blockIdx.x + blockIdx.y * 16) & 63) * 2;
        unsafeAtomicAdd(&stats[bkt], ds); unsafeAtomicAdd(&stats[bkt + 1], dss);
    }
}

// reduce 64 stat buckets -> sfin {mean, rsqrt}
__global__ __launch_bounds__(64)
void finalize_kernel(const double* __restrict__ sacc, float* __restrict__ sfin, double M)
{
    const int t = threadIdx.x;
    double s = sacc[t * 2], ss = sacc[t * 2 + 1];
    for (int o = 32; o; o >>= 1) { s += __shfl_down(s, o, 64); ss += __shfl_down(ss, o, 64); }
    if (t == 0) {
        const double mean = s / M;
        double var = ss / M - mean * mean;
        if (var < 0.0) var = 0.0;
        sfin[0] = (float)mean;
        sfin[1] = (float)(1.0 / sqrt(var + (double)LN_EPS));
    }
}

// ---------------------------------------------------------------------------
// ONE prep kernel: x->bf16 + all weight transposes (incl. loW -> [256][1536])
// ---------------------------------------------------------------------------
__global__ void prep_kernel(const float* __restrict__ x,
                            const float* __restrict__ lin1W,
                            const float* __restrict__ g0W1, const float* __restrict__ g0W2,
                            const float* __restrict__ g1W1, const float* __restrict__ g1W2,
                            const float* __restrict__ loW,
                            ushort* __restrict__ xb,
                            ushort* __restrict__ Wt1,
                            ushort* __restrict__ Wt0a, ushort* __restrict__ Wt0b,
                            ushort* __restrict__ Wtbd1, ushort* __restrict__ Wtbd2,
                            ushort* __restrict__ loWt,
                            int n32)
{
    const int i = blockIdx.x * 256 + threadIdx.x;
    if (i < n32) {
        const float4 v = reinterpret_cast<const float4*>(x)[i];
        reinterpret_cast<ushort4*>(xb)[i] = make_ushort4(f2b(v.x), f2b(v.y), f2b(v.z), f2b(v.w));
        return;
    }
    int j = i - n32;
    if (j < 32768) {                         // Wt1 [256][128]
        const int c = j >> 7, k = j & 127;
        Wt1[j] = f2b(lin1W[(size_t)k * 256 + c]);
    } else if (j < 98304) {                  // Wt0a [256][256]
        j -= 32768;
        const int c = j >> 8, k = j & 255;
        Wt0a[j] = f2b(g0W1[(size_t)k * 256 + c]);
    } else if (j < 163840) {                 // Wt0b
        j -= 98304;
        const int c = j >> 8, k = j & 255;
        Wt0b[j] = f2b(g0W2[(size_t)k * 256 + c]);
    } else if (j < 180224) {                 // Wtbd1 [4][64][64]
        j -= 163840;
        const int ch = j >> 12, r = j & 4095, cw = r >> 6, k = r & 63;
        Wtbd1[j] = f2b(g1W1[ch * 4096 + k * 64 + cw]);
    } else if (j < 196608) {                 // Wtbd2
        j -= 180224;
        const int ch = j >> 12, r = j & 4095, cw = r >> 6, k = r & 63;
        Wtbd2[j] = f2b(g1W2[ch * 4096 + k * 64 + cw]);
    } else if (j < 196608 + 393216) {        // loWt [256][1536]
        j -= 196608;
        const int c = j / 1536, k = j - c * 1536;
        loWt[j] = f2b(loW[(size_t)k * 256 + c]);
    }
}

// ---------------------------------------------------------------------------
// CSR construction: count + 3-level scan + fill
// ---------------------------------------------------------------------------
__global__ void count_kernel(const int* __restrict__ dst, int* __restrict__ cnt, int nE)
{
    const int e = blockIdx.x * 256 + threadIdx.x;
    if (e < nE) atomicAdd(&cnt[dst[e]], 1);
}

__global__ __launch_bounds__(256)
void scan1_kernel(const int* __restrict__ cnt, int* __restrict__ bsum, int n)
{
    __shared__ int ws[4];
    const int i = blockIdx.x * 256 + threadIdx.x;
    int v = (i < n) ? cnt[i] : 0;
    for (int o = 32; o; o >>= 1) v += __shfl_down(v, o, 64);
    if ((threadIdx.x & 63) == 0) ws[threadIdx.x >> 6] = v;
    __syncthreads();
    if (threadIdx.x == 0) bsum[blockIdx.x] = ws[0] + ws[1] + ws[2] + ws[3];
}

__global__ __launch_bounds__(256)
void scan2_kernel(int* __restrict__ bsum, int* __restrict__ rowptr, int nb, int n)
{
    __shared__ int sh[256];
    const int t = threadIdx.x;
    const int v = (t < nb) ? bsum[t] : 0;
    sh[t] = v;
    __syncthreads();
    for (int o = 1; o < 256; o <<= 1) {
        const int u = (t >= o) ? sh[t - o] : 0;
        __syncthreads();
        sh[t] += u;
        __syncthreads();
    }
    if (t < nb) bsum[t] = sh[t] - v;    // exclusive
    if (t == 255) rowptr[n] = sh[255];
}

__global__ __launch_bounds__(256)
void scan3_kernel(const int* __restrict__ cnt, const int* __restrict__ bsum,
                  int* __restrict__ rowptr, int* __restrict__ cursor, int n)
{
    __shared__ int sh[256];
    const int t = threadIdx.x;
    const int i = blockIdx.x * 256 + t;
    const int v = (i < n) ? cnt[i] : 0;
    sh[t] = v;
    __syncthreads();
    for (int o = 1; o < 256; o <<= 1) {
        const int u = (t >= o) ? sh[t - o] : 0;
        __syncthreads();
        sh[t] += u;
        __syncthreads();
    }
    if (i < n) {
        const int ex = bsum[blockIdx.x] + sh[t] - v;
        rowptr[i] = ex;
        cursor[i] = ex;
    }
}

__global__ void fill_kernel(const int* __restrict__ src, const int* __restrict__ dst,
                            int* __restrict__ cursor, int* __restrict__ es, int nE)
{
    const int e = blockIdx.x * 256 + threadIdx.x;
    if (e >= nE) return;
    const int p = atomicAdd(&cursor[dst[e]], 1);
    es[p] = src[e];
}

// ---------------------------------------------------------------------------
// Gathers (bf16 rows, one wave per node)
// ---------------------------------------------------------------------------
__global__ __launch_bounds__(256)
void gather0b_kernel(const ushort* __restrict__ hb, const int* __restrict__ rowptr,
                     const int* __restrict__ es, const float* __restrict__ vn_emb,
                     ushort* __restrict__ ob, int n)
{
    const int node = blockIdx.x * 4 + (threadIdx.x >> 6);
    if (node >= n) return;
    const int lane = threadIdx.x & 63;
    const ushort4* H4 = reinterpret_cast<const ushort4*>(hb);
    const ushort4 o = H4[(size_t)node * 64 + lane];
    const int b = rowptr[node], e = rowptr[node + 1];
    const float4 vn = reinterpret_cast<const float4*>(vn_emb)[lane];
    const float cv = (float)(2 + (e - b));
    float a0 = fmaf(cv, vn.x, 2.f * b2f(o.x));
    float a1 = fmaf(cv, vn.y, 2.f * b2f(o.y));
    float a2 = fmaf(cv, vn.z, 2.f * b2f(o.z));
    float a3 = fmaf(cv, vn.w, 2.f * b2f(o.w));
    int i = b;
    for (; i + 2 <= e; i += 2) {
        const ushort4 v0 = H4[(size_t)es[i] * 64 + lane];
        const ushort4 v1 = H4[(size_t)es[i + 1] * 64 + lane];
        a0 += b2f(v0.x) + b2f(v1.x);
        a1 += b2f(v0.y) + b2f(v1.y);
        a2 += b2f(v0.z) + b2f(v1.z);
        a3 += b2f(v0.w) + b2f(v1.w);
    }
    for (; i < e; ++i) {
        const ushort4 v = H4[(size_t)es[i] * 64 + lane];
        a0 += b2f(v.x); a1 += b2f(v.y); a2 += b2f(v.z); a3 += b2f(v.w);
    }
    reinterpret_cast<ushort4*>(ob)[(size_t)node * 64 + lane] =
        make_ushort4(f2b(a0), f2b(a1), f2b(a2), f2b(a3));
}

__global__ __launch_bounds__(256)
void gatherb_kernel(const ushort* __restrict__ tb, const int* __restrict__ rowptr,
                    const int* __restrict__ es, ushort* __restrict__ ob, int n)
{
    const int node = blockIdx.x * 4 + (threadIdx.x >> 6);
    if (node >= n) return;
    const int lane = threadIdx.x & 63;
    const ushort4* H4 = reinterpret_cast<const ushort4*>(tb);
    const ushort4 o = H4[(size_t)node * 64 + lane];
    float a0 = 2.f * b2f(o.x), a1 = 2.f * b2f(o.y), a2 = 2.f * b2f(o.z), a3 = 2.f * b2f(o.w);
    const int b = rowptr[node], e = rowptr[node + 1];
    int i = b;
    for (; i + 2 <= e; i += 2) {
        const ushort4 v0 = H4[(size_t)es[i] * 64 + lane];
        const ushort4 v1 = H4[(size_t)es[i + 1] * 64 + lane];
        a0 += b2f(v0.x) + b2f(v1.x);
        a1 += b2f(v0.y) + b2f(v1.y);
        a2 += b2f(v0.z) + b2f(v1.z);
        a3 += b2f(v0.w) + b2f(v1.w);
    }
    for (; i < e; ++i) {
        const ushort4 v = H4[(size_t)es[i] * 64 + lane];
        a0 += b2f(v.x); a1 += b2f(v.y); a2 += b2f(v.z); a3 += b2f(v.w);
    }
    reinterpret_cast<ushort4*>(ob)[(size_t)node * 64 + lane] =
        make_ushort4(f2b(a0), f2b(a1), f2b(a2), f2b(a3));
}

// Graph boundaries (batch is sorted)
__global__ void offsets_kernel(const int* __restrict__ batch, int n, int* __restrict__ off)
{
    const int g = blockIdx.x * blockDim.x + threadIdx.x;
    if (g > NG) return;
    int lo = 0, hi = n;
    while (lo < hi) { const int mid = (lo + hi) >> 1; if (batch[mid] < g) lo = mid + 1; else hi = mid; }
    off[g] = lo;
}

// LN normalize: bf16 z -> bf16 gr slice0 + bf16(z + vn2[batch]) for layer 1
__global__ void norm0f_kernel(const ushort* __restrict__ zb, const float* __restrict__ sfin,
                              const float* __restrict__ vn2, const int* __restrict__ batch,
                              ushort* __restrict__ grs, ushort* __restrict__ tb, int n)
{
    const size_t i4 = (size_t)blockIdx.x * blockDim.x + threadIdx.x;
    if (i4 >= (size_t)n * 64) return;
    const float m = sfin[0], rs = sfin[1];
    const int row = (int)(i4 >> 6), c4 = (int)(i4 & 63);
    const ushort4 u = reinterpret_cast<const ushort4*>(zb)[i4];
    const float z0 = (b2f(u.x) - m) * rs, z1 = (b2f(u.y) - m) * rs,
                z2 = (b2f(u.z) - m) * rs, z3 = (b2f(u.w) - m) * rs;
    reinterpret_cast<ushort4*>(grs)[(size_t)row * 128 + c4] =
        make_ushort4(f2b(z0), f2b(z1), f2b(z2), f2b(z3));
    const int g = batch[row];
    const float4 e = reinterpret_cast<const float4*>(vn2 + (size_t)g * 256)[c4];
    reinterpret_cast<ushort4*>(tb)[i4] =
        make_ushort4(f2b(z0 + e.x), f2b(z1 + e.y), f2b(z2 + e.z), f2b(z3 + e.w));
}

// LN normalize: bf16 z -> bf16 gr slice1
__global__ void norm1b_kernel(const ushort* __restrict__ zb, const float* __restrict__ sfin,
                              ushort* __restrict__ grs, int n)
{
    const size_t i4 = (size_t)blockIdx.x * blockDim.x + threadIdx.x;
    if (i4 >= (size_t)n * 64) return;
    const float m = sfin[0], rs = sfin[1];
    const int row = (int)(i4 >> 6), c4 = (int)(i4 & 63);
    const ushort4 u = reinterpret_cast<const ushort4*>(zb)[i4];
    reinterpret_cast<ushort4*>(grs)[(size_t)row * 128 + 64 + c4] =
        make_ushort4(f2b((b2f(u.x) - m) * rs), f2b((b2f(u.y) - m) * rs),
                     f2b((b2f(u.z) - m) * rs), f2b((b2f(u.w) - m) * rs));
}

// FUSED virtual-node update (reads h0 from bf16 B1)
__global__ __launch_bounds__(256)
void vnall_kernel(const ushort* __restrict__ hb, const int* __restrict__ off,
                  const float* __restrict__ vn_emb,
                  const float* __restrict__ W1, const float* __restrict__ bb1,
                  const float* __restrict__ W2, const float* __restrict__ bb2,
                  float* __restrict__ vn2)
{
    __shared__ float r1[256];
    __shared__ float r2[512];
    const int g = blockIdx.x, t = threadIdx.x;
    const int i0 = off[g], i1 = off[g + 1];
    float s = 0.f;
    for (int i = i0; i < i1; ++i) s += b2f(hb[(size_t)i * 256 + t]);
    r1[t] = s + vn_emb[t];
    __syncthreads();
    float a0 = 0.f, a1 = 0.f;
    for (int k = 0; k < 256; ++k) {
        const float rv = r1[k];
        a0 = fmaf(rv, W1[(size_t)k * 512 + t], a0);
        a1 = fmaf(rv, W1[(size_t)k * 512 + 256 + t], a1);
    }
    r2[t]       = fmaxf((a0 + bb1[t]) * BNS, 0.f);
    r2[t + 256] = fmaxf((a1 + bb1[256 + t]) * BNS, 0.f);
    __syncthreads();
    float a = 0.f;
    for (int k = 0; k < 512; ++k) a = fmaf(r2[k], W2[(size_t)k * 256 + t], a);
    vn2[(size_t)g * 256 + t] = fmaxf((a + bb2[t]) * BNS, 0.f);
}

// segment max+mean over [h0(B1) | gr slices] -> readbb (bf16) [NG][1536]
__global__ __launch_bounds__(256)
void pool_kernel(const ushort* __restrict__ hb, const ushort* __restrict__ g2,
                 const int* __restrict__ off, ushort* __restrict__ readbb)
{
    const int g = blockIdx.x, t = threadIdx.x;
    const int i0 = off[g], i1 = off[g + 1];
    float m0 = -__builtin_inff(), m1 = m0, m2 = m0;
    float s0 = 0.f, s1 = 0.f, s2 = 0.f;
    for (int i = i0; i < i1; ++i) {
        const float v0 = b2f(hb[(size_t)i * 256 + t]);
        const ushort2 z = *reinterpret_cast<const ushort2*>(g2 + (size_t)i * 512 + 2 * t);
        const float v1 = b2f(z.x), v2 = b2f(z.y);
        m0 = fmaxf(m0, v0); m1 = fmaxf(m1, v1); m2 = fmaxf(m2, v2);
        s0 += v0; s1 += v1; s2 += v2;
    }
    const float inv = 1.f / fmaxf((float)(i1 - i0), 1.f);
    ushort* rb = readbb + (size_t)g * 1536;
    rb[t] = f2b(m0);
    rb[256 + 2 * t] = f2b(m1); rb[256 + 2 * t + 1] = f2b(m2);
    rb[768 + t] = f2b(s0 * inv);
    rb[1024 + 2 * t] = f2b(s1 * inv); rb[1024 + 2 * t + 1] = f2b(s2 * inv);
}

// per-graph logits + ssl from f32 x5
__global__ __launch_bounds__(64)
void head_kernel(const float* __restrict__ x5, const float* __restrict__ clsW,
                 const float* __restrict__ clsb, const float* __restrict__ dW,
                 const float* __restrict__ db, float* __restrict__ logits,
                 float* __restrict__ ssl)
{
    const int g = blockIdx.x, l = threadIdx.x;
    const float* xg = x5 + (size_t)g * 256;
    const float4 v   = reinterpret_cast<const float4*>(xg)[l];
    const float4 w01 = reinterpret_cast<const float4*>(clsW)[l * 2];
    const float4 w23 = reinterpret_cast<const float4*>(clsW)[l * 2 + 1];
    float p0 = v.x * w01.x + v.y * w01.z + v.z * w23.x + v.w * w23.z;
    float p1 = v.x * w01.y + v.y * w01.w + v.z * w23.y + v.w * w23.w;
    float q0 = xg[l] * dW[l];
    float q1 = xg[64 + l] * dW[64 + l];
    float q2 = xg[128 + l] * dW[128 + l];
    for (int o = 32; o; o >>= 1) {
        p0 += __shfl_down(p0, o, 64); p1 += __shfl_down(p1, o, 64);
        q0 += __shfl_down(q0, o, 64); q1 += __shfl_down(q1, o, 64); q2 += __shfl_down(q2, o, 64);
    }
    if (l == 0) {
        const float z0 = p0 + clsb[0], z1 = p1 + clsb[1];
        const float m = fmaxf(z0, z1);
        const float lse = m + logf(expf(z0 - m) + expf(z1 - m));
        logits[(size_t)g * 2 + 0] = z0 - lse;
        logits[(size_t)g * 2 + 1] = z1 - lse;
        ssl[(size_t)g * 3 + 0] = 0.05f + 0.35f / (1.f + expf(-(q0 + db[0])));
        ssl[(size_t)g * 3 + 1] = 0.05f + 0.35f / (1.f + expf(-(q1 + db[1])));
        ssl[(size_t)g * 3 + 2] = 0.05f + 0.35f / (1.f + expf(-(q2 + db[2])));
    }
}

// ---------------------------------------------------------------------------
extern "C" void kernel_launch(void* const* d_in, const int* in_sizes, int n_in,
                              void* d_out, int out_size, void* d_ws, size_t ws_size,
                              hipStream_t stream)
{
    const float* x      = (const float*)d_in[0];
    const int*   eidx   = (const int*)d_in[1];
    const int*   batch  = (const int*)d_in[2];
    const float* lin1_W = (const float*)d_in[3];
    const float* lin1_b = (const float*)d_in[4];
    const float* g0W1   = (const float*)d_in[5];
    const float* g0b1   = (const float*)d_in[6];
    const float* g0W2   = (const float*)d_in[7];
    const float* g0b2   = (const float*)d_in[8];
    const float* g1W1   = (const float*)d_in[9];
    const float* g1b1   = (const float*)d_in[10];
    const float* g1W2   = (const float*)d_in[11];
    const float* g1b2   = (const float*)d_in[12];
    const float* vn_emb = (const float*)d_in[13];
    const float* vnW1   = (const float*)d_in[14];
    const float* vnb1   = (const float*)d_in[15];
    const float* vnW2   = (const float*)d_in[16];
    const float* vnb2   = (const float*)d_in[17];
    const float* loW    = (const float*)d_in[18];
    const float* lob    = (const float*)d_in[19];
    const float* clsW   = (const float*)d_in[20];
    const float* clsb   = (const float*)d_in[21];
    const float* dhW    = (const float*)d_in[22];
    const float* dhb    = (const float*)d_in[23];

    const int N = in_sizes[2];        // 50000 nodes
    const int E = in_sizes[1] / 2;    // 800000 edges
    const int* esrc = eidx;
    const int* edst = eidx + E;

    float* out = (float*)d_out;
    float* out_logits = out;                                     // [NG,2]
    float* out_x5     = out + (size_t)NG * 2;                    // [NG,256]
    float* out_ssl    = out + (size_t)NG * 2 + (size_t)NG * 256; // [NG,3]

    // --- workspace carve (256B aligned; sacc(2KB)+cnt adjacent, one memset) ---
    char* p = (char*)d_ws;
    auto carve = [&](size_t bytes) { char* r = p; p += (bytes + 255) & ~(size_t)255; return (void*)r; };
    double* sacc   = (double*)carve(256 * sizeof(double));          // 64 buckets x2 x 2 layers
    int*    cnt    = (int*)   carve((size_t)N * sizeof(int));
    float*  sfin   = (float*) carve(4 * sizeof(float));
    int*    goff   = (int*)   carve((NG + 1) * sizeof(int));
    int*    rowptr = (int*)   carve((size_t)(N + 1) * sizeof(int));
    int*    cursor = (int*)   carve((size_t)N * sizeof(int));
    int*    bsum   = (int*)   carve(256 * sizeof(int));
    int*    es     = (int*)   carve((size_t)E * sizeof(int));
    ushort* gr2    = (ushort*)carve((size_t)N * 512 * sizeof(ushort)); // [z1|z2] bf16
    ushort* xb     = (ushort*)carve((size_t)N * 128 * sizeof(ushort));
    ushort* B1     = (ushort*)carve((size_t)N * 256 * sizeof(ushort)); // h0 (kept for pool)
    ushort* B2     = (ushort*)carve((size_t)N * 256 * sizeof(ushort));
    ushort* B3     = (ushort*)carve((size_t)N * 256 * sizeof(ushort));
    ushort* Wt1    = (ushort*)carve(256 * 128 * sizeof(ushort));
    ushort* Wt0a   = (ushort*)carve(256 * 256 * sizeof(ushort));
    ushort* Wt0b   = (ushort*)carve(256 * 256 * sizeof(ushort));
    ushort* Wtbd1  = (ushort*)carve(16384 * sizeof(ushort));
    ushort* Wtbd2  = (ushort*)carve(16384 * sizeof(ushort));
    ushort* loWt   = (ushort*)carve(256 * 1536 * sizeof(ushort));
    float*  vn2    = (float*) carve((size_t)NG * 256 * sizeof(float));
    ushort* readbb = (ushort*)carve((size_t)NG * 1536 * sizeof(ushort));

    hipMemsetAsync(sacc, 0, 2048 + (size_t)N * sizeof(int), stream);

    const int mt = (N + 127) / 128;
    const int vecGrid = (N * 64 + 255) / 256;
    const int eGrid = (E + 255) / 256;
    const int gatherGrid = (N + 3) / 4;
    const int nb = (N + 255) / 256;     // scan blocks (196 <= 256)
    const int prepTotal = N * 32 + 196608 + 393216;

    // ---- CSR build (count + 3-level scan + fill) ----
    count_kernel<<<eGrid, 256, 0, stream>>>(edst, cnt, E);
    scan1_kernel<<<nb, 256, 0, stream>>>(cnt, bsum, N);
    scan2_kernel<<<1, 256, 0, stream>>>(bsum, rowptr, nb, N);
    scan3_kernel<<<nb, 256, 0, stream>>>(cnt, bsum, rowptr, cursor, N);
    fill_kernel<<<eGrid, 256, 0, stream>>>(esrc, edst, cursor, es, E);

    // ---- all weight/input prep ----
    prep_kernel<<<(prepTotal + 255) / 256, 256, 0, stream>>>(
        x, lin1_W, g0W1, g0W2, g1W1, g1W2, loW,
        xb, Wt1, Wt0a, Wt0b, Wtbd1, Wtbd2, loWt, N * 32);

    // h0 = elu(x @ lin1_W + b) -> B1 (bf16)
    tgemm_kernel<2, true, false><<<mt, 512, 0, stream>>>(xb, 128, Wt1, lin1_b, B1, nullptr, N);
    offsets_kernel<<<3, 256, 0, stream>>>(batch, N, goff);

    // ---- virtual node update (reads B1 bf16) ----
    vnall_kernel<<<NG, 256, 0, stream>>>(B1, goff, vn_emb, vnW1, vnb1, vnW2, vnb2, vn2);

    // ---- layer 0 ----
    gather0b_kernel<<<gatherGrid, 256, 0, stream>>>(B1, rowptr, es, vn_emb, B2, N);
    mlp0_kernel<<<mt, 512, 0, stream>>>(B2, Wt0a, Wt0b, g0b1, g0b2, B3, N, sacc);
    finalize_kernel<<<1, 64, 0, stream>>>(sacc, sfin, (double)N * 256.0);
    norm0f_kernel<<<vecGrid, 256, 0, stream>>>(B3, sfin, vn2, batch, gr2, B2, N);

    // ---- layer 1 ----
    gatherb_kernel<<<gatherGrid, 256, 0, stream>>>(B2, rowptr, es, B3, N);
    bd2_kernel<<<dim3(mt, 4), 256, 0, stream>>>(B3, Wtbd1, Wtbd2, g1b1, g1b2, B2, N, sacc + 128);
    finalize_kernel<<<1, 64, 0, stream>>>(sacc + 128, sfin + 2, (double)N * 256.0);
    norm1b_kernel<<<vecGrid, 256, 0, stream>>>(B2, sfin + 2, gr2, N);

    // ---- readout ----
    pool_kernel<<<NG, 256, 0, stream>>>(B1, gr2, goff, readbb);
    tgemm_kernel<24, false, true><<<(NG + 127) / 128, 512, 0, stream>>>(
        readbb, 1536, loWt, lob, nullptr, out_x5, NG);
    head_kernel<<<NG, 64, 0, stream>>>(out_x5, clsW, clsb, dhW, dhb, out_logits, out_ssl);
}

// Round 14
// 468.072 us; speedup vs baseline: 1.8455x; 1.0775x over previous
//
#include <hip/hip_runtime.h>

static constexpr int NG = 512;       // graphs
static constexpr float LN_EPS = 1e-5f;
static constexpr float BNS = 0.9999950000374997f; // rsqrt(1 + 1e-5) for BatchNorm eval

__device__ __forceinline__ float eluf(float v) { return v > 0.f ? v : expm1f(v); }

typedef __attribute__((ext_vector_type(8))) short bf16x8;
typedef __attribute__((ext_vector_type(4))) float f32x4;

__device__ __forceinline__ ushort f2b(float f) {   // f32 -> bf16 RNE
    union { float f; unsigned u; } v; v.f = f;
    const unsigned u = v.u;
    return (ushort)((u + 0x7FFFu + ((u >> 16) & 1u)) >> 16);
}
__device__ __forceinline__ float b2f(ushort b) {
    union { unsigned u; float f; } v; v.u = ((unsigned)b) << 16;
    return v.f;
}

// async global->LDS, 16B per lane. LDS dest lane-contiguous (linear).
__device__ __forceinline__ void gl16(const ushort* g, ushort* l) {
    __builtin_amdgcn_global_load_lds(
        (const __attribute__((address_space(1))) void*)g,
        (__attribute__((address_space(3))) void*)l, 16, 0, 0);
}

// ---------------------------------------------------------------------------
// lin1 MFMA GEMM: B1 = bf16(elu(x@W+b)). BM=128, BN=256, BK=64, KSTEPS=2.
// ---------------------------------------------------------------------------
template<int KSTEPS>
__global__ __launch_bounds__(512)
void tgemm_kernel(const ushort* __restrict__ Ab, int ldab,
                  const ushort* __restrict__ Wt,   // [256][KSTEPS*64]
                  const float* __restrict__ bias,
                  ushort* __restrict__ Cb,
                  int n)
{
    __shared__ __align__(16) ushort sbuf[32768];   // 64 KB
    ushort* As = sbuf;          // 128*64
    ushort* Bs = sbuf + 8192;   // 256*64

    const int tid = threadIdx.x;
    const int lane = tid & 63;
    const int wv = tid >> 6;
    const int wr = wv >> 1, wc = wv & 1;
    const int r0 = blockIdx.x * 128;
    const int colL = lane & 15;
    const int lr = lane >> 4;

    f32x4 acc[2][8];
#pragma unroll
    for (int rt = 0; rt < 2; ++rt)
#pragma unroll
        for (int ct = 0; ct < 8; ++ct) acc[rt][ct] = (f32x4){0.f, 0.f, 0.f, 0.f};

    for (int ks = 0; ks < KSTEPS; ++ks) {
#pragma unroll
        for (int it = 0; it < 2; ++it) {           // A
            const int i = it * 512 + tid;
            const int row = i >> 3, cb = i & 7;
            const int rg = min(r0 + row, n - 1);
            gl16(Ab + (size_t)rg * ldab + ks * 64 + ((cb ^ (row & 7)) * 8), As + i * 8);
        }
#pragma unroll
        for (int it = 0; it < 4; ++it) {           // B
            const int i = it * 512 + tid;
            const int col = i >> 3, cb = i & 7;
            gl16(Wt + (size_t)col * (KSTEPS * 64) + ks * 64 + ((cb ^ (col & 7)) * 8), Bs + i * 8);
        }
        __syncthreads();

        bf16x8 af[2][2];
#pragma unroll
        for (int rt = 0; rt < 2; ++rt)
#pragma unroll
            for (int kk = 0; kk < 2; ++kk) {
                const int row = wr * 32 + rt * 16 + colL;
                const int blk = kk * 4 + lr;
                af[rt][kk] = *reinterpret_cast<const bf16x8*>(As + row * 64 + ((blk ^ (row & 7)) * 8));
            }
#pragma unroll
        for (int ct = 0; ct < 8; ++ct)
#pragma unroll
            for (int kk = 0; kk < 2; ++kk) {
                const int col = wc * 128 + ct * 16 + colL;
                const int blk = kk * 4 + lr;
                const bf16x8 bf = *reinterpret_cast<const bf16x8*>(Bs + col * 64 + ((blk ^ (col & 7)) * 8));
                acc[0][ct] = __builtin_amdgcn_mfma_f32_16x16x32_bf16(af[0][kk], bf, acc[0][ct], 0, 0, 0);
                acc[1][ct] = __builtin_amdgcn_mfma_f32_16x16x32_bf16(af[1][kk], bf, acc[1][ct], 0, 0, 0);
            }
        __syncthreads();
    }

    float bv[8];
#pragma unroll
    for (int ct = 0; ct < 8; ++ct) bv[ct] = bias[wc * 128 + ct * 16 + colL];

    ushort* eb = sbuf + wv * 4096;   // 32 rows x 128 cols
#pragma unroll
    for (int rt = 0; rt < 2; ++rt)
#pragma unroll
        for (int ct = 0; ct < 8; ++ct)
#pragma unroll
            for (int r = 0; r < 4; ++r) {
                const float v = eluf(acc[rt][ct][r] + bv[ct]);
                eb[(rt * 16 + lr * 4 + r) * 128 + ct * 16 + colL] = f2b(v);
            }
#pragma unroll
    for (int j = 0; j < 8; ++j) {
        const int idx = j * 64 + lane;
        const int lrow = idx >> 4, c8 = idx & 15;
        const int grow = r0 + wr * 32 + lrow;
        if (grow < n)
            *reinterpret_cast<bf16x8*>(Cb + (size_t)grow * 256 + wc * 128 + c8 * 8) =
                *reinterpret_cast<const bf16x8*>(eb + lrow * 128 + c8 * 8);
    }
}

// ---------------------------------------------------------------------------
// Split-K readout GEMM: xacc += readbb[128 rows][K-slice] @ loWt^T.
// grid (4 row-tiles, 6 K-chunks of 256). f32 atomic accumulate.
// ---------------------------------------------------------------------------
__global__ __launch_bounds__(512)
void xsk_kernel(const ushort* __restrict__ Ab,   // [NG][1536]
                const ushort* __restrict__ Wt,   // [256][1536]
                float* __restrict__ xacc, int n)
{
    __shared__ __align__(16) ushort sbuf[32768];
    ushort* As = sbuf;
    ushort* Bs = sbuf + 8192;

    const int tid = threadIdx.x;
    const int lane = tid & 63;
    const int wv = tid >> 6;
    const int wr = wv >> 1, wc = wv & 1;
    const int r0 = blockIdx.x * 128;
    const int kc = blockIdx.y;          // K chunk (256 wide)
    const int colL = lane & 15;
    const int lr = lane >> 4;

    f32x4 acc[2][8];
#pragma unroll
    for (int rt = 0; rt < 2; ++rt)
#pragma unroll
        for (int ct = 0; ct < 8; ++ct) acc[rt][ct] = (f32x4){0.f, 0.f, 0.f, 0.f};

    for (int ks = 0; ks < 4; ++ks) {
        const int kbase = kc * 256 + ks * 64;
#pragma unroll
        for (int it = 0; it < 2; ++it) {
            const int i = it * 512 + tid;
            const int row = i >> 3, cb = i & 7;
            const int rg = min(r0 + row, n - 1);
            gl16(Ab + (size_t)rg * 1536 + kbase + ((cb ^ (row & 7)) * 8), As + i * 8);
        }
#pragma unroll
        for (int it = 0; it < 4; ++it) {
            const int i = it * 512 + tid;
            const int col = i >> 3, cb = i & 7;
            gl16(Wt + (size_t)col * 1536 + kbase + ((cb ^ (col & 7)) * 8), Bs + i * 8);
        }
        __syncthreads();

        bf16x8 af[2][2];
#pragma unroll
        for (int rt = 0; rt < 2; ++rt)
#pragma unroll
            for (int kk = 0; kk < 2; ++kk) {
                const int row = wr * 32 + rt * 16 + colL;
                const int blk = kk * 4 + lr;
                af[rt][kk] = *reinterpret_cast<const bf16x8*>(As + row * 64 + ((blk ^ (row & 7)) * 8));
            }
#pragma unroll
        for (int ct = 0; ct < 8; ++ct)
#pragma unroll
            for (int kk = 0; kk < 2; ++kk) {
                const int col = wc * 128 + ct * 16 + colL;
                const int blk = kk * 4 + lr;
                const bf16x8 bf = *reinterpret_cast<const bf16x8*>(Bs + col * 64 + ((blk ^ (col & 7)) * 8));
                acc[0][ct] = __builtin_amdgcn_mfma_f32_16x16x32_bf16(af[0][kk], bf, acc[0][ct], 0, 0, 0);
                acc[1][ct] = __builtin_amdgcn_mfma_f32_16x16x32_bf16(af[1][kk], bf, acc[1][ct], 0, 0, 0);
            }
        __syncthreads();
    }

#pragma unroll
    for (int rt = 0; rt < 2; ++rt)
#pragma unroll
        for (int ct = 0; ct < 8; ++ct) {
            const int col = wc * 128 + ct * 16 + colL;
#pragma unroll
            for (int r = 0; r < 4; ++r) {
                const int row = r0 + wr * 32 + rt * 16 + lr * 4 + r;
                if (row < n) unsafeAtomicAdd(&xacc[(size_t)row * 256 + col], acc[rt][ct][r]);
            }
        }
}

// per-graph: x5 = elu(xacc + lob); logits + ssl
__global__ __launch_bounds__(256)
void head2_kernel(const float* __restrict__ xacc, const float* __restrict__ lob,
                  const float* __restrict__ clsW, const float* __restrict__ clsb,
                  const float* __restrict__ dW, const float* __restrict__ db,
                  float* __restrict__ x5, float* __restrict__ logits, float* __restrict__ ssl)
{
    __shared__ float sh[256];
    const int g = blockIdx.x, t = threadIdx.x;
    const float v = eluf(xacc[(size_t)g * 256 + t] + lob[t]);
    x5[(size_t)g * 256 + t] = v;
    sh[t] = v;
    __syncthreads();
    if (t < 64) {
        const int l = t;
        const float4 x4  = reinterpret_cast<const float4*>(sh)[l];
        const float4 w01 = reinterpret_cast<const float4*>(clsW)[l * 2];
        const float4 w23 = reinterpret_cast<const float4*>(clsW)[l * 2 + 1];
        float p0 = x4.x * w01.x + x4.y * w01.z + x4.z * w23.x + x4.w * w23.z;
        float p1 = x4.x * w01.y + x4.y * w01.w + x4.z * w23.y + x4.w * w23.w;
        float q0 = sh[l] * dW[l];
        float q1 = sh[64 + l] * dW[64 + l];
        float q2 = sh[128 + l] * dW[128 + l];
        for (int o = 32; o; o >>= 1) {
            p0 += __shfl_down(p0, o, 64); p1 += __shfl_down(p1, o, 64);
            q0 += __shfl_down(q0, o, 64); q1 += __shfl_down(q1, o, 64); q2 += __shfl_down(q2, o, 64);
        }
        if (l == 0) {
            const float z0 = p0 + clsb[0], z1 = p1 + clsb[1];
            const float m = fmaxf(z0, z1);
            const float lse = m + logf(expf(z0 - m) + expf(z1 - m));
            logits[(size_t)g * 2 + 0] = z0 - lse;
            logits[(size_t)g * 2 + 1] = z1 - lse;
            ssl[(size_t)g * 3 + 0] = 0.05f + 0.35f / (1.f + expf(-(q0 + db[0])));
            ssl[(size_t)g * 3 + 1] = 0.05f + 0.35f / (1.f + expf(-(q1 + db[1])));
            ssl[(size_t)g * 3 + 2] = 0.05f + 0.35f / (1.f + expf(-(q2 + db[2])));
        }
    }
}

// ---------------------------------------------------------------------------
// FUSED dense GIN MLP (layer 0). Stats -> 64 atomic buckets (blockIdx&63).
// ---------------------------------------------------------------------------
__global__ __launch_bounds__(512)
void mlp0_kernel(const ushort* __restrict__ Ab,    // [n][256]
                 const ushort* __restrict__ W1t,   // [256][256]
                 const ushort* __restrict__ W2t,
                 const float* __restrict__ b1, const float* __restrict__ b2,
                 ushort* __restrict__ Cb,
                 int n, double* __restrict__ stats)
{
    __shared__ __align__(16) ushort As[8192];
    __shared__ __align__(16) ushort Bs[16384];
    __shared__ __align__(16) ushort Z[32768];

    const int tid = threadIdx.x;
    const int lane = tid & 63;
    const int wv = tid >> 6;
    const int wr = wv >> 1, wc = wv & 1;
    const int r0 = blockIdx.x * 128;
    const int colL = lane & 15;
    const int lr = lane >> 4;

    f32x4 acc[2][8];
#pragma unroll
    for (int rt = 0; rt < 2; ++rt)
#pragma unroll
        for (int ct = 0; ct < 8; ++ct) acc[rt][ct] = (f32x4){0.f, 0.f, 0.f, 0.f};

    // ---- stage 1: z = relu(A @ W1 + b1) ----
    for (int ks = 0; ks < 4; ++ks) {
#pragma unroll
        for (int it = 0; it < 2; ++it) {
            const int i = it * 512 + tid;
            const int row = i >> 3, cb = i & 7;
            const int rg = min(r0 + row, n - 1);
            gl16(Ab + (size_t)rg * 256 + ks * 64 + ((cb ^ (row & 7)) * 8), As + i * 8);
        }
#pragma unroll
        for (int it = 0; it < 4; ++it) {
            const int i = it * 512 + tid;
            const int col = i >> 3, cb = i & 7;
            gl16(W1t + (size_t)col * 256 + ks * 64 + ((cb ^ (col & 7)) * 8), Bs + i * 8);
        }
        __syncthreads();
        bf16x8 af[2][2];
#pragma unroll
        for (int rt = 0; rt < 2; ++rt)
#pragma unroll
            for (int kk = 0; kk < 2; ++kk) {
                const int row = wr * 32 + rt * 16 + colL;
                const int blk = kk * 4 + lr;
                af[rt][kk] = *reinterpret_cast<const bf16x8*>(As + row * 64 + ((blk ^ (row & 7)) * 8));
            }
#pragma unroll
        for (int ct = 0; ct < 8; ++ct)
#pragma unroll
            for (int kk = 0; kk < 2; ++kk) {
                const int col = wc * 128 + ct * 16 + colL;
                const int blk = kk * 4 + lr;
                const bf16x8 bf = *reinterpret_cast<const bf16x8*>(Bs + col * 64 + ((blk ^ (col & 7)) * 8));
                acc[0][ct] = __builtin_amdgcn_mfma_f32_16x16x32_bf16(af[0][kk], bf, acc[0][ct], 0, 0, 0);
                acc[1][ct] = __builtin_amdgcn_mfma_f32_16x16x32_bf16(af[1][kk], bf, acc[1][ct], 0, 0, 0);
            }
        __syncthreads();
    }
#pragma unroll
    for (int ct = 0; ct < 8; ++ct) {
        const float bvv = b1[wc * 128 + ct * 16 + colL];
#pragma unroll
        for (int rt = 0; rt < 2; ++rt)
#pragma unroll
            for (int r = 0; r < 4; ++r) {
                const float v = fmaxf(acc[rt][ct][r] + bvv, 0.f);
                const int zrow = wr * 32 + rt * 16 + lr * 4 + r;
                const int zcol = wc * 128 + ct * 16 + colL;
                const int chunk = zcol >> 3;
                const int sw = (chunk & 24) | ((chunk & 7) ^ (zrow & 7));
                Z[zrow * 256 + sw * 8 + (zcol & 7)] = f2b(v);
            }
    }
    __syncthreads();

    // ---- stage 2: out = elu(z @ W2 + b2) ----
#pragma unroll
    for (int rt = 0; rt < 2; ++rt)
#pragma unroll
        for (int ct = 0; ct < 8; ++ct) acc[rt][ct] = (f32x4){0.f, 0.f, 0.f, 0.f};

    for (int ks = 0; ks < 4; ++ks) {
#pragma unroll
        for (int it = 0; it < 4; ++it) {
            const int i = it * 512 + tid;
            const int col = i >> 3, cb = i & 7;
            gl16(W2t + (size_t)col * 256 + ks * 64 + ((cb ^ (col & 7)) * 8), Bs + i * 8);
        }
        __syncthreads();
        bf16x8 zf[2][2];
#pragma unroll
        for (int rt = 0; rt < 2; ++rt)
#pragma unroll
            for (int kk = 0; kk < 2; ++kk) {
                const int zrow = wr * 32 + rt * 16 + colL;
                const int chunk = ks * 8 + kk * 4 + lr;
                const int sw = (chunk & 24) | ((chunk & 7) ^ (zrow & 7));
                zf[rt][kk] = *reinterpret_cast<const bf16x8*>(Z + zrow * 256 + sw * 8);
            }
#pragma unroll
        for (int ct = 0; ct < 8; ++ct)
#pragma unroll
            for (int kk = 0; kk < 2; ++kk) {
                const int col = wc * 128 + ct * 16 + colL;
                const int blk = kk * 4 + lr;
                const bf16x8 bf = *reinterpret_cast<const bf16x8*>(Bs + col * 64 + ((blk ^ (col & 7)) * 8));
                acc[0][ct] = __builtin_amdgcn_mfma_f32_16x16x32_bf16(zf[0][kk], bf, acc[0][ct], 0, 0, 0);
                acc[1][ct] = __builtin_amdgcn_mfma_f32_16x16x32_bf16(zf[1][kk], bf, acc[1][ct], 0, 0, 0);
            }
        __syncthreads();
    }

    float bv[8];
#pragma unroll
    for (int ct = 0; ct < 8; ++ct) bv[ct] = b2[wc * 128 + ct * 16 + colL];
    ushort* eb = Z + wv * 4096;
    float s = 0.f, ss = 0.f;
#pragma unroll
    for (int rt = 0; rt < 2; ++rt)
#pragma unroll
        for (int ct = 0; ct < 8; ++ct)
#pragma unroll
            for (int r = 0; r < 4; ++r) {
                const float v = eluf(acc[rt][ct][r] + bv[ct]);
                eb[(rt * 16 + lr * 4 + r) * 128 + ct * 16 + colL] = f2b(v);
                const int row = r0 + wr * 32 + rt * 16 + lr * 4 + r;
                if (row < n) { s += v; ss += v * v; }
            }
#pragma unroll
    for (int j = 0; j < 8; ++j) {
        const int idx = j * 64 + lane;
        const int lrow = idx >> 4, c8 = idx & 15;
        const int grow = r0 + wr * 32 + lrow;
        if (grow < n)
            *reinterpret_cast<bf16x8*>(Cb + (size_t)grow * 256 + wc * 128 + c8 * 8) =
                *reinterpret_cast<const bf16x8*>(eb + lrow * 128 + c8 * 8);
    }
    double ds = (double)s, dss = (double)ss;
    for (int o = 32; o; o >>= 1) { ds += __shfl_down(ds, o, 64); dss += __shfl_down(dss, o, 64); }
    if (lane == 0) {
        const int bkt = (blockIdx.x & 63) * 2;
        unsafeAtomicAdd(&stats[bkt], ds); unsafeAtomicAdd(&stats[bkt + 1], dss);
    }
}

// ---------------------------------------------------------------------------
// FUSED block-diagonal GIN MLP (layer 1). Bucketed stats.
// ---------------------------------------------------------------------------
__global__ __launch_bounds__(256)
void bd2_kernel(const ushort* __restrict__ Ab,    // [n][256]
                const ushort* __restrict__ W1t,   // [4][64 col][64 k]
                const ushort* __restrict__ W2t,
                const float* __restrict__ b1, const float* __restrict__ b2,
                ushort* __restrict__ Cb,
                int n, double* __restrict__ stats)
{
    __shared__ __align__(16) ushort As[8192];
    __shared__ __align__(16) ushort B1s[4096];
    __shared__ __align__(16) ushort B2s[4096];

    const int tid = threadIdx.x;
    const int lane = tid & 63;
    const int wv = tid >> 6;
    const int ch = blockIdx.y;
    const int r0 = blockIdx.x * 128;
    const int colL = lane & 15;
    const int lr = lane >> 4;

#pragma unroll
    for (int it = 0; it < 4; ++it) {             // A
        const int i = it * 256 + tid;
        const int row = i >> 3, cb = i & 7;
        const int rg = min(r0 + row, n - 1);
        gl16(Ab + (size_t)rg * 256 + ch * 64 + ((cb ^ (row & 7)) * 8), As + i * 8);
    }
#pragma unroll
    for (int it = 0; it < 2; ++it) {             // W1
        const int i = it * 256 + tid;
        const int col = i >> 3, cb = i & 7;
        gl16(W1t + ch * 4096 + col * 64 + ((cb ^ (col & 7)) * 8), B1s + i * 8);
    }
#pragma unroll
    for (int it = 0; it < 2; ++it) {             // W2
        const int i = it * 256 + tid;
        const int col = i >> 3, cb = i & 7;
        gl16(W2t + ch * 4096 + col * 64 + ((cb ^ (col & 7)) * 8), B2s + i * 8);
    }
    __syncthreads();

    bf16x8 af[2][2];
#pragma unroll
    for (int rt = 0; rt < 2; ++rt)
#pragma unroll
        for (int kk = 0; kk < 2; ++kk) {
            const int row = wv * 32 + rt * 16 + colL;
            const int blk = kk * 4 + lr;
            af[rt][kk] = *reinterpret_cast<const bf16x8*>(As + row * 64 + ((blk ^ (row & 7)) * 8));
        }
    f32x4 acc[2][4];
#pragma unroll
    for (int rt = 0; rt < 2; ++rt)
#pragma unroll
        for (int ct = 0; ct < 4; ++ct) acc[rt][ct] = (f32x4){0.f, 0.f, 0.f, 0.f};
#pragma unroll
    for (int ct = 0; ct < 4; ++ct)
#pragma unroll
        for (int kk = 0; kk < 2; ++kk) {
            const int col = ct * 16 + colL;
            const int blk = kk * 4 + lr;
            const bf16x8 bf = *reinterpret_cast<const bf16x8*>(B1s + col * 64 + ((blk ^ (col & 7)) * 8));
            acc[0][ct] = __builtin_amdgcn_mfma_f32_16x16x32_bf16(af[0][kk], bf, acc[0][ct], 0, 0, 0);
            acc[1][ct] = __builtin_amdgcn_mfma_f32_16x16x32_bf16(af[1][kk], bf, acc[1][ct], 0, 0, 0);
        }

    ushort* Zw = As + wv * 2048;    // wave-private 32x64
#pragma unroll
    for (int rt = 0; rt < 2; ++rt)
#pragma unroll
        for (int ct = 0; ct < 4; ++ct) {
            const float bvv = b1[ch * 64 + ct * 16 + colL];
#pragma unroll
            for (int r = 0; r < 4; ++r) {
                const float v = fmaxf(acc[rt][ct][r] + bvv, 0.f);
                const int zrow = rt * 16 + lr * 4 + r;
                const int zcol = ct * 16 + colL;
                Zw[zrow * 64 + (((zcol >> 3) ^ (zrow & 7)) * 8) + (zcol & 7)] = f2b(v);
            }
        }

    bf16x8 zf[2][2];
#pragma unroll
    for (int rt = 0; rt < 2; ++rt)
#pragma unroll
        for (int kk = 0; kk < 2; ++kk) {
            const int zrow = rt * 16 + colL;
            const int blk = kk * 4 + lr;
            zf[rt][kk] = *reinterpret_cast<const bf16x8*>(Zw + zrow * 64 + ((blk ^ (zrow & 7)) * 8));
        }
#pragma unroll
    for (int rt = 0; rt < 2; ++rt)
#pragma unroll
        for (int ct = 0; ct < 4; ++ct) acc[rt][ct] = (f32x4){0.f, 0.f, 0.f, 0.f};
#pragma unroll
    for (int ct = 0; ct < 4; ++ct)
#pragma unroll
        for (int kk = 0; kk < 2; ++kk) {
            const int col = ct * 16 + colL;
            const int blk = kk * 4 + lr;
            const bf16x8 bf = *reinterpret_cast<const bf16x8*>(B2s + col * 64 + ((blk ^ (col & 7)) * 8));
            acc[0][ct] = __builtin_amdgcn_mfma_f32_16x16x32_bf16(zf[0][kk], bf, acc[0][ct], 0, 0, 0);
            acc[1][ct] = __builtin_amdgcn_mfma_f32_16x16x32_bf16(zf[1][kk], bf, acc[1][ct], 0, 0, 0);
        }

    float s = 0.f, ss = 0.f;
#pragma unroll
    for (int rt = 0; rt < 2; ++rt)
#pragma unroll
        for (int ct = 0; ct < 4; ++ct) {
            const float bvv = b2[ch * 64 + ct * 16 + colL];
#pragma unroll
            for (int r = 0; r < 4; ++r) {
                const float v = eluf(acc[rt][ct][r] + bvv);
                Zw[(rt * 16 + lr * 4 + r) * 64 + ct * 16 + colL] = f2b(v);
                const int row = r0 + wv * 32 + rt * 16 + lr * 4 + r;
                if (row < n) { s += v; ss += v * v; }
            }
        }
#pragma unroll
    for (int j = 0; j < 4; ++j) {
        const int idx = j * 64 + lane;
        const int lrow = idx >> 3, c8 = idx & 7;
        const int grow = r0 + wv * 32 + lrow;
        if (grow < n)
            *reinterpret_cast<bf16x8*>(Cb + (size_t)grow * 256 + ch * 64 + c8 * 8) =
                *reinterpret_cast<const bf16x8*>(Zw + lrow * 64 + c8 * 8);
    }

    double ds = (double)s, dss = (double)ss;
    for (int o = 32; o; o >>= 1) { ds += __shfl_down(ds, o, 64); dss += __shfl_down(dss, o, 64); }
    if (lane == 0) {
        const int bkt = ((blockIdx.x + blockIdx.y * 16) & 63) * 2;
        unsafeAtomicAdd(&stats[bkt], ds); unsafeAtomicAdd(&stats[bkt + 1], dss);
    }
}

// reduce 64 stat buckets -> sfin {mean, rsqrt}
__global__ __launch_bounds__(64)
void finalize_kernel(const double* __restrict__ sacc, float* __restrict__ sfin, double M)
{
    const int t = threadIdx.x;
    double s = sacc[t * 2], ss = sacc[t * 2 + 1];
    for (int o = 32; o; o >>= 1) { s += __shfl_down(s, o, 64); ss += __shfl_down(ss, o, 64); }
    if (t == 0) {
        const double mean = s / M;
        double var = ss / M - mean * mean;
        if (var < 0.0) var = 0.0;
        sfin[0] = (float)mean;
        sfin[1] = (float)(1.0 / sqrt(var + (double)LN_EPS));
    }
}

// ---------------------------------------------------------------------------
// ONE prep kernel: x->bf16 + all weight transposes (incl. loW -> [256][1536])
// ---------------------------------------------------------------------------
__global__ void prep_kernel(const float* __restrict__ x,
                            const float* __restrict__ lin1W,
                            const float* __restrict__ g0W1, const float* __restrict__ g0W2,
                            const float* __restrict__ g1W1, const float* __restrict__ g1W2,
                            const float* __restrict__ loW,
                            ushort* __restrict__ xb,
                            ushort* __restrict__ Wt1,
                            ushort* __restrict__ Wt0a, ushort* __restrict__ Wt0b,
                            ushort* __restrict__ Wtbd1, ushort* __restrict__ Wtbd2,
                            ushort* __restrict__ loWt,
                            int n32)
{
    const int i = blockIdx.x * 256 + threadIdx.x;
    if (i < n32) {
        const float4 v = reinterpret_cast<const float4*>(x)[i];
        reinterpret_cast<ushort4*>(xb)[i] = make_ushort4(f2b(v.x), f2b(v.y), f2b(v.z), f2b(v.w));
        return;
    }
    int j = i - n32;
    if (j < 32768) {                         // Wt1 [256][128]
        const int c = j >> 7, k = j & 127;
        Wt1[j] = f2b(lin1W[(size_t)k * 256 + c]);
    } else if (j < 98304) {                  // Wt0a [256][256]
        j -= 32768;
        const int c = j >> 8, k = j & 255;
        Wt0a[j] = f2b(g0W1[(size_t)k * 256 + c]);
    } else if (j < 163840) {                 // Wt0b
        j -= 98304;
        const int c = j >> 8, k = j & 255;
        Wt0b[j] = f2b(g0W2[(size_t)k * 256 + c]);
    } else if (j < 180224) {                 // Wtbd1 [4][64][64]
        j -= 163840;
        const int ch = j >> 12, r = j & 4095, cw = r >> 6, k = r & 63;
        Wtbd1[j] = f2b(g1W1[ch * 4096 + k * 64 + cw]);
    } else if (j < 196608) {                 // Wtbd2
        j -= 180224;
        const int ch = j >> 12, r = j & 4095, cw = r >> 6, k = r & 63;
        Wtbd2[j] = f2b(g1W2[ch * 4096 + k * 64 + cw]);
    } else if (j < 196608 + 393216) {        // loWt [256][1536]
        j -= 196608;
        const int c = j / 1536, k = j - c * 1536;
        loWt[j] = f2b(loW[(size_t)k * 256 + c]);
    }
}

// ---------------------------------------------------------------------------
// CSR construction: count + 3-level scan + fill
// ---------------------------------------------------------------------------
__global__ void count_kernel(const int* __restrict__ dst, int* __restrict__ cnt, int nE)
{
    const int e = blockIdx.x * 256 + threadIdx.x;
    if (e < nE) atomicAdd(&cnt[dst[e]], 1);
}

__global__ __launch_bounds__(256)
void scan1_kernel(const int* __restrict__ cnt, int* __restrict__ bsum, int n)
{
    __shared__ int ws[4];
    const int i = blockIdx.x * 256 + threadIdx.x;
    int v = (i < n) ? cnt[i] : 0;
    for (int o = 32; o; o >>= 1) v += __shfl_down(v, o, 64);
    if ((threadIdx.x & 63) == 0) ws[threadIdx.x >> 6] = v;
    __syncthreads();
    if (threadIdx.x == 0) bsum[blockIdx.x] = ws[0] + ws[1] + ws[2] + ws[3];
}

__global__ __launch_bounds__(256)
void scan2_kernel(int* __restrict__ bsum, int* __restrict__ rowptr, int nb, int n)
{
    __shared__ int sh[256];
    const int t = threadIdx.x;
    const int v = (t < nb) ? bsum[t] : 0;
    sh[t] = v;
    __syncthreads();
    for (int o = 1; o < 256; o <<= 1) {
        const int u = (t >= o) ? sh[t - o] : 0;
        __syncthreads();
        sh[t] += u;
        __syncthreads();
    }
    if (t < nb) bsum[t] = sh[t] - v;    // exclusive
    if (t == 255) rowptr[n] = sh[255];
}

__global__ __launch_bounds__(256)
void scan3_kernel(const int* __restrict__ cnt, const int* __restrict__ bsum,
                  int* __restrict__ rowptr, int* __restrict__ cursor, int n)
{
    __shared__ int sh[256];
    const int t = threadIdx.x;
    const int i = blockIdx.x * 256 + t;
    const int v = (i < n) ? cnt[i] : 0;
    sh[t] = v;
    __syncthreads();
    for (int o = 1; o < 256; o <<= 1) {
        const int u = (t >= o) ? sh[t - o] : 0;
        __syncthreads();
        sh[t] += u;
        __syncthreads();
    }
    if (i < n) {
        const int ex = bsum[blockIdx.x] + sh[t] - v;
        rowptr[i] = ex;
        cursor[i] = ex;
    }
}

__global__ void fill_kernel(const int* __restrict__ src, const int* __restrict__ dst,
                            int* __restrict__ cursor, int* __restrict__ es, int nE)
{
    const int e = blockIdx.x * 256 + threadIdx.x;
    if (e >= nE) return;
    const int p = atomicAdd(&cursor[dst[e]], 1);
    es[p] = src[e];
}

// ---------------------------------------------------------------------------
// Gathers (bf16 rows, one wave per node)
// ---------------------------------------------------------------------------
__global__ __launch_bounds__(256)
void gather0b_kernel(const ushort* __restrict__ hb, const int* __restrict__ rowptr,
                     const int* __restrict__ es, const float* __restrict__ vn_emb,
                     ushort* __restrict__ ob, int n)
{
    const int node = blockIdx.x * 4 + (threadIdx.x >> 6);
    if (node >= n) return;
    const int lane = threadIdx.x & 63;
    const ushort4* H4 = reinterpret_cast<const ushort4*>(hb);
    const ushort4 o = H4[(size_t)node * 64 + lane];
    const int b = rowptr[node], e = rowptr[node + 1];
    const float4 vn = reinterpret_cast<const float4*>(vn_emb)[lane];
    const float cv = (float)(2 + (e - b));
    float a0 = fmaf(cv, vn.x, 2.f * b2f(o.x));
    float a1 = fmaf(cv, vn.y, 2.f * b2f(o.y));
    float a2 = fmaf(cv, vn.z, 2.f * b2f(o.z));
    float a3 = fmaf(cv, vn.w, 2.f * b2f(o.w));
    int i = b;
    for (; i + 2 <= e; i += 2) {
        const ushort4 v0 = H4[(size_t)es[i] * 64 + lane];
        const ushort4 v1 = H4[(size_t)es[i + 1] * 64 + lane];
        a0 += b2f(v0.x) + b2f(v1.x);
        a1 += b2f(v0.y) + b2f(v1.y);
        a2 += b2f(v0.z) + b2f(v1.z);
        a3 += b2f(v0.w) + b2f(v1.w);
    }
    for (; i < e; ++i) {
        const ushort4 v = H4[(size_t)es[i] * 64 + lane];
        a0 += b2f(v.x); a1 += b2f(v.y); a2 += b2f(v.z); a3 += b2f(v.w);
    }
    reinterpret_cast<ushort4*>(ob)[(size_t)node * 64 + lane] =
        make_ushort4(f2b(a0), f2b(a1), f2b(a2), f2b(a3));
}

__global__ __launch_bounds__(256)
void gatherb_kernel(const ushort* __restrict__ tb, const int* __restrict__ rowptr,
                    const int* __restrict__ es, ushort* __restrict__ ob, int n)
{
    const int node = blockIdx.x * 4 + (threadIdx.x >> 6);
    if (node >= n) return;
    const int lane = threadIdx.x & 63;
    const ushort4* H4 = reinterpret_cast<const ushort4*>(tb);
    const ushort4 o = H4[(size_t)node * 64 + lane];
    float a0 = 2.f * b2f(o.x), a1 = 2.f * b2f(o.y), a2 = 2.f * b2f(o.z), a3 = 2.f * b2f(o.w);
    const int b = rowptr[node], e = rowptr[node + 1];
    int i = b;
    for (; i + 2 <= e; i += 2) {
        const ushort4 v0 = H4[(size_t)es[i] * 64 + lane];
        const ushort4 v1 = H4[(size_t)es[i + 1] * 64 + lane];
        a0 += b2f(v0.x) + b2f(v1.x);
        a1 += b2f(v0.y) + b2f(v1.y);
        a2 += b2f(v0.z) + b2f(v1.z);
        a3 += b2f(v0.w) + b2f(v1.w);
    }
    for (; i < e; ++i) {
        const ushort4 v = H4[(size_t)es[i] * 64 + lane];
        a0 += b2f(v.x); a1 += b2f(v.y); a2 += b2f(v.z); a3 += b2f(v.w);
    }
    reinterpret_cast<ushort4*>(ob)[(size_t)node * 64 + lane] =
        make_ushort4(f2b(a0), f2b(a1), f2b(a2), f2b(a3));
}

// Graph boundaries (batch is sorted)
__global__ void offsets_kernel(const int* __restrict__ batch, int n, int* __restrict__ off)
{
    const int g = blockIdx.x * blockDim.x + threadIdx.x;
    if (g > NG) return;
    int lo = 0, hi = n;
    while (lo < hi) { const int mid = (lo + hi) >> 1; if (batch[mid] < g) lo = mid + 1; else hi = mid; }
    off[g] = lo;
}

// LN normalize: bf16 z -> bf16 gr slice0 + bf16(z + vn2[batch]) for layer 1
__global__ void norm0f_kernel(const ushort* __restrict__ zb, const float* __restrict__ sfin,
                              const float* __restrict__ vn2, const int* __restrict__ batch,
                              ushort* __restrict__ grs, ushort* __restrict__ tb, int n)
{
    const size_t i4 = (size_t)blockIdx.x * blockDim.x + threadIdx.x;
    if (i4 >= (size_t)n * 64) return;
    const float m = sfin[0], rs = sfin[1];
    const int row = (int)(i4 >> 6), c4 = (int)(i4 & 63);
    const ushort4 u = reinterpret_cast<const ushort4*>(zb)[i4];
    const float z0 = (b2f(u.x) - m) * rs, z1 = (b2f(u.y) - m) * rs,
                z2 = (b2f(u.z) - m) * rs, z3 = (b2f(u.w) - m) * rs;
    reinterpret_cast<ushort4*>(grs)[(size_t)row * 128 + c4] =
        make_ushort4(f2b(z0), f2b(z1), f2b(z2), f2b(z3));
    const int g = batch[row];
    const float4 e = reinterpret_cast<const float4*>(vn2 + (size_t)g * 256)[c4];
    reinterpret_cast<ushort4*>(tb)[i4] =
        make_ushort4(f2b(z0 + e.x), f2b(z1 + e.y), f2b(z2 + e.z), f2b(z3 + e.w));
}

// LN normalize: bf16 z -> bf16 gr slice1
__global__ void norm1b_kernel(const ushort* __restrict__ zb, const float* __restrict__ sfin,
                              ushort* __restrict__ grs, int n)
{
    const size_t i4 = (size_t)blockIdx.x * blockDim.x + threadIdx.x;
    if (i4 >= (size_t)n * 64) return;
    const float m = sfin[0], rs = sfin[1];
    const int row = (int)(i4 >> 6), c4 = (int)(i4 & 63);
    const ushort4 u = reinterpret_cast<const ushort4*>(zb)[i4];
    reinterpret_cast<ushort4*>(grs)[(size_t)row * 128 + 64 + c4] =
        make_ushort4(f2b((b2f(u.x) - m) * rs), f2b((b2f(u.y) - m) * rs),
                     f2b((b2f(u.z) - m) * rs), f2b((b2f(u.w) - m) * rs));
}

// FUSED virtual-node update (reads h0 from bf16 B1)
__global__ __launch_bounds__(256)
void vnall_kernel(const ushort* __restrict__ hb, const int* __restrict__ off,
                  const float* __restrict__ vn_emb,
                  const float* __restrict__ W1, const float* __restrict__ bb1,
                  const float* __restrict__ W2, const float* __restrict__ bb2,
                  float* __restrict__ vn2)
{
    __shared__ float r1[256];
    __shared__ float r2[512];
    const int g = blockIdx.x, t = threadIdx.x;
    const int i0 = off[g], i1 = off[g + 1];
    float s = 0.f;
    for (int i = i0; i < i1; ++i) s += b2f(hb[(size_t)i * 256 + t]);
    r1[t] = s + vn_emb[t];
    __syncthreads();
    float a0 = 0.f, a1 = 0.f;
    for (int k = 0; k < 256; ++k) {
        const float rv = r1[k];
        a0 = fmaf(rv, W1[(size_t)k * 512 + t], a0);
        a1 = fmaf(rv, W1[(size_t)k * 512 + 256 + t], a1);
    }
    r2[t]       = fmaxf((a0 + bb1[t]) * BNS, 0.f);
    r2[t + 256] = fmaxf((a1 + bb1[256 + t]) * BNS, 0.f);
    __syncthreads();
    float a = 0.f;
    for (int k = 0; k < 512; ++k) a = fmaf(r2[k], W2[(size_t)k * 256 + t], a);
    vn2[(size_t)g * 256 + t] = fmaxf((a + bb2[t]) * BNS, 0.f);
}

// segment max+mean over [h0(B1) | gr slices] -> readbb (bf16) [NG][1536]
__global__ __launch_bounds__(256)
void pool_kernel(const ushort* __restrict__ hb, const ushort* __restrict__ g2,
                 const int* __restrict__ off, ushort* __restrict__ readbb)
{
    const int g = blockIdx.x, t = threadIdx.x;
    const int i0 = off[g], i1 = off[g + 1];
    float m0 = -__builtin_inff(), m1 = m0, m2 = m0;
    float s0 = 0.f, s1 = 0.f, s2 = 0.f;
    for (int i = i0; i < i1; ++i) {
        const float v0 = b2f(hb[(size_t)i * 256 + t]);
        const ushort2 z = *reinterpret_cast<const ushort2*>(g2 + (size_t)i * 512 + 2 * t);
        const float v1 = b2f(z.x), v2 = b2f(z.y);
        m0 = fmaxf(m0, v0); m1 = fmaxf(m1, v1); m2 = fmaxf(m2, v2);
        s0 += v0; s1 += v1; s2 += v2;
    }
    const float inv = 1.f / fmaxf((float)(i1 - i0), 1.f);
    ushort* rb = readbb + (size_t)g * 1536;
    rb[t] = f2b(m0);
    rb[256 + 2 * t] = f2b(m1); rb[256 + 2 * t + 1] = f2b(m2);
    rb[768 + t] = f2b(s0 * inv);
    rb[1024 + 2 * t] = f2b(s1 * inv); rb[1024 + 2 * t + 1] = f2b(s2 * inv);
}

// ---------------------------------------------------------------------------
extern "C" void kernel_launch(void* const* d_in, const int* in_sizes, int n_in,
                              void* d_out, int out_size, void* d_ws, size_t ws_size,
                              hipStream_t stream)
{
    const float* x      = (const float*)d_in[0];
    const int*   eidx   = (const int*)d_in[1];
    const int*   batch  = (const int*)d_in[2];
    const float* lin1_W = (const float*)d_in[3];
    const float* lin1_b = (const float*)d_in[4];
    const float* g0W1   = (const float*)d_in[5];
    const float* g0b1   = (const float*)d_in[6];
    const float* g0W2   = (const float*)d_in[7];
    const float* g0b2   = (const float*)d_in[8];
    const float* g1W1   = (const float*)d_in[9];
    const float* g1b1   = (const float*)d_in[10];
    const float* g1W2   = (const float*)d_in[11];
    const float* g1b2   = (const float*)d_in[12];
    const float* vn_emb = (const float*)d_in[13];
    const float* vnW1   = (const float*)d_in[14];
    const float* vnb1   = (const float*)d_in[15];
    const float* vnW2   = (const float*)d_in[16];
    const float* vnb2   = (const float*)d_in[17];
    const float* loW    = (const float*)d_in[18];
    const float* lob    = (const float*)d_in[19];
    const float* clsW   = (const float*)d_in[20];
    const float* clsb   = (const float*)d_in[21];
    const float* dhW    = (const float*)d_in[22];
    const float* dhb    = (const float*)d_in[23];

    const int N = in_sizes[2];        // 50000 nodes
    const int E = in_sizes[1] / 2;    // 800000 edges
    const int* esrc = eidx;
    const int* edst = eidx + E;

    float* out = (float*)d_out;
    float* out_logits = out;                                     // [NG,2]
    float* out_x5     = out + (size_t)NG * 2;                    // [NG,256]
    float* out_ssl    = out + (size_t)NG * 2 + (size_t)NG * 256; // [NG,3]

    // --- workspace carve (256B aligned; sacc(2KB)+cnt adjacent, one memset) ---
    char* p = (char*)d_ws;
    auto carve = [&](size_t bytes) { char* r = p; p += (bytes + 255) & ~(size_t)255; return (void*)r; };
    double* sacc   = (double*)carve(256 * sizeof(double));          // 64 buckets x2 x 2 layers
    int*    cnt    = (int*)   carve((size_t)N * sizeof(int));
    float*  sfin   = (float*) carve(4 * sizeof(float));
    int*    goff   = (int*)   carve((NG + 1) * sizeof(int));
    int*    rowptr = (int*)   carve((size_t)(N + 1) * sizeof(int));
    int*    cursor = (int*)   carve((size_t)N * sizeof(int));
    int*    bsum   = (int*)   carve(256 * sizeof(int));
    int*    es     = (int*)   carve((size_t)E * sizeof(int));
    ushort* gr2    = (ushort*)carve((size_t)N * 512 * sizeof(ushort)); // [z1|z2] bf16
    ushort* xb     = (ushort*)carve((size_t)N * 128 * sizeof(ushort));
    ushort* B1     = (ushort*)carve((size_t)N * 256 * sizeof(ushort)); // h0 (kept for pool)
    ushort* B2     = (ushort*)carve((size_t)N * 256 * sizeof(ushort));
    ushort* B3     = (ushort*)carve((size_t)N * 256 * sizeof(ushort));
    ushort* Wt1    = (ushort*)carve(256 * 128 * sizeof(ushort));
    ushort* Wt0a   = (ushort*)carve(256 * 256 * sizeof(ushort));
    ushort* Wt0b   = (ushort*)carve(256 * 256 * sizeof(ushort));
    ushort* Wtbd1  = (ushort*)carve(16384 * sizeof(ushort));
    ushort* Wtbd2  = (ushort*)carve(16384 * sizeof(ushort));
    ushort* loWt   = (ushort*)carve(256 * 1536 * sizeof(ushort));
    float*  vn2    = (float*) carve((size_t)NG * 256 * sizeof(float));
    ushort* readbb = (ushort*)carve((size_t)NG * 1536 * sizeof(ushort));
    float*  xacc   = (float*) carve((size_t)NG * 256 * sizeof(float));

    hipMemsetAsync(sacc, 0, 2048 + (size_t)N * sizeof(int), stream);
    hipMemsetAsync(xacc, 0, (size_t)NG * 256 * sizeof(float), stream);

    const int mt = (N + 127) / 128;
    const int vecGrid = (N * 64 + 255) / 256;
    const int eGrid = (E + 255) / 256;
    const int gatherGrid = (N + 3) / 4;
    const int nb = (N + 255) / 256;     // scan blocks (196 <= 256)
    const int prepTotal = N * 32 + 196608 + 393216;

    // ---- CSR build (count + 3-level scan + fill) ----
    count_kernel<<<eGrid, 256, 0, stream>>>(edst, cnt, E);
    scan1_kernel<<<nb, 256, 0, stream>>>(cnt, bsum, N);
    scan2_kernel<<<1, 256, 0, stream>>>(bsum, rowptr, nb, N);
    scan3_kernel<<<nb, 256, 0, stream>>>(cnt, bsum, rowptr, cursor, N);
    fill_kernel<<<eGrid, 256, 0, stream>>>(esrc, edst, cursor, es, E);

    // ---- all weight/input prep ----
    prep_kernel<<<(prepTotal + 255) / 256, 256, 0, stream>>>(
        x, lin1_W, g0W1, g0W2, g1W1, g1W2, loW,
        xb, Wt1, Wt0a, Wt0b, Wtbd1, Wtbd2, loWt, N * 32);

    // h0 = elu(x @ lin1_W + b) -> B1 (bf16)
    tgemm_kernel<2><<<mt, 512, 0, stream>>>(xb, 128, Wt1, lin1_b, B1, N);
    offsets_kernel<<<3, 256, 0, stream>>>(batch, N, goff);

    // ---- virtual node update (reads B1 bf16) ----
    vnall_kernel<<<NG, 256, 0, stream>>>(B1, goff, vn_emb, vnW1, vnb1, vnW2, vnb2, vn2);

    // ---- layer 0 ----
    gather0b_kernel<<<gatherGrid, 256, 0, stream>>>(B1, rowptr, es, vn_emb, B2, N);
    mlp0_kernel<<<mt, 512, 0, stream>>>(B2, Wt0a, Wt0b, g0b1, g0b2, B3, N, sacc);
    finalize_kernel<<<1, 64, 0, stream>>>(sacc, sfin, (double)N * 256.0);
    norm0f_kernel<<<vecGrid, 256, 0, stream>>>(B3, sfin, vn2, batch, gr2, B2, N);

    // ---- layer 1 ----
    gatherb_kernel<<<gatherGrid, 256, 0, stream>>>(B2, rowptr, es, B3, N);
    bd2_kernel<<<dim3(mt, 4), 256, 0, stream>>>(B3, Wtbd1, Wtbd2, g1b1, g1b2, B2, N, sacc + 128);
    finalize_kernel<<<1, 64, 0, stream>>>(sacc + 128, sfin + 2, (double)N * 256.0);
    norm1b_kernel<<<vecGrid, 256, 0, stream>>>(B2, sfin + 2, gr2, N);

    // ---- readout (pool + split-K MFMA GEMM + head) ----
    pool_kernel<<<NG, 256, 0, stream>>>(B1, gr2, goff, readbb);
    xsk_kernel<<<dim3((NG + 127) / 128, 6), 512, 0, stream>>>(readbb, loWt, xacc, NG);
    head2_kernel<<<NG, 256, 0, stream>>>(xacc, lob, clsW, clsb, dhW, dhb,
                                         out_x5, out_logits, out_ssl);
}